// Round 1
// baseline (311.740 us; speedup 1.0000x reference)
//
#include <hip/hip_runtime.h>
#include <hip/hip_bf16.h>
#include <math.h>

#define BB 8
#define LL 160000
#define CC 4
#define NFFT 320
#define HOP 160
#define FB 161          // rfft bins
#define TT 1001         // frames
#define TP 1024         // padded frames per batch (t-slots) for STFT GEMM
#define RBLK 128        // stats blocks per batch
#define PI_D 3.14159265358979323846
#define NPAD 160320     // reflect-padded samples per (b,c): p in [-160, 160159]

#define CH 2            // scan t-chunk per thread (CH=2 + 256-thread blocks)
#define SCH 504         // scan outputs per half-block (2 halves cover 1001)
#define KWARM 4         // warm-up frames; tail weight 0.05^5 ~ 3e-7 rel << bf16 error floor (4.9e-4)

#define GM 16016        // irfft GEMM M = 2*BB*TT rows (beam,b,t)
#define KSEC 352        // irfft padded K per split-section (322 used)
#define LDK 704         // irfft A/Bt leading dim = 2 sections
#define KT 11           // irfft K-tiles of 32 per section
// R14: K-loops in k_gstft/k_gemm converted to barrier-free direct-global fragment
// gathers (no LDS staging). Every fragment slice is a 64B-aligned full cacheline
// (NPAD*2=320640, 640*2=1280, LDK*2=1408, KSEC*2=704 all 64B multiples), so the
// gather has zero over-fetch; A is L2-resident (reused 6x / 5x across col-blocks),
// B is L1/L2-resident (reused 512x / 251x across row-blocks).
// LIFETIME NOTE (R13 bug): Bt/Bts must NOT live in the S region — k_gstft overwrites
// ALL of S. Both live in d_out's head (dead until k_ola fully overwrites at the end).

typedef __attribute__((ext_vector_type(8))) short bf16x8;
typedef __attribute__((ext_vector_type(4))) float f32x4;

__device__ __forceinline__ float2 cmulf(float2 a, float2 b){           // a*b
    return make_float2(a.x*b.x - a.y*b.y, a.x*b.y + a.y*b.x);
}
__device__ __forceinline__ float2 cmulcj(float2 a, float2 b){          // a*conj(b)
    return make_float2(a.x*b.x + a.y*b.y, a.y*b.x - a.x*b.y);
}
__device__ __forceinline__ float2 cjmul(float2 a, float2 b){           // conj(a)*b
    return make_float2(a.x*b.x + a.y*b.y, a.x*b.y - a.y*b.x);
}
__device__ __forceinline__ float2 csub(float2 a, float2 b){ return make_float2(a.x-b.x, a.y-b.y); }
__device__ __forceinline__ float2 cscale(float2 a, float s){ return make_float2(a.x*s, a.y*s); }
__device__ __forceinline__ float2 cdivf(float2 a, float2 b){           // a/b
    float inv = 1.0f/(b.x*b.x + b.y*b.y);
    return make_float2((a.x*b.x + a.y*b.y)*inv, (a.y*b.x - a.x*b.y)*inv);
}
__device__ __forceinline__ short bf_hi(float v){
    __hip_bfloat16 h = __float2bfloat16(v);
    short s; __builtin_memcpy(&s, &h, 2); return s;
}
__device__ __forceinline__ short bf_lo(float v){
    __hip_bfloat16 h = __float2bfloat16(v);
    float r = v - __bfloat162float(h);
    __hip_bfloat16 l = __float2bfloat16(r);
    short s; __builtin_memcpy(&s, &l, 2); return s;
}

// ---------- fused table generator: htab | Bts (STFT B) | Bt (irfft B) ----------
__global__ void k_gen(const float* __restrict__ win, float* __restrict__ htab,
                      short* __restrict__ Bts, short* __restrict__ Bt){
    int gid = blockIdx.x*256 + threadIdx.x;
    if (gid < 2*FB*CC){
        int i = gid;
        int c = i & 3;
        int k = (i >> 2) % FB;
        int m = i / (FB*CC);
        double coef = 2.0*PI_D*50.0*0.027*sin(40.0*PI_D/180.0)/340.0;
        double sgn = (m == 0) ? -1.0 : 1.0;
        double ph = sgn*coef*(double)k*(double)c;
        double s, c2;
        sincos(ph, &s, &c2);
        ((float2*)htab)[i] = make_float2((float)c2, (float)s);
        return;
    }
    gid -= 2*FB*CC;
    if (gid < 384*640){
        int col = gid / 640, kk = gid % 640;
        int n = (kk >= 320) ? kk - 320 : kk;
        int sec = (kk >= 320) ? 1 : 0;
        float v = 0.f;
        if (col < 2*FB){
            int k = col >> 1;
            double th = 2.0*PI_D*(double)k*(double)n/320.0;
            double s, co; sincos(th, &s, &co);
            double tw = (col & 1) ? -s : co;
            v = (float)((double)win[n]*tw);
        }
        Bts[gid] = sec ? bf_lo(v) : bf_hi(v);
        return;
    }
    gid -= 384*640;
    if (gid < NFFT*LDK){
        int n = gid / LDK, kk = gid % LDK;
        int sec = (kk >= KSEC) ? 1 : 0;
        int kk2 = kk - (sec ? KSEC : 0);
        float v = 0.f;
        if (kk2 < 2*FB){
            int bin = kk2 >> 1;
            double c = ((bin == 0 || bin == 160) ? 1.0 : 2.0) / 320.0;
            double th = 2.0*PI_D*(double)bin*(double)n/320.0;
            double s, co; sincos(th, &s, &co);
            v = (float)((kk2 & 1) ? -c*s : c*co);
        }
        Bt[(size_t)n*LDK + kk] = sec ? bf_lo(v) : bf_hi(v);
    }
}

// ---------- stage 1: per-(b,chunk) partial {sum4, min4, max4} ----------
__global__ __launch_bounds__(256) void k_stats1(const float* __restrict__ in, float* __restrict__ part){
    __shared__ float4 s4[256];
    __shared__ float4 mn4[256];
    __shared__ float4 mx4[256];
    int b = blockIdx.x / RBLK, chunk = blockIdx.x % RBLK;
    int tid = threadIdx.x;
    const float4* p = (const float4*)(in + (size_t)b*LL*CC);
    const int per = LL / RBLK;
    int start = chunk*per;
    float4 s  = make_float4(0.f,0.f,0.f,0.f);
    float4 mn = make_float4( 3.4e38f, 3.4e38f, 3.4e38f, 3.4e38f);
    float4 mx = make_float4(-3.4e38f,-3.4e38f,-3.4e38f,-3.4e38f);
    for (int i = start + tid; i < start + per; i += 256){
        float4 v = p[i];
        s.x += v.x; s.y += v.y; s.z += v.z; s.w += v.w;
        mn.x = fminf(mn.x, v.x); mn.y = fminf(mn.y, v.y); mn.z = fminf(mn.z, v.z); mn.w = fminf(mn.w, v.w);
        mx.x = fmaxf(mx.x, v.x); mx.y = fmaxf(mx.y, v.y); mx.z = fmaxf(mx.z, v.z); mx.w = fmaxf(mx.w, v.w);
    }
    s4[tid] = s; mn4[tid] = mn; mx4[tid] = mx;
    __syncthreads();
    for (int st = 128; st >= 1; st >>= 1){
        if (tid < st){
            float4 a = s4[tid], c = s4[tid+st];
            s4[tid] = make_float4(a.x+c.x, a.y+c.y, a.z+c.z, a.w+c.w);
            float4 d = mn4[tid], e = mn4[tid+st];
            mn4[tid] = make_float4(fminf(d.x,e.x), fminf(d.y,e.y), fminf(d.z,e.z), fminf(d.w,e.w));
            float4 f = mx4[tid], g = mx4[tid+st];
            mx4[tid] = make_float4(fmaxf(f.x,g.x), fmaxf(f.y,g.y), fmaxf(f.z,g.z), fmaxf(f.w,g.w));
        }
        __syncthreads();
    }
    if (tid == 0){
        float* dst = part + (size_t)(b*RBLK + chunk)*12;
        float4 a = s4[0], d = mn4[0], f = mx4[0];
        dst[0]=a.x; dst[1]=a.y; dst[2]=a.z; dst[3]=a.w;
        dst[4]=d.x; dst[5]=d.y; dst[6]=d.z; dst[7]=d.w;
        dst[8]=f.x; dst[9]=f.y; dst[10]=f.z; dst[11]=f.w;
    }
}

// ---------- stage 2: finalize mean + invmax per batch ----------
__global__ __launch_bounds__(128) void k_stats2(const float* __restrict__ part,
                                                float* __restrict__ mean, float* __restrict__ invmax){
    __shared__ float4 s4[128];
    __shared__ float4 mn4[128];
    __shared__ float4 mx4[128];
    int b = blockIdx.x, tid = threadIdx.x;
    const float* src = part + (size_t)(b*RBLK + tid)*12;
    s4[tid]  = make_float4(src[0], src[1], src[2], src[3]);
    mn4[tid] = make_float4(src[4], src[5], src[6], src[7]);
    mx4[tid] = make_float4(src[8], src[9], src[10], src[11]);
    __syncthreads();
    for (int st = 64; st >= 1; st >>= 1){
        if (tid < st){
            float4 a = s4[tid], c = s4[tid+st];
            s4[tid] = make_float4(a.x+c.x, a.y+c.y, a.z+c.z, a.w+c.w);
            float4 d = mn4[tid], e = mn4[tid+st];
            mn4[tid] = make_float4(fminf(d.x,e.x), fminf(d.y,e.y), fminf(d.z,e.z), fminf(d.w,e.w));
            float4 f = mx4[tid], g = mx4[tid+st];
            mx4[tid] = make_float4(fmaxf(f.x,g.x), fmaxf(f.y,g.y), fmaxf(f.z,g.z), fmaxf(f.w,g.w));
        }
        __syncthreads();
    }
    if (tid == 0){
        float4 sum = s4[0], mn = mn4[0], mx = mx4[0];
        float m0 = sum.x*(1.0f/LL), m1 = sum.y*(1.0f/LL), m2 = sum.z*(1.0f/LL), m3 = sum.w*(1.0f/LL);
        mean[b*4+0]=m0; mean[b*4+1]=m1; mean[b*4+2]=m2; mean[b*4+3]=m3;
        float a0 = fmaxf(mx.x - m0, m0 - mn.x);
        float a1 = fmaxf(mx.y - m1, m1 - mn.y);
        float a2 = fmaxf(mx.z - m2, m2 - mn.z);
        float a3 = fmaxf(mx.w - m3, m3 - mn.w);
        invmax[b] = 1.0f / fmaxf(fmaxf(a0, a1), fmaxf(a2, a3));
    }
}

// ---------- A-normalize: reflect-padded normalized bf16 hi/lo planes Ahi/Alo[b][c][NPAD] ----------
__global__ __launch_bounds__(256) void k_anorm(const float* __restrict__ in,
        const float* __restrict__ mean, const float* __restrict__ invmax,
        short* __restrict__ Ahi, short* __restrict__ Alo){
    int gid = blockIdx.x*256 + threadIdx.x;
    if (gid >= BB*CC*(NPAD/8)) return;
    int p8 = gid % (NPAD/8);
    int bc = gid / (NPAD/8);
    int b = bc >> 2;
    float mc = mean[bc];
    float iv = invmax[b];
    const float* px = in + (size_t)b*LL*CC + (bc & 3);
    bf16x8 h8, l8;
    #pragma unroll
    for (int j = 0; j < 8; ++j){
        int p = p8*8 + j - 160;
        int m2 = p < 0 ? -p : (p >= LL ? 2*LL - 2 - p : p);
        float v = (px[(size_t)m2*CC] - mc) * iv;
        __hip_bfloat16 h = __float2bfloat16(v);
        float r = v - __bfloat162float(h);
        __hip_bfloat16 l = __float2bfloat16(r);
        short hs, ls; __builtin_memcpy(&hs, &h, 2); __builtin_memcpy(&ls, &l, 2);
        h8[j] = hs; l8[j] = ls;
    }
    size_t o = (size_t)bc*NPAD + (size_t)p8*8;
    *(bf16x8*)&Ahi[o] = h8;
    *(bf16x8*)&Alo[o] = l8;
}

// ---------- STFT as MFMA GEMM, R14: barrier-free direct-global fragment gather ----------
// rows=(b,t,c), cols=(k,ri). Each lane loads its MFMA fragment straight from global:
// every fragment slice is a full 64B-aligned cacheline (quad*16B within a 64B row
// segment), so the gather has zero over-fetch; A hits L2 (reused 6x by col-blocks),
// B hits L1/L2 (reused by all 512 row-blocks). No LDS staging, no K-loop barriers:
// waves free-run, the compiler pipelines loads across kt (no vmcnt(0) convoy).
// S out layout: complex S[b][k][t][c], c fastest (two float4 per (b,k,t))
__global__ __launch_bounds__(256) void k_gstft(const short* __restrict__ Ahi, const short* __restrict__ Alo,
        const short* __restrict__ Bts, float* __restrict__ S){
    __shared__ float Ct[64*66];              // epilogue transpose only (16.9 KB)
    int tid = threadIdx.x;
    int row0 = blockIdx.x*64;                // over b*TP*CC rows
    int col0 = blockIdx.y*64;
    int b  = row0 >> 12;                     // TP*CC = 4096 rows per batch
    int t0 = (row0 & 4095) >> 2;
    if (t0 >= TT) return;                    // fully-padded row-block (t0==1008): skip
    int wave = tid >> 6, lane = tid & 63;
    int wm = wave >> 1, wn = wave & 1;
    int l15 = lane & 15, quad = lane >> 4;
    // A fragment rows r = wm*32 + l15 (+16): tloc = t0 + (r>>2), c = r&3.
    // Clamp out-of-range tloc to last valid frame: reads stay in initialized data;
    // garbage rows feed only their own (unstored) output rows.
    int r0 = wm*32 + l15;
    int r1 = r0 + 16;
    int tl0 = t0 + (r0 >> 2); if (tl0 >= TT) tl0 = TT - 1;
    int tl1 = t0 + (r1 >> 2); if (tl1 >= TT) tl1 = TT - 1;
    size_t oa0 = (size_t)(b*4 + (r0 & 3))*NPAD + (size_t)tl0*160 + quad*8;
    size_t oa1 = (size_t)(b*4 + (r1 & 3))*NPAD + (size_t)tl1*160 + quad*8;
    const short* pa0h = Ahi + oa0;
    const short* pa0l = Alo + oa0;
    const short* pa1h = Ahi + oa1;
    const short* pa1l = Alo + oa1;
    const short* pb0 = Bts + (size_t)(col0 + wn*32 + l15)*640 + quad*8;
    const short* pb1 = Bts + (size_t)(col0 + wn*32 + 16 + l15)*640 + quad*8;
    f32x4 acc00 = {0.f,0.f,0.f,0.f}, acc01 = acc00, acc10 = acc00, acc11 = acc00;
    #pragma unroll 2
    for (int kt = 0; kt < 10; ++kt){
        int k0 = kt*32;
        bf16x8 a0h = *(const bf16x8*)(pa0h + k0);
        bf16x8 a1h = *(const bf16x8*)(pa1h + k0);
        bf16x8 a0l = *(const bf16x8*)(pa0l + k0);
        bf16x8 a1l = *(const bf16x8*)(pa1l + k0);
        bf16x8 b0h = *(const bf16x8*)(pb0 + k0);
        bf16x8 b1h = *(const bf16x8*)(pb1 + k0);
        bf16x8 b0l = *(const bf16x8*)(pb0 + 320 + k0);
        bf16x8 b1l = *(const bf16x8*)(pb1 + 320 + k0);
        acc00 = __builtin_amdgcn_mfma_f32_16x16x32_bf16(a0h, b0h, acc00, 0, 0, 0);
        acc01 = __builtin_amdgcn_mfma_f32_16x16x32_bf16(a0h, b1h, acc01, 0, 0, 0);
        acc10 = __builtin_amdgcn_mfma_f32_16x16x32_bf16(a1h, b0h, acc10, 0, 0, 0);
        acc11 = __builtin_amdgcn_mfma_f32_16x16x32_bf16(a1h, b1h, acc11, 0, 0, 0);
        acc00 = __builtin_amdgcn_mfma_f32_16x16x32_bf16(a0l, b0h, acc00, 0, 0, 0);
        acc01 = __builtin_amdgcn_mfma_f32_16x16x32_bf16(a0l, b1h, acc01, 0, 0, 0);
        acc10 = __builtin_amdgcn_mfma_f32_16x16x32_bf16(a1l, b0h, acc10, 0, 0, 0);
        acc11 = __builtin_amdgcn_mfma_f32_16x16x32_bf16(a1l, b1h, acc11, 0, 0, 0);
        acc00 = __builtin_amdgcn_mfma_f32_16x16x32_bf16(a0h, b0l, acc00, 0, 0, 0);
        acc01 = __builtin_amdgcn_mfma_f32_16x16x32_bf16(a0h, b1l, acc01, 0, 0, 0);
        acc10 = __builtin_amdgcn_mfma_f32_16x16x32_bf16(a1h, b0l, acc10, 0, 0, 0);
        acc11 = __builtin_amdgcn_mfma_f32_16x16x32_bf16(a1h, b1l, acc11, 0, 0, 0);
    }
    // epilogue: LDS transpose, out in S layout. Per-wave Ct regions are disjoint:
    // no barrier needed before the writes, one barrier before cross-wave readout.
    #pragma unroll
    for (int r = 0; r < 4; ++r){
        int rl = wm*32 + quad*4 + r;       // channel = r (rl & 3 == r)
        Ct[rl*66 + wn*32 + l15]           = acc00[r];
        Ct[rl*66 + wn*32 + l15 + 16]      = acc01[r];
        Ct[(rl+16)*66 + wn*32 + l15]      = acc10[r];
        Ct[(rl+16)*66 + wn*32 + l15 + 16] = acc11[r];
    }
    __syncthreads();
    int tl = tid & 15, h = (tid >> 4) & 1, kq = tid >> 5;
    int t = t0 + tl;
    if (t < TT){
        float4* S4 = (float4*)S;
        for (int kk = kq; kk < 32; kk += 8){
            int kg = (col0 >> 1) + kk;
            if (kg < FB){
                float2 e0 = *(float2*)&Ct[(tl*4 + 2*h)*66 + 2*kk];
                float2 e1 = *(float2*)&Ct[(tl*4 + 2*h + 1)*66 + 2*kk];
                S4[((size_t)(b*FB + kg)*TT + t)*2 + h] = make_float4(e0.x, e0.y, e1.x, e1.y);
            }
        }
    }
}

// covariance recurrence update: R = a*R + wg*outer(X), a/wg handle first-frame
#define UPD(first) do{ \
    float aa = (first) ? 0.f : 0.05f; float wg = (first) ? 1.f : 0.95f; \
    float y0x=wg*x0.x, y0y=wg*x0.y, y1x=wg*x1.x, y1y=wg*x1.y; \
    float y2x=wg*x2.x, y2y=wg*x2.y, y3x=wg*x3.x, y3y=wg*x3.y; \
    d0 = aa*d0 + y0x*x0.x + y0y*x0.y; \
    d1 = aa*d1 + y1x*x1.x + y1y*x1.y; \
    d2 = aa*d2 + y2x*x2.x + y2y*x2.y; \
    d3 = aa*d3 + y3x*x3.x + y3y*x3.y; \
    r10.x = aa*r10.x + y1x*x0.x + y1y*x0.y;  r10.y = aa*r10.y + y1y*x0.x - y1x*x0.y; \
    r20.x = aa*r20.x + y2x*x0.x + y2y*x0.y;  r20.y = aa*r20.y + y2y*x0.x - y2x*x0.y; \
    r30.x = aa*r30.x + y3x*x0.x + y3y*x0.y;  r30.y = aa*r30.y + y3y*x0.x - y3x*x0.y; \
    r21.x = aa*r21.x + y2x*x1.x + y2y*x1.y;  r21.y = aa*r21.y + y2y*x1.x - y2x*x1.y; \
    r31.x = aa*r31.x + y3x*x1.x + y3y*x1.y;  r31.y = aa*r31.y + y3y*x1.x - y3x*x1.y; \
    r32.x = aa*r32.x + y3x*x2.x + y3y*x2.y;  r32.y = aa*r32.y + y3y*x2.x - y3x*x2.y; \
}while(0)

// ---------- LDS-staged chunked scan, half-strip, CH=2 x 256 threads, 4-frame warm-up ----------
// Warm-up frames below tbase (threads 0..1) come straight from gmem.
// Division/sqrt-free Schur-adjugate solve (scale-invariance of s). S1/S2 layout: complex [b][f][t]
__global__ __launch_bounds__(256) void k_scan(const float* __restrict__ S, const float* __restrict__ htab,
                      float* __restrict__ S1, float* __restrict__ S2){
    __shared__ float4 tile[1008];     // 16,128 B: swizzled [tbase,te) strip; reused as output buffer
    int bid = blockIdx.x;
    int half = bid & 1;
    int bf = bid >> 1;                // b*FB + f
    int f  = bf % FB;
    int tid = threadIdx.x;
    int tbase = half*SCH;
    int te  = tbase + SCH; if (te > TT) te = TT;
    int nst = 2*(te - tbase);
    const float4* Sg = (const float4*)S + (size_t)bf*TT*2;
    const float4* Sp = Sg + (size_t)tbase*2;
    for (int i = tid; i < nst; i += 256)
        tile[i ^ ((i>>4)&7)] = Sp[i];                    // coalesced gmem read, swizzled LDS write
    __syncthreads();
    float2 out1[CH], out2[CH];
    int t0 = tbase + tid*CH;
    bool act = (tid*CH < SCH) && (t0 < TT);
    if (act){
        const float2* hp = (const float2*)htab;
        float2 ha0 = hp[f*4+0], ha1 = hp[f*4+1], ha2 = hp[f*4+2], ha3 = hp[f*4+3];
        float2 hb0 = hp[(FB+f)*4+0], hb1 = hp[(FB+f)*4+1], hb2 = hp[(FB+f)*4+2], hb3 = hp[(FB+f)*4+3];
        float d0=0,d1=0,d2=0,d3=0;
        float2 r10={0,0}, r20={0,0}, r30={0,0}, r21={0,0}, r31={0,0}, r32={0,0};
        int ts = t0 - KWARM; if (ts < 0) ts = 0;
        for (int tau = ts; tau < t0; ++tau){
            float4 v0, v1;
            if (tau >= tbase){
                int i0 = 2*(tau - tbase);
                v0 = tile[i0 ^ ((i0>>4)&7)];
                v1 = tile[(i0+1) ^ ((i0>>4)&7)];
            } else {
                v0 = Sg[2*tau];
                v1 = Sg[2*tau + 1];
            }
            float2 x0 = make_float2(v0.x, v0.y), x1 = make_float2(v0.z, v0.w);
            float2 x2 = make_float2(v1.x, v1.y), x3 = make_float2(v1.z, v1.w);
            UPD(tau == 0);
        }
        for (int j = 0; j < CH; ++j){
            int t = t0 + j;
            if (t >= TT) break;
            int i0 = 2*(t - tbase);
            float4 v0 = tile[i0 ^ ((i0>>4)&7)];
            float4 v1 = tile[(i0+1) ^ ((i0>>4)&7)];
            float2 x0 = make_float2(v0.x, v0.y), x1 = make_float2(v0.z, v0.w);
            float2 x2 = make_float2(v1.x, v1.y), x3 = make_float2(v1.z, v1.w);
            UPD(t == 0);
            float trc = d0 + d1 + d2 + d3;
            float lam = trc * 0.25f;
            float e0 = d0 + lam, e1 = d1 + lam, e2 = d2 + lam, e3 = d3 + lam;
            float detP = e0*e1 - (r10.x*r10.x + r10.y*r10.y);
            float2 w00 = csub(cscale(r20, e1), cmulf(r10, r21));
            float2 w01 = csub(cscale(r30, e1), cmulf(r10, r31));
            float2 w10 = csub(cscale(r21, e0), cjmul(r10, r20));
            float2 w11 = csub(cscale(r31, e0), cjmul(r10, r30));
            float2 va = cjmul(r30, w00), vb = cjmul(r31, w10);
            float2 V10 = make_float2(va.x + vb.x, -(va.y + vb.y));
            float reV00 = r20.x*w00.x + r20.y*w00.y + r21.x*w10.x + r21.y*w10.y;
            float reV11 = r30.x*w01.x + r30.y*w01.y + r31.x*w11.x + r31.y*w11.y;
            float t00 = detP*e2 - reV00;
            float t11 = detP*e3 - reV11;
            float2 t10 = csub(cscale(r32, detP), V10);
            float detT = t00*t11 - (t10.x*t10.x + t10.y*t10.y);
            #pragma unroll
            for (int m = 0; m < 2; ++m){
                float2 h0 = m ? hb0 : ha0;
                float2 h1 = m ? hb1 : ha1;
                float2 h2 = m ? hb2 : ha2;
                float2 h3 = m ? hb3 : ha3;
                float2 g0 = csub(cscale(h0, e1), cjmul(r10, h1));
                float2 g1 = csub(cscale(h1, e0), cmulf(r10, h0));
                float2 ta = cmulf(r20, g0), tb = cmulf(r21, g1);
                float2 hh0 = make_float2(detP*h2.x - ta.x - tb.x, detP*h2.y - ta.y - tb.y);
                ta = cmulf(r30, g0); tb = cmulf(r31, g1);
                float2 hh1 = make_float2(detP*h3.x - ta.x - tb.x, detP*h3.y - ta.y - tb.y);
                float2 y20 = csub(cscale(hh0, t11), cjmul(t10, hh1));
                float2 y21 = csub(cscale(hh1, t00), cmulf(t10, hh0));
                float2 u20 = cscale(y20, detP), u21 = cscale(y21, detP);
                ta = cmulcj(y20, r20); tb = cmulcj(y21, r30);
                float2 q0 = make_float2(detT*h0.x - ta.x - tb.x, detT*h0.y - ta.y - tb.y);
                ta = cmulcj(y20, r21); tb = cmulcj(y21, r31);
                float2 q1 = make_float2(detT*h1.x - ta.x - tb.x, detT*h1.y - ta.y - tb.y);
                float2 u10 = csub(cscale(q0, e1), cjmul(r10, q1));
                float2 u11 = csub(cscale(q1, e0), cmulf(r10, q0));
                float2 den = cjmul(h0, u10), tmp;
                tmp = cjmul(h1, u11); den.x += tmp.x; den.y += tmp.y;
                tmp = cjmul(h2, u20); den.x += tmp.x; den.y += tmp.y;
                tmp = cjmul(h3, u21); den.x += tmp.x; den.y += tmp.y;
                float2 num = cjmul(u10, x0);
                tmp = cjmul(u11, x1); num.x += tmp.x; num.y += tmp.y;
                tmp = cjmul(u20, x2); num.x += tmp.x; num.y += tmp.y;
                tmp = cjmul(u21, x3); num.x += tmp.x; num.y += tmp.y;
                float2 s = cdivf(num, make_float2(den.x, -den.y));
                if (m) out2[j] = s; else out1[j] = s;
            }
        }
    }
    __syncthreads();                      // all tile reads done -> reuse as output buffers
    float2* o1 = (float2*)tile;           // [0..511]
    float2* o2 = ((float2*)tile) + 528;   // [528..1039] (ends at float4 520 <= 1008)
    if (act){
        for (int j = 0; j < CH && t0 + j < TT; ++j){
            int lt = t0 - tbase + j;
            int iw = lt ^ ((lt>>3)&7);    // bank-spread write
            o1[iw] = out1[j];
            o2[iw] = out2[j];
        }
    }
    __syncthreads();
    int nout = te - tbase;
    float2* S1g = (float2*)S1 + (size_t)bf*TT + tbase;
    float2* S2g = (float2*)S2 + (size_t)bf*TT + tbase;
    for (int i = tid; i < nout; i += 256){
        int ir = i ^ ((i>>3)&7);
        S1g[i] = o1[ir];
        S2g[i] = o2[ir];
    }
}

// ---------- pack v2 (R8-verified): coalesced LDS transpose. block = (rb, 32-t tile) ----------
__global__ __launch_bounds__(256) void k_pack(const float* __restrict__ S1, const float* __restrict__ S2,
                                              short* __restrict__ A){
    __shared__ short tile[32*708];        // 45,312 B; row = t-in-tile, col = kk (hi 0..351 | lo 352..703)
    int bid = blockIdx.x;                 // rb*32 + tb
    int tb = bid & 31, rb = bid >> 5;
    int t0 = tb*32;
    int beam = rb >> 3, b = rb & 7;
    const float2* Sp = (const float2*)(beam ? S2 : S1) + (size_t)b*FB*TT;
    int tid = threadIdx.x;
    for (int idx = tid; idx < 32*176; idx += 256){
        int bin = idx >> 5, tq = idx & 31;
        int t = t0 + tq;
        float2 s = make_float2(0.f, 0.f);
        if (bin < FB && t < TT) s = Sp[(size_t)bin*TT + t];
        int c0 = 2*bin;
        tile[tq*708 + c0]            = bf_hi(s.x);
        tile[tq*708 + c0 + 1]        = bf_hi(s.y);
        tile[tq*708 + KSEC + c0]     = bf_lo(s.x);
        tile[tq*708 + KSEC + c0 + 1] = bf_lo(s.y);
    }
    __syncthreads();
    for (int idx = tid; idx < 32*176; idx += 256){
        int tq = idx / 176, k4 = idx % 176;
        int t = t0 + tq;
        if (t < TT)
            *(short4*)&A[(size_t)(rb*TT + t)*LDK + k4*4] = *(short4*)&tile[tq*708 + k4*4];
    }
}

// ---------- irfft MFMA GEMM, R14: barrier-free direct-global fragment gather ----------
// frames[GM,320] = 3-segment bf16 split product. Zero LDS, zero barriers: each lane
// gathers 64B-aligned fragment lines; Bt (450 KB) is L1/L2-resident across all 251
// row-blocks, A is streamed/L2 (reused by 5 col-blocks).
__global__ __launch_bounds__(256) void k_gemm(const short* __restrict__ A, const short* __restrict__ Bt,
                                              float* __restrict__ C){
    int tid = threadIdx.x;
    int row0 = blockIdx.x * 64;
    int col0 = blockIdx.y * 64;
    int wave = tid >> 6, lane = tid & 63;
    int wm = wave >> 1, wn = wave & 1;
    int l15 = lane & 15, quad = lane >> 4;
    int gr0 = row0 + wm*32 + l15;      if (gr0 >= GM) gr0 = GM - 1;   // clamp: reads stay
    int gr1 = row0 + wm*32 + 16 + l15; if (gr1 >= GM) gr1 = GM - 1;   // in-bounds, stores guarded
    const short* pa0 = A + (size_t)gr0*LDK + quad*8;
    const short* pa1 = A + (size_t)gr1*LDK + quad*8;
    const short* pb0 = Bt + (size_t)(col0 + wn*32 + l15)*LDK + quad*8;
    const short* pb1 = Bt + (size_t)(col0 + wn*32 + 16 + l15)*LDK + quad*8;
    f32x4 acc00 = {0.f,0.f,0.f,0.f}, acc01 = acc00, acc10 = acc00, acc11 = acc00;
    #pragma unroll
    for (int seg = 0; seg < 3; ++seg){
        int aofs = (seg == 1) ? KSEC : 0;
        int bofs = (seg == 2) ? KSEC : 0;
        #pragma unroll 2
        for (int kt = 0; kt < KT; ++kt){
            int ka = aofs + kt*32;
            int kb = bofs + kt*32;
            bf16x8 a0 = *(const bf16x8*)(pa0 + ka);
            bf16x8 a1 = *(const bf16x8*)(pa1 + ka);
            bf16x8 b0 = *(const bf16x8*)(pb0 + kb);
            bf16x8 b1 = *(const bf16x8*)(pb1 + kb);
            acc00 = __builtin_amdgcn_mfma_f32_16x16x32_bf16(a0, b0, acc00, 0, 0, 0);
            acc01 = __builtin_amdgcn_mfma_f32_16x16x32_bf16(a0, b1, acc01, 0, 0, 0);
            acc10 = __builtin_amdgcn_mfma_f32_16x16x32_bf16(a1, b0, acc10, 0, 0, 0);
            acc11 = __builtin_amdgcn_mfma_f32_16x16x32_bf16(a1, b1, acc11, 0, 0, 0);
        }
    }
    for (int r = 0; r < 4; ++r){
        int orow0 = row0 + wm*32 + quad*4 + r;
        int ocol0 = col0 + wn*32 + l15;
        if (orow0 < GM){
            C[(size_t)orow0*NFFT + ocol0]      = acc00[r];
            C[(size_t)orow0*NFFT + ocol0 + 16] = acc01[r];
        }
        if (orow0 + 16 < GM){
            C[(size_t)(orow0+16)*NFFT + ocol0]      = acc10[r];
            C[(size_t)(orow0+16)*NFFT + ocol0 + 16] = acc11[r];
        }
    }
}

// ---------- overlap-add, float4: 4 outputs/thread (wsum==2 in cropped interior) ----------
__global__ __launch_bounds__(256) void k_ola(const float* __restrict__ frames, float* __restrict__ out){
    int gid = blockIdx.x*256 + threadIdx.x;
    if (gid >= 2*BB*(LL/4)) return;
    int o4 = (gid % (LL/4))*4;
    int rb = gid / (LL/4);                 // beam*BB + b
    int i  = o4 + HOP;                     // mult of 4; r in {0,4,...,156}
    int t1 = i / HOP;
    int r  = i - t1*HOP;
    const float4* fb = (const float4*)(frames + (size_t)rb*TT*NFFT);
    float4 a = fb[(t1*NFFT + r) >> 2];
    float4 b = fb[((t1-1)*NFFT + r + HOP) >> 2];
    ((float4*)out)[gid] = make_float4(0.5f*(a.x+b.x), 0.5f*(a.y+b.y), 0.5f*(a.z+b.z), 0.5f*(a.w+b.w));
}

extern "C" void kernel_launch(void* const* d_in, const int* in_sizes, int n_in,
                              void* d_out, int out_size, void* d_ws, size_t ws_size,
                              hipStream_t stream){
    const float* in  = (const float*)d_in[0];   // [B, L, C] fp32
    const float* win = (const float*)d_in[1];   // [320] fp32
    float* ws = (float*)d_ws;
    // ws (floats): mean 32 | invmax 8 | htab 2576 | pad -> header 3072
    //              | S1 (2,578,576) | S2 (2,578,576) | S (10,314,304)   total ~62 MB
    // aliases: part -> S1 head (dead before k_anorm); Ahi/Alo -> S1+S2 (dead after k_gstft);
    //          Bts + Bt -> head of d_out (dead until k_ola fully overwrites; NOT in S — R13 bug);
    //          A_ir -> S (post-scan); frames -> S1/S2 (post-pack)
    float* mean   = ws;
    float* invmax = ws + 32;
    float* htab   = ws + 48;
    float* S1     = ws + 3072;
    size_t nS1 = (size_t)2*BB*FB*TT;            // 2,578,576 floats
    float* S2 = S1 + nS1;
    float* S  = S2 + nS1;                       // 10,314,304 floats
    float* part = S1;
    short* Ahi = (short*)S1;                    // 8*4*160320 = 5,130,240 shorts
    short* Alo = Ahi + (size_t)BB*CC*NPAD;      // total 10,260,480 shorts <= S1+S2 (10,314,304 short-equiv)
    short* Bts = (short*)d_out;                 // 245,760 shorts (= 122,880 floats)
    short* Bt  = (short*)((float*)d_out + 131072); // 225,280 shorts at float-offset 131072 (16B aligned)
    short* A  = (short*)S;                      // irfft A: 16016*704 bf16
    float* frames = S1;                         // 16016*320 floats over dead S1+S2

    int ngen = 2*FB*CC + 384*640 + NFFT*LDK;    // fused table generation
    k_gen<<<dim3((ngen + 255)/256), dim3(256), 0, stream>>>(win, htab, Bts, Bt);
    k_stats1<<<dim3(BB*RBLK), dim3(256), 0, stream>>>(in, part);
    k_stats2<<<dim3(BB), dim3(128), 0, stream>>>(part, mean, invmax);
    k_anorm<<<dim3((BB*CC*(NPAD/8) + 255)/256), dim3(256), 0, stream>>>(in, mean, invmax, Ahi, Alo);
    k_gstft<<<dim3(BB*TP*CC/64, 6), dim3(256), 0, stream>>>(Ahi, Alo, Bts, S);
    k_scan<<<dim3(2*BB*FB), dim3(256), 0, stream>>>(S, htab, S1, S2);
    k_pack<<<dim3(512), dim3(256), 0, stream>>>(S1, S2, A);
    k_gemm<<<dim3((GM + 63)/64, NFFT/64), dim3(256), 0, stream>>>(A, Bt, frames);
    k_ola<<<dim3((2*BB*(LL/4) + 255)/256), dim3(256), 0, stream>>>(frames, (float*)d_out);
}

// Round 2
// 220.804 us; speedup vs baseline: 1.4118x; 1.4118x over previous
//
#include <hip/hip_runtime.h>
#include <hip/hip_bf16.h>
#include <math.h>

#define BB 8
#define LL 160000
#define CC 4
#define NFFT 320
#define HOP 160
#define FB 161          // rfft bins
#define TT 1001         // frames
#define TP 1024         // padded frames per batch (t-slots) for STFT GEMM
#define RBLK 128        // stats blocks per batch
#define PI_D 3.14159265358979323846
#define NPAD 160320     // reflect-padded samples per (b,c): p in [-160, 160159]

#define CH 2            // scan t-chunk per thread (CH=2 + 256-thread blocks)
#define SCH 504         // scan outputs per half-block (2 halves cover 1001)
#define KWARM 4         // warm-up frames; tail weight 0.05^5 ~ 3e-7 rel << bf16 error floor (4.9e-4)

#define GM 16016        // irfft GEMM M = 2*BB*TT rows (beam,b,t)
#define KSEC 352        // irfft padded K per split-section (322 used)
#define LDK 704         // irfft A/Bt leading dim = 2 sections
#define KT 11           // irfft K-tiles of 32 per section
// R15: 2-phase double-buffered global_load_lds staging (T3 minimum recipe + m193's
// width-16 DMA). One barrier per K-step (was 2); prefetch kt+1 issued before the
// compute phase of kt so the barrier's implicit vmcnt(0) drain waits on a load that
// had the whole MFMA phase to land. global_load_lds writes linearly (rule #21), so
// LDS rows are 64B-linear with a both-sides XOR swizzle: slot' = quad ^ ((row>>1)&3),
// applied as pre-swizzled per-lane GLOBAL source + swizzled ds_read. Gives uniform
// 2 lanes/bank (the wave64 minimum) on ds_read_b128.
// R14 lesson (direct-global gather, 47->115us): LDS staging is a latency-decoupling
// pipeline, not just a cache — do not remove it.
// LIFETIME NOTE (R13 bug): Bt/Bts must NOT live in the S region — k_gstft overwrites
// ALL of S. Both live in d_out's head (dead until k_ola fully overwrites at the end).

typedef __attribute__((ext_vector_type(8))) short bf16x8;
typedef __attribute__((ext_vector_type(4))) float f32x4;

__device__ __forceinline__ void ldsdma16(const short* g, short* l){
    // wave-level DMA: per-lane global src, wave-uniform LDS base + lane*16B
    __builtin_amdgcn_global_load_lds((const __attribute__((address_space(1))) void*)g,
                                     (__attribute__((address_space(3))) void*)l, 16, 0, 0);
}

__device__ __forceinline__ float2 cmulf(float2 a, float2 b){           // a*b
    return make_float2(a.x*b.x - a.y*b.y, a.x*b.y + a.y*b.x);
}
__device__ __forceinline__ float2 cmulcj(float2 a, float2 b){          // a*conj(b)
    return make_float2(a.x*b.x + a.y*b.y, a.y*b.x - a.x*b.y);
}
__device__ __forceinline__ float2 cjmul(float2 a, float2 b){           // conj(a)*b
    return make_float2(a.x*b.x + a.y*b.y, a.x*b.y - a.y*b.x);
}
__device__ __forceinline__ float2 csub(float2 a, float2 b){ return make_float2(a.x-b.x, a.y-b.y); }
__device__ __forceinline__ float2 cscale(float2 a, float s){ return make_float2(a.x*s, a.y*s); }
__device__ __forceinline__ float2 cdivf(float2 a, float2 b){           // a/b
    float inv = 1.0f/(b.x*b.x + b.y*b.y);
    return make_float2((a.x*b.x + a.y*b.y)*inv, (a.y*b.x - a.x*b.y)*inv);
}
__device__ __forceinline__ short bf_hi(float v){
    __hip_bfloat16 h = __float2bfloat16(v);
    short s; __builtin_memcpy(&s, &h, 2); return s;
}
__device__ __forceinline__ short bf_lo(float v){
    __hip_bfloat16 h = __float2bfloat16(v);
    float r = v - __bfloat162float(h);
    __hip_bfloat16 l = __float2bfloat16(r);
    short s; __builtin_memcpy(&s, &l, 2); return s;
}

// ---------- fused table generator: htab | Bts (STFT B) | Bt (irfft B) ----------
__global__ void k_gen(const float* __restrict__ win, float* __restrict__ htab,
                      short* __restrict__ Bts, short* __restrict__ Bt){
    int gid = blockIdx.x*256 + threadIdx.x;
    if (gid < 2*FB*CC){
        int i = gid;
        int c = i & 3;
        int k = (i >> 2) % FB;
        int m = i / (FB*CC);
        double coef = 2.0*PI_D*50.0*0.027*sin(40.0*PI_D/180.0)/340.0;
        double sgn = (m == 0) ? -1.0 : 1.0;
        double ph = sgn*coef*(double)k*(double)c;
        double s, c2;
        sincos(ph, &s, &c2);
        ((float2*)htab)[i] = make_float2((float)c2, (float)s);
        return;
    }
    gid -= 2*FB*CC;
    if (gid < 384*640){
        int col = gid / 640, kk = gid % 640;
        int n = (kk >= 320) ? kk - 320 : kk;
        int sec = (kk >= 320) ? 1 : 0;
        float v = 0.f;
        if (col < 2*FB){
            int k = col >> 1;
            double th = 2.0*PI_D*(double)k*(double)n/320.0;
            double s, co; sincos(th, &s, &co);
            double tw = (col & 1) ? -s : co;
            v = (float)((double)win[n]*tw);
        }
        Bts[gid] = sec ? bf_lo(v) : bf_hi(v);
        return;
    }
    gid -= 384*640;
    if (gid < NFFT*LDK){
        int n = gid / LDK, kk = gid % LDK;
        int sec = (kk >= KSEC) ? 1 : 0;
        int kk2 = kk - (sec ? KSEC : 0);
        float v = 0.f;
        if (kk2 < 2*FB){
            int bin = kk2 >> 1;
            double c = ((bin == 0 || bin == 160) ? 1.0 : 2.0) / 320.0;
            double th = 2.0*PI_D*(double)bin*(double)n/320.0;
            double s, co; sincos(th, &s, &co);
            v = (float)((kk2 & 1) ? -c*s : c*co);
        }
        Bt[(size_t)n*LDK + kk] = sec ? bf_lo(v) : bf_hi(v);
    }
}

// ---------- stage 1: per-(b,chunk) partial {sum4, min4, max4} ----------
__global__ __launch_bounds__(256) void k_stats1(const float* __restrict__ in, float* __restrict__ part){
    __shared__ float4 s4[256];
    __shared__ float4 mn4[256];
    __shared__ float4 mx4[256];
    int b = blockIdx.x / RBLK, chunk = blockIdx.x % RBLK;
    int tid = threadIdx.x;
    const float4* p = (const float4*)(in + (size_t)b*LL*CC);
    const int per = LL / RBLK;
    int start = chunk*per;
    float4 s  = make_float4(0.f,0.f,0.f,0.f);
    float4 mn = make_float4( 3.4e38f, 3.4e38f, 3.4e38f, 3.4e38f);
    float4 mx = make_float4(-3.4e38f,-3.4e38f,-3.4e38f,-3.4e38f);
    for (int i = start + tid; i < start + per; i += 256){
        float4 v = p[i];
        s.x += v.x; s.y += v.y; s.z += v.z; s.w += v.w;
        mn.x = fminf(mn.x, v.x); mn.y = fminf(mn.y, v.y); mn.z = fminf(mn.z, v.z); mn.w = fminf(mn.w, v.w);
        mx.x = fmaxf(mx.x, v.x); mx.y = fmaxf(mx.y, v.y); mx.z = fmaxf(mx.z, v.z); mx.w = fmaxf(mx.w, v.w);
    }
    s4[tid] = s; mn4[tid] = mn; mx4[tid] = mx;
    __syncthreads();
    for (int st = 128; st >= 1; st >>= 1){
        if (tid < st){
            float4 a = s4[tid], c = s4[tid+st];
            s4[tid] = make_float4(a.x+c.x, a.y+c.y, a.z+c.z, a.w+c.w);
            float4 d = mn4[tid], e = mn4[tid+st];
            mn4[tid] = make_float4(fminf(d.x,e.x), fminf(d.y,e.y), fminf(d.z,e.z), fminf(d.w,e.w));
            float4 f = mx4[tid], g = mx4[tid+st];
            mx4[tid] = make_float4(fmaxf(f.x,g.x), fmaxf(f.y,g.y), fmaxf(f.z,g.z), fmaxf(f.w,g.w));
        }
        __syncthreads();
    }
    if (tid == 0){
        float* dst = part + (size_t)(b*RBLK + chunk)*12;
        float4 a = s4[0], d = mn4[0], f = mx4[0];
        dst[0]=a.x; dst[1]=a.y; dst[2]=a.z; dst[3]=a.w;
        dst[4]=d.x; dst[5]=d.y; dst[6]=d.z; dst[7]=d.w;
        dst[8]=f.x; dst[9]=f.y; dst[10]=f.z; dst[11]=f.w;
    }
}

// ---------- stage 2: finalize mean + invmax per batch ----------
__global__ __launch_bounds__(128) void k_stats2(const float* __restrict__ part,
                                                float* __restrict__ mean, float* __restrict__ invmax){
    __shared__ float4 s4[128];
    __shared__ float4 mn4[128];
    __shared__ float4 mx4[128];
    int b = blockIdx.x, tid = threadIdx.x;
    const float* src = part + (size_t)(b*RBLK + tid)*12;
    s4[tid]  = make_float4(src[0], src[1], src[2], src[3]);
    mn4[tid] = make_float4(src[4], src[5], src[6], src[7]);
    mx4[tid] = make_float4(src[8], src[9], src[10], src[11]);
    __syncthreads();
    for (int st = 64; st >= 1; st >>= 1){
        if (tid < st){
            float4 a = s4[tid], c = s4[tid+st];
            s4[tid] = make_float4(a.x+c.x, a.y+c.y, a.z+c.z, a.w+c.w);
            float4 d = mn4[tid], e = mn4[tid+st];
            mn4[tid] = make_float4(fminf(d.x,e.x), fminf(d.y,e.y), fminf(d.z,e.z), fminf(d.w,e.w));
            float4 f = mx4[tid], g = mx4[tid+st];
            mx4[tid] = make_float4(fmaxf(f.x,g.x), fmaxf(f.y,g.y), fmaxf(f.z,g.z), fmaxf(f.w,g.w));
        }
        __syncthreads();
    }
    if (tid == 0){
        float4 sum = s4[0], mn = mn4[0], mx = mx4[0];
        float m0 = sum.x*(1.0f/LL), m1 = sum.y*(1.0f/LL), m2 = sum.z*(1.0f/LL), m3 = sum.w*(1.0f/LL);
        mean[b*4+0]=m0; mean[b*4+1]=m1; mean[b*4+2]=m2; mean[b*4+3]=m3;
        float a0 = fmaxf(mx.x - m0, m0 - mn.x);
        float a1 = fmaxf(mx.y - m1, m1 - mn.y);
        float a2 = fmaxf(mx.z - m2, m2 - mn.z);
        float a3 = fmaxf(mx.w - m3, m3 - mn.w);
        invmax[b] = 1.0f / fmaxf(fmaxf(a0, a1), fmaxf(a2, a3));
    }
}

// ---------- A-normalize: reflect-padded normalized bf16 hi/lo planes Ahi/Alo[b][c][NPAD] ----------
__global__ __launch_bounds__(256) void k_anorm(const float* __restrict__ in,
        const float* __restrict__ mean, const float* __restrict__ invmax,
        short* __restrict__ Ahi, short* __restrict__ Alo){
    int gid = blockIdx.x*256 + threadIdx.x;
    if (gid >= BB*CC*(NPAD/8)) return;
    int p8 = gid % (NPAD/8);
    int bc = gid / (NPAD/8);
    int b = bc >> 2;
    float mc = mean[bc];
    float iv = invmax[b];
    const float* px = in + (size_t)b*LL*CC + (bc & 3);
    bf16x8 h8, l8;
    #pragma unroll
    for (int j = 0; j < 8; ++j){
        int p = p8*8 + j - 160;
        int m2 = p < 0 ? -p : (p >= LL ? 2*LL - 2 - p : p);
        float v = (px[(size_t)m2*CC] - mc) * iv;
        __hip_bfloat16 h = __float2bfloat16(v);
        float r = v - __bfloat162float(h);
        __hip_bfloat16 l = __float2bfloat16(r);
        short hs, ls; __builtin_memcpy(&hs, &h, 2); __builtin_memcpy(&ls, &l, 2);
        h8[j] = hs; l8[j] = ls;
    }
    size_t o = (size_t)bc*NPAD + (size_t)p8*8;
    *(bf16x8*)&Ahi[o] = h8;
    *(bf16x8*)&Alo[o] = l8;
}

// ---------- STFT as MFMA GEMM, R15: 2-phase dbuf global_load_lds staging ----------
// rows=(b,t,c), cols=(k,ri). LDS per buffer: Ah|Al|Bh|Bl, each 64 rows x 32 shorts
// (64B linear rows, DMA-written). Swizzle: LDS slot s of row r holds k-chunk
// s ^ ((r>>1)&3); reader at (row r, chunk quad) reads slot quad ^ ((r>>1)&3).
// S out layout: complex S[b][k][t][c], c fastest (two float4 per (b,k,t))
__global__ __launch_bounds__(256) void k_gstft(const short* __restrict__ Ahi, const short* __restrict__ Alo,
        const short* __restrict__ Bts, float* __restrict__ S){
    __shared__ short stage[16384];           // 32 KB: 2 buffers x (Ah|Al|Bh|Bl) x 2048 shorts
    float* Ct = (float*)stage;               // 64 x 66 floats (16.9 KB) overlays after K-loop
    int tid = threadIdx.x;
    int row0 = blockIdx.x*64;                // over b*TP*CC rows
    int col0 = blockIdx.y*64;
    int b  = row0 >> 12;                     // TP*CC = 4096 rows per batch
    int t0 = (row0 & 4095) >> 2;
    if (t0 >= TT) return;                    // fully-padded row-block (t0==1008): skip
    int wave = tid >> 6, lane = tid & 63;
    int wm = wave >> 1, wn = wave & 1;
    int l15 = lane & 15, quad = lane >> 4;
    // ---- staging addresses (per lane): wave w stages rows w*16..w*16+15 ----
    int rowS  = wave*16 + (lane >> 2);       // staged LDS row 0..63
    int chunk = (lane & 3) ^ ((lane >> 3) & 3);   // pre-swizzled global k-chunk
    int tls = t0 + (rowS >> 2); if (tls >= TT) tls = TT - 1;   // clamp; stores guarded later
    size_t gao = (size_t)(b*4 + (rowS & 3))*NPAD + (size_t)tls*160 + chunk*8;
    const short* gAh = Ahi + gao;
    const short* gAl = Alo + gao;
    const short* gB  = Bts + (size_t)(col0 + rowS)*640 + chunk*8;   // hi; lo at +320
    short* lA = stage + wave*512;            // wave-uniform LDS bases (+buffer offset)
    // ---- read addresses ----
    int sw  = (l15 >> 1) & 3;                // (row>>1)&3 for all 4 row variants
    int c0r = (quad ^ sw) * 8;               // swizzled chunk offset (shorts)
    int ra0 = (wm*32 + l15)*32 + c0r;        // A rows
    int ra1 = (wm*32 + 16 + l15)*32 + c0r;
    int rb0 = (wn*32 + l15)*32 + c0r;        // B rows
    int rb1 = (wn*32 + 16 + l15)*32 + c0r;
    f32x4 acc00 = {0.f,0.f,0.f,0.f}, acc01 = acc00, acc10 = acc00, acc11 = acc00;

    #define STG(kt_, off_) do{ \
        ldsdma16(gAh + (kt_)*32,       lA + (off_));        \
        ldsdma16(gAl + (kt_)*32,       lA + (off_) + 2048); \
        ldsdma16(gB  + (kt_)*32,       lA + (off_) + 4096); \
        ldsdma16(gB  + (kt_)*32 + 320, lA + (off_) + 6144); \
    }while(0)

    STG(0, 0);
    __syncthreads();                         // implicit vmcnt(0): buf0 ready
    int offc = 0;
    #pragma unroll
    for (int kt = 0; kt < 10; ++kt){
        int offn = 8192 - offc;
        if (kt < 9) STG(kt+1, offn);         // prefetch next K-step into alt buffer
        bf16x8 a0h = *(bf16x8*)&stage[offc + ra0];
        bf16x8 a1h = *(bf16x8*)&stage[offc + ra1];
        bf16x8 a0l = *(bf16x8*)&stage[offc + 2048 + ra0];
        bf16x8 a1l = *(bf16x8*)&stage[offc + 2048 + ra1];
        bf16x8 b0h = *(bf16x8*)&stage[offc + 4096 + rb0];
        bf16x8 b1h = *(bf16x8*)&stage[offc + 4096 + rb1];
        bf16x8 b0l = *(bf16x8*)&stage[offc + 6144 + rb0];
        bf16x8 b1l = *(bf16x8*)&stage[offc + 6144 + rb1];
        acc00 = __builtin_amdgcn_mfma_f32_16x16x32_bf16(a0h, b0h, acc00, 0, 0, 0);
        acc01 = __builtin_amdgcn_mfma_f32_16x16x32_bf16(a0h, b1h, acc01, 0, 0, 0);
        acc10 = __builtin_amdgcn_mfma_f32_16x16x32_bf16(a1h, b0h, acc10, 0, 0, 0);
        acc11 = __builtin_amdgcn_mfma_f32_16x16x32_bf16(a1h, b1h, acc11, 0, 0, 0);
        acc00 = __builtin_amdgcn_mfma_f32_16x16x32_bf16(a0l, b0h, acc00, 0, 0, 0);
        acc01 = __builtin_amdgcn_mfma_f32_16x16x32_bf16(a0l, b1h, acc01, 0, 0, 0);
        acc10 = __builtin_amdgcn_mfma_f32_16x16x32_bf16(a1l, b0h, acc10, 0, 0, 0);
        acc11 = __builtin_amdgcn_mfma_f32_16x16x32_bf16(a1l, b1h, acc11, 0, 0, 0);
        acc00 = __builtin_amdgcn_mfma_f32_16x16x32_bf16(a0h, b0l, acc00, 0, 0, 0);
        acc01 = __builtin_amdgcn_mfma_f32_16x16x32_bf16(a0h, b1l, acc01, 0, 0, 0);
        acc10 = __builtin_amdgcn_mfma_f32_16x16x32_bf16(a1h, b0l, acc10, 0, 0, 0);
        acc11 = __builtin_amdgcn_mfma_f32_16x16x32_bf16(a1h, b1l, acc11, 0, 0, 0);
        __syncthreads();                     // drains prefetch (vmcnt 0) + guards buffer reuse
        offc = offn;
    }
    #undef STG
    // epilogue: LDS transpose (Ct overlays stage — all reads drained by loop's last barrier)
    #pragma unroll
    for (int r = 0; r < 4; ++r){
        int rl = wm*32 + quad*4 + r;         // channel = r (rl & 3 == r)
        Ct[rl*66 + wn*32 + l15]           = acc00[r];
        Ct[rl*66 + wn*32 + l15 + 16]      = acc01[r];
        Ct[(rl+16)*66 + wn*32 + l15]      = acc10[r];
        Ct[(rl+16)*66 + wn*32 + l15 + 16] = acc11[r];
    }
    __syncthreads();
    int tl = tid & 15, h = (tid >> 4) & 1, kq = tid >> 5;
    int t = t0 + tl;
    if (t < TT){
        float4* S4 = (float4*)S;
        for (int kk = kq; kk < 32; kk += 8){
            int kg = (col0 >> 1) + kk;
            if (kg < FB){
                float2 e0 = *(float2*)&Ct[(tl*4 + 2*h)*66 + 2*kk];
                float2 e1 = *(float2*)&Ct[(tl*4 + 2*h + 1)*66 + 2*kk];
                S4[((size_t)(b*FB + kg)*TT + t)*2 + h] = make_float4(e0.x, e0.y, e1.x, e1.y);
            }
        }
    }
}

// covariance recurrence update: R = a*R + wg*outer(X), a/wg handle first-frame
#define UPD(first) do{ \
    float aa = (first) ? 0.f : 0.05f; float wg = (first) ? 1.f : 0.95f; \
    float y0x=wg*x0.x, y0y=wg*x0.y, y1x=wg*x1.x, y1y=wg*x1.y; \
    float y2x=wg*x2.x, y2y=wg*x2.y, y3x=wg*x3.x, y3y=wg*x3.y; \
    d0 = aa*d0 + y0x*x0.x + y0y*x0.y; \
    d1 = aa*d1 + y1x*x1.x + y1y*x1.y; \
    d2 = aa*d2 + y2x*x2.x + y2y*x2.y; \
    d3 = aa*d3 + y3x*x3.x + y3y*x3.y; \
    r10.x = aa*r10.x + y1x*x0.x + y1y*x0.y;  r10.y = aa*r10.y + y1y*x0.x - y1x*x0.y; \
    r20.x = aa*r20.x + y2x*x0.x + y2y*x0.y;  r20.y = aa*r20.y + y2y*x0.x - y2x*x0.y; \
    r30.x = aa*r30.x + y3x*x0.x + y3y*x0.y;  r30.y = aa*r30.y + y3y*x0.x - y3x*x0.y; \
    r21.x = aa*r21.x + y2x*x1.x + y2y*x1.y;  r21.y = aa*r21.y + y2y*x1.x - y2x*x1.y; \
    r31.x = aa*r31.x + y3x*x1.x + y3y*x1.y;  r31.y = aa*r31.y + y3y*x1.x - y3x*x1.y; \
    r32.x = aa*r32.x + y3x*x2.x + y3y*x2.y;  r32.y = aa*r32.y + y3y*x2.x - y3x*x2.y; \
}while(0)

// ---------- LDS-staged chunked scan, half-strip, CH=2 x 256 threads, 4-frame warm-up ----------
// Warm-up frames below tbase (threads 0..1) come straight from gmem.
// Division/sqrt-free Schur-adjugate solve (scale-invariance of s). S1/S2 layout: complex [b][f][t]
__global__ __launch_bounds__(256) void k_scan(const float* __restrict__ S, const float* __restrict__ htab,
                      float* __restrict__ S1, float* __restrict__ S2){
    __shared__ float4 tile[1008];     // 16,128 B: swizzled [tbase,te) strip; reused as output buffer
    int bid = blockIdx.x;
    int half = bid & 1;
    int bf = bid >> 1;                // b*FB + f
    int f  = bf % FB;
    int tid = threadIdx.x;
    int tbase = half*SCH;
    int te  = tbase + SCH; if (te > TT) te = TT;
    int nst = 2*(te - tbase);
    const float4* Sg = (const float4*)S + (size_t)bf*TT*2;
    const float4* Sp = Sg + (size_t)tbase*2;
    for (int i = tid; i < nst; i += 256)
        tile[i ^ ((i>>4)&7)] = Sp[i];                    // coalesced gmem read, swizzled LDS write
    __syncthreads();
    float2 out1[CH], out2[CH];
    int t0 = tbase + tid*CH;
    bool act = (tid*CH < SCH) && (t0 < TT);
    if (act){
        const float2* hp = (const float2*)htab;
        float2 ha0 = hp[f*4+0], ha1 = hp[f*4+1], ha2 = hp[f*4+2], ha3 = hp[f*4+3];
        float2 hb0 = hp[(FB+f)*4+0], hb1 = hp[(FB+f)*4+1], hb2 = hp[(FB+f)*4+2], hb3 = hp[(FB+f)*4+3];
        float d0=0,d1=0,d2=0,d3=0;
        float2 r10={0,0}, r20={0,0}, r30={0,0}, r21={0,0}, r31={0,0}, r32={0,0};
        int ts = t0 - KWARM; if (ts < 0) ts = 0;
        for (int tau = ts; tau < t0; ++tau){
            float4 v0, v1;
            if (tau >= tbase){
                int i0 = 2*(tau - tbase);
                v0 = tile[i0 ^ ((i0>>4)&7)];
                v1 = tile[(i0+1) ^ ((i0>>4)&7)];
            } else {
                v0 = Sg[2*tau];
                v1 = Sg[2*tau + 1];
            }
            float2 x0 = make_float2(v0.x, v0.y), x1 = make_float2(v0.z, v0.w);
            float2 x2 = make_float2(v1.x, v1.y), x3 = make_float2(v1.z, v1.w);
            UPD(tau == 0);
        }
        for (int j = 0; j < CH; ++j){
            int t = t0 + j;
            if (t >= TT) break;
            int i0 = 2*(t - tbase);
            float4 v0 = tile[i0 ^ ((i0>>4)&7)];
            float4 v1 = tile[(i0+1) ^ ((i0>>4)&7)];
            float2 x0 = make_float2(v0.x, v0.y), x1 = make_float2(v0.z, v0.w);
            float2 x2 = make_float2(v1.x, v1.y), x3 = make_float2(v1.z, v1.w);
            UPD(t == 0);
            float trc = d0 + d1 + d2 + d3;
            float lam = trc * 0.25f;
            float e0 = d0 + lam, e1 = d1 + lam, e2 = d2 + lam, e3 = d3 + lam;
            float detP = e0*e1 - (r10.x*r10.x + r10.y*r10.y);
            float2 w00 = csub(cscale(r20, e1), cmulf(r10, r21));
            float2 w01 = csub(cscale(r30, e1), cmulf(r10, r31));
            float2 w10 = csub(cscale(r21, e0), cjmul(r10, r20));
            float2 w11 = csub(cscale(r31, e0), cjmul(r10, r30));
            float2 va = cjmul(r30, w00), vb = cjmul(r31, w10);
            float2 V10 = make_float2(va.x + vb.x, -(va.y + vb.y));
            float reV00 = r20.x*w00.x + r20.y*w00.y + r21.x*w10.x + r21.y*w10.y;
            float reV11 = r30.x*w01.x + r30.y*w01.y + r31.x*w11.x + r31.y*w11.y;
            float t00 = detP*e2 - reV00;
            float t11 = detP*e3 - reV11;
            float2 t10 = csub(cscale(r32, detP), V10);
            float detT = t00*t11 - (t10.x*t10.x + t10.y*t10.y);
            #pragma unroll
            for (int m = 0; m < 2; ++m){
                float2 h0 = m ? hb0 : ha0;
                float2 h1 = m ? hb1 : ha1;
                float2 h2 = m ? hb2 : ha2;
                float2 h3 = m ? hb3 : ha3;
                float2 g0 = csub(cscale(h0, e1), cjmul(r10, h1));
                float2 g1 = csub(cscale(h1, e0), cmulf(r10, h0));
                float2 ta = cmulf(r20, g0), tb = cmulf(r21, g1);
                float2 hh0 = make_float2(detP*h2.x - ta.x - tb.x, detP*h2.y - ta.y - tb.y);
                ta = cmulf(r30, g0); tb = cmulf(r31, g1);
                float2 hh1 = make_float2(detP*h3.x - ta.x - tb.x, detP*h3.y - ta.y - tb.y);
                float2 y20 = csub(cscale(hh0, t11), cjmul(t10, hh1));
                float2 y21 = csub(cscale(hh1, t00), cmulf(t10, hh0));
                float2 u20 = cscale(y20, detP), u21 = cscale(y21, detP);
                ta = cmulcj(y20, r20); tb = cmulcj(y21, r30);
                float2 q0 = make_float2(detT*h0.x - ta.x - tb.x, detT*h0.y - ta.y - tb.y);
                ta = cmulcj(y20, r21); tb = cmulcj(y21, r31);
                float2 q1 = make_float2(detT*h1.x - ta.x - tb.x, detT*h1.y - ta.y - tb.y);
                float2 u10 = csub(cscale(q0, e1), cjmul(r10, q1));
                float2 u11 = csub(cscale(q1, e0), cmulf(r10, q0));
                float2 den = cjmul(h0, u10), tmp;
                tmp = cjmul(h1, u11); den.x += tmp.x; den.y += tmp.y;
                tmp = cjmul(h2, u20); den.x += tmp.x; den.y += tmp.y;
                tmp = cjmul(h3, u21); den.x += tmp.x; den.y += tmp.y;
                float2 num = cjmul(u10, x0);
                tmp = cjmul(u11, x1); num.x += tmp.x; num.y += tmp.y;
                tmp = cjmul(u20, x2); num.x += tmp.x; num.y += tmp.y;
                tmp = cjmul(u21, x3); num.x += tmp.x; num.y += tmp.y;
                float2 s = cdivf(num, make_float2(den.x, -den.y));
                if (m) out2[j] = s; else out1[j] = s;
            }
        }
    }
    __syncthreads();                      // all tile reads done -> reuse as output buffers
    float2* o1 = (float2*)tile;           // [0..511]
    float2* o2 = ((float2*)tile) + 528;   // [528..1039] (ends at float4 520 <= 1008)
    if (act){
        for (int j = 0; j < CH && t0 + j < TT; ++j){
            int lt = t0 - tbase + j;
            int iw = lt ^ ((lt>>3)&7);    // bank-spread write
            o1[iw] = out1[j];
            o2[iw] = out2[j];
        }
    }
    __syncthreads();
    int nout = te - tbase;
    float2* S1g = (float2*)S1 + (size_t)bf*TT + tbase;
    float2* S2g = (float2*)S2 + (size_t)bf*TT + tbase;
    for (int i = tid; i < nout; i += 256){
        int ir = i ^ ((i>>3)&7);
        S1g[i] = o1[ir];
        S2g[i] = o2[ir];
    }
}

// ---------- pack v2 (R8-verified): coalesced LDS transpose. block = (rb, 32-t tile) ----------
__global__ __launch_bounds__(256) void k_pack(const float* __restrict__ S1, const float* __restrict__ S2,
                                              short* __restrict__ A){
    __shared__ short tile[32*708];        // 45,312 B; row = t-in-tile, col = kk (hi 0..351 | lo 352..703)
    int bid = blockIdx.x;                 // rb*32 + tb
    int tb = bid & 31, rb = bid >> 5;
    int t0 = tb*32;
    int beam = rb >> 3, b = rb & 7;
    const float2* Sp = (const float2*)(beam ? S2 : S1) + (size_t)b*FB*TT;
    int tid = threadIdx.x;
    for (int idx = tid; idx < 32*176; idx += 256){
        int bin = idx >> 5, tq = idx & 31;
        int t = t0 + tq;
        float2 s = make_float2(0.f, 0.f);
        if (bin < FB && t < TT) s = Sp[(size_t)bin*TT + t];
        int c0 = 2*bin;
        tile[tq*708 + c0]            = bf_hi(s.x);
        tile[tq*708 + c0 + 1]        = bf_hi(s.y);
        tile[tq*708 + KSEC + c0]     = bf_lo(s.x);
        tile[tq*708 + KSEC + c0 + 1] = bf_lo(s.y);
    }
    __syncthreads();
    for (int idx = tid; idx < 32*176; idx += 256){
        int tq = idx / 176, k4 = idx % 176;
        int t = t0 + tq;
        if (t < TT)
            *(short4*)&A[(size_t)(rb*TT + t)*LDK + k4*4] = *(short4*)&tile[tq*708 + k4*4];
    }
}

// ---------- irfft MFMA GEMM, R15: 2-phase dbuf global_load_lds staging ----------
// frames[GM,320] = 3-segment bf16 split product. Same swizzled-linear LDS scheme as
// k_gstft; 33 flat steps (seg 0..2 x kt 0..10), one barrier per step.
__global__ __launch_bounds__(256) void k_gemm(const short* __restrict__ A, const short* __restrict__ Bt,
                                              float* __restrict__ C){
    __shared__ short sb2[8192];            // 16 KB: 2 buffers x (A|B) x 2048 shorts
    int tid = threadIdx.x;
    int row0 = blockIdx.x * 64;
    int col0 = blockIdx.y * 64;
    int wave = tid >> 6, lane = tid & 63;
    int wm = wave >> 1, wn = wave & 1;
    int l15 = lane & 15, quad = lane >> 4;
    // staging (per lane)
    int rowS  = wave*16 + (lane >> 2);
    int chunk = (lane & 3) ^ ((lane >> 3) & 3);
    int grS = row0 + rowS; if (grS >= GM) grS = GM - 1;   // clamp; stores guarded
    const short* gA = A  + (size_t)grS*LDK + chunk*8;
    const short* gB = Bt + (size_t)(col0 + rowS)*LDK + chunk*8;
    short* lA = sb2 + wave*512;
    // reads
    int sw  = (l15 >> 1) & 3;
    int c0r = (quad ^ sw) * 8;
    int ra0 = (wm*32 + l15)*32 + c0r;
    int ra1 = (wm*32 + 16 + l15)*32 + c0r;
    int rb0 = (wn*32 + l15)*32 + c0r;
    int rb1 = (wn*32 + 16 + l15)*32 + c0r;
    f32x4 acc00 = {0.f,0.f,0.f,0.f}, acc01 = acc00, acc10 = acc00, acc11 = acc00;

    #define KOF(s_, ka_, kb_) { int sg_ = ((s_) >= 22) ? 2 : ((s_) >= 11) ? 1 : 0; \
        int kt_ = (s_) - sg_*11; \
        ka_ = ((sg_ == 1) ? KSEC : 0) + kt_*32; \
        kb_ = ((sg_ == 2) ? KSEC : 0) + kt_*32; }
    #define STG2(s_, off_) do{ int ka_, kb_; KOF(s_, ka_, kb_); \
        ldsdma16(gA + ka_, lA + (off_));        \
        ldsdma16(gB + kb_, lA + (off_) + 2048); \
    }while(0)

    STG2(0, 0);
    __syncthreads();
    int offc = 0;
    #pragma unroll
    for (int s = 0; s < 33; ++s){
        int offn = 4096 - offc;
        if (s < 32) STG2(s+1, offn);
        bf16x8 a0 = *(bf16x8*)&sb2[offc + ra0];
        bf16x8 a1 = *(bf16x8*)&sb2[offc + ra1];
        bf16x8 b0 = *(bf16x8*)&sb2[offc + 2048 + rb0];
        bf16x8 b1 = *(bf16x8*)&sb2[offc + 2048 + rb1];
        acc00 = __builtin_amdgcn_mfma_f32_16x16x32_bf16(a0, b0, acc00, 0, 0, 0);
        acc01 = __builtin_amdgcn_mfma_f32_16x16x32_bf16(a0, b1, acc01, 0, 0, 0);
        acc10 = __builtin_amdgcn_mfma_f32_16x16x32_bf16(a1, b0, acc10, 0, 0, 0);
        acc11 = __builtin_amdgcn_mfma_f32_16x16x32_bf16(a1, b1, acc11, 0, 0, 0);
        __syncthreads();
        offc = offn;
    }
    #undef STG2
    #undef KOF
    for (int r = 0; r < 4; ++r){
        int orow0 = row0 + wm*32 + quad*4 + r;
        int ocol0 = col0 + wn*32 + l15;
        if (orow0 < GM){
            C[(size_t)orow0*NFFT + ocol0]      = acc00[r];
            C[(size_t)orow0*NFFT + ocol0 + 16] = acc01[r];
        }
        if (orow0 + 16 < GM){
            C[(size_t)(orow0+16)*NFFT + ocol0]      = acc10[r];
            C[(size_t)(orow0+16)*NFFT + ocol0 + 16] = acc11[r];
        }
    }
}

// ---------- overlap-add, float4: 4 outputs/thread (wsum==2 in cropped interior) ----------
__global__ __launch_bounds__(256) void k_ola(const float* __restrict__ frames, float* __restrict__ out){
    int gid = blockIdx.x*256 + threadIdx.x;
    if (gid >= 2*BB*(LL/4)) return;
    int o4 = (gid % (LL/4))*4;
    int rb = gid / (LL/4);                 // beam*BB + b
    int i  = o4 + HOP;                     // mult of 4; r in {0,4,...,156}
    int t1 = i / HOP;
    int r  = i - t1*HOP;
    const float4* fb = (const float4*)(frames + (size_t)rb*TT*NFFT);
    float4 a = fb[(t1*NFFT + r) >> 2];
    float4 b = fb[((t1-1)*NFFT + r + HOP) >> 2];
    ((float4*)out)[gid] = make_float4(0.5f*(a.x+b.x), 0.5f*(a.y+b.y), 0.5f*(a.z+b.z), 0.5f*(a.w+b.w));
}

extern "C" void kernel_launch(void* const* d_in, const int* in_sizes, int n_in,
                              void* d_out, int out_size, void* d_ws, size_t ws_size,
                              hipStream_t stream){
    const float* in  = (const float*)d_in[0];   // [B, L, C] fp32
    const float* win = (const float*)d_in[1];   // [320] fp32
    float* ws = (float*)d_ws;
    // ws (floats): mean 32 | invmax 8 | htab 2576 | pad -> header 3072
    //              | S1 (2,578,576) | S2 (2,578,576) | S (10,314,304)   total ~62 MB
    // aliases: part -> S1 head (dead before k_anorm); Ahi/Alo -> S1+S2 (dead after k_gstft);
    //          Bts + Bt -> head of d_out (dead until k_ola fully overwrites; NOT in S — R13 bug);
    //          A_ir -> S (post-scan); frames -> S1/S2 (post-pack)
    float* mean   = ws;
    float* invmax = ws + 32;
    float* htab   = ws + 48;
    float* S1     = ws + 3072;
    size_t nS1 = (size_t)2*BB*FB*TT;            // 2,578,576 floats
    float* S2 = S1 + nS1;
    float* S  = S2 + nS1;                       // 10,314,304 floats
    float* part = S1;
    short* Ahi = (short*)S1;                    // 8*4*160320 = 5,130,240 shorts
    short* Alo = Ahi + (size_t)BB*CC*NPAD;      // total 10,260,480 shorts <= S1+S2 (10,314,304 short-equiv)
    short* Bts = (short*)d_out;                 // 245,760 shorts (= 122,880 floats)
    short* Bt  = (short*)((float*)d_out + 131072); // 225,280 shorts at float-offset 131072 (16B aligned)
    short* A  = (short*)S;                      // irfft A: 16016*704 bf16
    float* frames = S1;                         // 16016*320 floats over dead S1+S2

    int ngen = 2*FB*CC + 384*640 + NFFT*LDK;    // fused table generation
    k_gen<<<dim3((ngen + 255)/256), dim3(256), 0, stream>>>(win, htab, Bts, Bt);
    k_stats1<<<dim3(BB*RBLK), dim3(256), 0, stream>>>(in, part);
    k_stats2<<<dim3(BB), dim3(128), 0, stream>>>(part, mean, invmax);
    k_anorm<<<dim3((BB*CC*(NPAD/8) + 255)/256), dim3(256), 0, stream>>>(in, mean, invmax, Ahi, Alo);
    k_gstft<<<dim3(BB*TP*CC/64, 6), dim3(256), 0, stream>>>(Ahi, Alo, Bts, S);
    k_scan<<<dim3(2*BB*FB), dim3(256), 0, stream>>>(S, htab, S1, S2);
    k_pack<<<dim3(512), dim3(256), 0, stream>>>(S1, S2, A);
    k_gemm<<<dim3((GM + 63)/64, NFFT/64), dim3(256), 0, stream>>>(A, Bt, frames);
    k_ola<<<dim3((2*BB*(LL/4) + 255)/256), dim3(256), 0, stream>>>(frames, (float*)d_out);
}

// Round 3
// 220.401 us; speedup vs baseline: 1.4144x; 1.0018x over previous
//
#include <hip/hip_runtime.h>
#include <hip/hip_bf16.h>
#include <math.h>

#define BB 8
#define LL 160000
#define CC 4
#define NFFT 320
#define HOP 160
#define FB 161          // rfft bins
#define TT 1001         // frames
#define TP 1024         // padded frames per batch (t-slots) for STFT GEMM
#define RBLK 128        // stats blocks per batch
#define PI_D 3.14159265358979323846
#define NPAD 160320     // reflect-padded samples per (b,c): p in [-160, 160159]

#define SCH 504         // scan outputs per half-block (2 halves cover 1001); R16: CH=1 x 512 threads
#define KWARM 4         // warm-up frames; tail weight 0.05^4 ~ 6e-6 rel << bf16 error floor (4.9e-4)

#define GM 16016        // irfft GEMM M = 2*BB*TT rows (beam,b,t)
#define KSEC 352        // irfft padded K per split-section (322 used)
#define LDK 704         // irfft A/Bt leading dim = 2 sections
#define KT 11           // irfft K-tiles of 32 per section
// R16: 2-deep counted-vmcnt pipeline (T4). R15's __syncthreads() carried an implicit
// vmcnt(0) that DRAINED the just-issued prefetch -> DMA latency fully exposed each kt
// (R13/R15 both 46.5us for this reason). Now: raw s_barrier + "s_waitcnt vmcnt(4)"
// (wave-local; only the oldest STG must land, the newer stays in flight), prefetch
// depth 2, never drain to 0 in the main loop. lgkmcnt(0)+sched_barrier(0) after
// ds_reads per rule #18 before the buffer-reuse barrier.
// R14 lesson (direct-global gather, 47->115us): LDS staging is a latency-decoupling
// pipeline, not just a cache — do not remove it.
// LIFETIME NOTE (R13 bug): Bt/Bts must NOT live in the S region — k_gstft overwrites
// ALL of S. Both live in d_out's head (dead until k_ola fully overwrites at the end).

typedef __attribute__((ext_vector_type(8))) short bf16x8;
typedef __attribute__((ext_vector_type(4))) float f32x4;

__device__ __forceinline__ void ldsdma16(const short* g, short* l){
    // wave-level DMA: per-lane global src, wave-uniform LDS base + lane*16B
    __builtin_amdgcn_global_load_lds((const __attribute__((address_space(1))) void*)g,
                                     (__attribute__((address_space(3))) void*)l, 16, 0, 0);
}

__device__ __forceinline__ float2 cmulf(float2 a, float2 b){           // a*b
    return make_float2(a.x*b.x - a.y*b.y, a.x*b.y + a.y*b.x);
}
__device__ __forceinline__ float2 cmulcj(float2 a, float2 b){          // a*conj(b)
    return make_float2(a.x*b.x + a.y*b.y, a.y*b.x - a.x*b.y);
}
__device__ __forceinline__ float2 cjmul(float2 a, float2 b){           // conj(a)*b
    return make_float2(a.x*b.x + a.y*b.y, a.x*b.y - a.y*b.x);
}
__device__ __forceinline__ float2 csub(float2 a, float2 b){ return make_float2(a.x-b.x, a.y-b.y); }
__device__ __forceinline__ float2 cscale(float2 a, float s){ return make_float2(a.x*s, a.y*s); }
__device__ __forceinline__ float2 cdivf(float2 a, float2 b){           // a/b
    float inv = 1.0f/(b.x*b.x + b.y*b.y);
    return make_float2((a.x*b.x + a.y*b.y)*inv, (a.y*b.x - a.x*b.y)*inv);
}
__device__ __forceinline__ short bf_hi(float v){
    __hip_bfloat16 h = __float2bfloat16(v);
    short s; __builtin_memcpy(&s, &h, 2); return s;
}
__device__ __forceinline__ short bf_lo(float v){
    __hip_bfloat16 h = __float2bfloat16(v);
    float r = v - __bfloat162float(h);
    __hip_bfloat16 l = __float2bfloat16(r);
    short s; __builtin_memcpy(&s, &l, 2); return s;
}

// ---------- fused table generator: htab | Bts (STFT B) | Bt (irfft B) ----------
__global__ void k_gen(const float* __restrict__ win, float* __restrict__ htab,
                      short* __restrict__ Bts, short* __restrict__ Bt){
    int gid = blockIdx.x*256 + threadIdx.x;
    if (gid < 2*FB*CC){
        int i = gid;
        int c = i & 3;
        int k = (i >> 2) % FB;
        int m = i / (FB*CC);
        double coef = 2.0*PI_D*50.0*0.027*sin(40.0*PI_D/180.0)/340.0;
        double sgn = (m == 0) ? -1.0 : 1.0;
        double ph = sgn*coef*(double)k*(double)c;
        double s, c2;
        sincos(ph, &s, &c2);
        ((float2*)htab)[i] = make_float2((float)c2, (float)s);
        return;
    }
    gid -= 2*FB*CC;
    if (gid < 384*640){
        int col = gid / 640, kk = gid % 640;
        int n = (kk >= 320) ? kk - 320 : kk;
        int sec = (kk >= 320) ? 1 : 0;
        float v = 0.f;
        if (col < 2*FB){
            int k = col >> 1;
            double th = 2.0*PI_D*(double)k*(double)n/320.0;
            double s, co; sincos(th, &s, &co);
            double tw = (col & 1) ? -s : co;
            v = (float)((double)win[n]*tw);
        }
        Bts[gid] = sec ? bf_lo(v) : bf_hi(v);
        return;
    }
    gid -= 384*640;
    if (gid < NFFT*LDK){
        int n = gid / LDK, kk = gid % LDK;
        int sec = (kk >= KSEC) ? 1 : 0;
        int kk2 = kk - (sec ? KSEC : 0);
        float v = 0.f;
        if (kk2 < 2*FB){
            int bin = kk2 >> 1;
            double c = ((bin == 0 || bin == 160) ? 1.0 : 2.0) / 320.0;
            double th = 2.0*PI_D*(double)bin*(double)n/320.0;
            double s, co; sincos(th, &s, &co);
            v = (float)((kk2 & 1) ? -c*s : c*co);
        }
        Bt[(size_t)n*LDK + kk] = sec ? bf_lo(v) : bf_hi(v);
    }
}

// ---------- stage 1: per-(b,chunk) partial {sum4, min4, max4} ----------
__global__ __launch_bounds__(256) void k_stats1(const float* __restrict__ in, float* __restrict__ part){
    __shared__ float4 s4[256];
    __shared__ float4 mn4[256];
    __shared__ float4 mx4[256];
    int b = blockIdx.x / RBLK, chunk = blockIdx.x % RBLK;
    int tid = threadIdx.x;
    const float4* p = (const float4*)(in + (size_t)b*LL*CC);
    const int per = LL / RBLK;
    int start = chunk*per;
    float4 s  = make_float4(0.f,0.f,0.f,0.f);
    float4 mn = make_float4( 3.4e38f, 3.4e38f, 3.4e38f, 3.4e38f);
    float4 mx = make_float4(-3.4e38f,-3.4e38f,-3.4e38f,-3.4e38f);
    for (int i = start + tid; i < start + per; i += 256){
        float4 v = p[i];
        s.x += v.x; s.y += v.y; s.z += v.z; s.w += v.w;
        mn.x = fminf(mn.x, v.x); mn.y = fminf(mn.y, v.y); mn.z = fminf(mn.z, v.z); mn.w = fminf(mn.w, v.w);
        mx.x = fmaxf(mx.x, v.x); mx.y = fmaxf(mx.y, v.y); mx.z = fmaxf(mx.z, v.z); mx.w = fmaxf(mx.w, v.w);
    }
    s4[tid] = s; mn4[tid] = mn; mx4[tid] = mx;
    __syncthreads();
    for (int st = 128; st >= 1; st >>= 1){
        if (tid < st){
            float4 a = s4[tid], c = s4[tid+st];
            s4[tid] = make_float4(a.x+c.x, a.y+c.y, a.z+c.z, a.w+c.w);
            float4 d = mn4[tid], e = mn4[tid+st];
            mn4[tid] = make_float4(fminf(d.x,e.x), fminf(d.y,e.y), fminf(d.z,e.z), fminf(d.w,e.w));
            float4 f = mx4[tid], g = mx4[tid+st];
            mx4[tid] = make_float4(fmaxf(f.x,g.x), fmaxf(f.y,g.y), fmaxf(f.z,g.z), fmaxf(f.w,g.w));
        }
        __syncthreads();
    }
    if (tid == 0){
        float* dst = part + (size_t)(b*RBLK + chunk)*12;
        float4 a = s4[0], d = mn4[0], f = mx4[0];
        dst[0]=a.x; dst[1]=a.y; dst[2]=a.z; dst[3]=a.w;
        dst[4]=d.x; dst[5]=d.y; dst[6]=d.z; dst[7]=d.w;
        dst[8]=f.x; dst[9]=f.y; dst[10]=f.z; dst[11]=f.w;
    }
}

// ---------- stage 2: finalize mean + invmax per batch ----------
__global__ __launch_bounds__(128) void k_stats2(const float* __restrict__ part,
                                                float* __restrict__ mean, float* __restrict__ invmax){
    __shared__ float4 s4[128];
    __shared__ float4 mn4[128];
    __shared__ float4 mx4[128];
    int b = blockIdx.x, tid = threadIdx.x;
    const float* src = part + (size_t)(b*RBLK + tid)*12;
    s4[tid]  = make_float4(src[0], src[1], src[2], src[3]);
    mn4[tid] = make_float4(src[4], src[5], src[6], src[7]);
    mx4[tid] = make_float4(src[8], src[9], src[10], src[11]);
    __syncthreads();
    for (int st = 64; st >= 1; st >>= 1){
        if (tid < st){
            float4 a = s4[tid], c = s4[tid+st];
            s4[tid] = make_float4(a.x+c.x, a.y+c.y, a.z+c.z, a.w+c.w);
            float4 d = mn4[tid], e = mn4[tid+st];
            mn4[tid] = make_float4(fminf(d.x,e.x), fminf(d.y,e.y), fminf(d.z,e.z), fminf(d.w,e.w));
            float4 f = mx4[tid], g = mx4[tid+st];
            mx4[tid] = make_float4(fmaxf(f.x,g.x), fmaxf(f.y,g.y), fmaxf(f.z,g.z), fmaxf(f.w,g.w));
        }
        __syncthreads();
    }
    if (tid == 0){
        float4 sum = s4[0], mn = mn4[0], mx = mx4[0];
        float m0 = sum.x*(1.0f/LL), m1 = sum.y*(1.0f/LL), m2 = sum.z*(1.0f/LL), m3 = sum.w*(1.0f/LL);
        mean[b*4+0]=m0; mean[b*4+1]=m1; mean[b*4+2]=m2; mean[b*4+3]=m3;
        float a0 = fmaxf(mx.x - m0, m0 - mn.x);
        float a1 = fmaxf(mx.y - m1, m1 - mn.y);
        float a2 = fmaxf(mx.z - m2, m2 - mn.z);
        float a3 = fmaxf(mx.w - m3, m3 - mn.w);
        invmax[b] = 1.0f / fmaxf(fmaxf(a0, a1), fmaxf(a2, a3));
    }
}

// ---------- A-normalize: reflect-padded normalized bf16 hi/lo planes Ahi/Alo[b][c][NPAD] ----------
__global__ __launch_bounds__(256) void k_anorm(const float* __restrict__ in,
        const float* __restrict__ mean, const float* __restrict__ invmax,
        short* __restrict__ Ahi, short* __restrict__ Alo){
    int gid = blockIdx.x*256 + threadIdx.x;
    if (gid >= BB*CC*(NPAD/8)) return;
    int p8 = gid % (NPAD/8);
    int bc = gid / (NPAD/8);
    int b = bc >> 2;
    float mc = mean[bc];
    float iv = invmax[b];
    const float* px = in + (size_t)b*LL*CC + (bc & 3);
    bf16x8 h8, l8;
    #pragma unroll
    for (int j = 0; j < 8; ++j){
        int p = p8*8 + j - 160;
        int m2 = p < 0 ? -p : (p >= LL ? 2*LL - 2 - p : p);
        float v = (px[(size_t)m2*CC] - mc) * iv;
        __hip_bfloat16 h = __float2bfloat16(v);
        float r = v - __bfloat162float(h);
        __hip_bfloat16 l = __float2bfloat16(r);
        short hs, ls; __builtin_memcpy(&hs, &h, 2); __builtin_memcpy(&ls, &l, 2);
        h8[j] = hs; l8[j] = ls;
    }
    size_t o = (size_t)bc*NPAD + (size_t)p8*8;
    *(bf16x8*)&Ahi[o] = h8;
    *(bf16x8*)&Alo[o] = l8;
}

// ---------- STFT as MFMA GEMM, R16: 2-deep counted-vmcnt DMA pipeline ----------
// rows=(b,t,c), cols=(k,ri). LDS per buffer: Ah|Al|Bh|Bl, each 64 rows x 32 shorts
// (64B linear rows, DMA-written). Swizzle: LDS slot s of row r holds k-chunk
// s ^ ((r>>1)&3); reader at (row r, chunk quad) reads slot quad ^ ((r>>1)&3).
// S out layout: complex S[b][k][t][c], c fastest (two float4 per (b,k,t))
__global__ __launch_bounds__(256) void k_gstft(const short* __restrict__ Ahi, const short* __restrict__ Alo,
        const short* __restrict__ Bts, float* __restrict__ S){
    __shared__ short stage[16384];           // 32 KB: 2 buffers x (Ah|Al|Bh|Bl) x 2048 shorts
    float* Ct = (float*)stage;               // 64 x 66 floats (16.9 KB) overlays after K-loop
    int tid = threadIdx.x;
    int row0 = blockIdx.x*64;                // over b*TP*CC rows
    int col0 = blockIdx.y*64;
    int b  = row0 >> 12;                     // TP*CC = 4096 rows per batch
    int t0 = (row0 & 4095) >> 2;
    if (t0 >= TT) return;                    // fully-padded row-block (t0==1008): skip
    int wave = tid >> 6, lane = tid & 63;
    int wm = wave >> 1, wn = wave & 1;
    int l15 = lane & 15, quad = lane >> 4;
    // ---- staging addresses (per lane): wave w stages rows w*16..w*16+15 ----
    int rowS  = wave*16 + (lane >> 2);       // staged LDS row 0..63
    int chunk = (lane & 3) ^ ((lane >> 3) & 3);   // pre-swizzled global k-chunk
    int tls = t0 + (rowS >> 2); if (tls >= TT) tls = TT - 1;   // clamp; stores guarded later
    size_t gao = (size_t)(b*4 + (rowS & 3))*NPAD + (size_t)tls*160 + chunk*8;
    const short* gAh = Ahi + gao;
    const short* gAl = Alo + gao;
    const short* gB  = Bts + (size_t)(col0 + rowS)*640 + chunk*8;   // hi; lo at +320
    short* lA = stage + wave*512;            // wave-uniform LDS bases (+buffer offset)
    // ---- read addresses ----
    int sw  = (l15 >> 1) & 3;                // (row>>1)&3 for all 4 row variants
    int c0r = (quad ^ sw) * 8;               // swizzled chunk offset (shorts)
    int ra0 = (wm*32 + l15)*32 + c0r;        // A rows
    int ra1 = (wm*32 + 16 + l15)*32 + c0r;
    int rb0 = (wn*32 + l15)*32 + c0r;        // B rows
    int rb1 = (wn*32 + 16 + l15)*32 + c0r;
    f32x4 acc00 = {0.f,0.f,0.f,0.f}, acc01 = acc00, acc10 = acc00, acc11 = acc00;

    #define STG(kt_, off_) do{ \
        ldsdma16(gAh + (kt_)*32,       lA + (off_));        \
        ldsdma16(gAl + (kt_)*32,       lA + (off_) + 2048); \
        ldsdma16(gB  + (kt_)*32,       lA + (off_) + 4096); \
        ldsdma16(gB  + (kt_)*32 + 320, lA + (off_) + 6144); \
    }while(0)

    STG(0, 0);                               // 2-deep prologue
    STG(1, 8192);
    #pragma unroll
    for (int kt = 0; kt < 10; ++kt){
        int offc = (kt & 1) ? 8192 : 0;
        // wave-local: oldest STG (this kt's buffer) must land; newer stays in flight
        if (kt < 9) asm volatile("s_waitcnt vmcnt(4)" ::: "memory");
        else        asm volatile("s_waitcnt vmcnt(0)" ::: "memory");
        __builtin_amdgcn_s_barrier();        // all waves' data for buf[kt&1] present
        bf16x8 a0h = *(bf16x8*)&stage[offc + ra0];
        bf16x8 a1h = *(bf16x8*)&stage[offc + ra1];
        bf16x8 a0l = *(bf16x8*)&stage[offc + 2048 + ra0];
        bf16x8 a1l = *(bf16x8*)&stage[offc + 2048 + ra1];
        bf16x8 b0h = *(bf16x8*)&stage[offc + 4096 + rb0];
        bf16x8 b1h = *(bf16x8*)&stage[offc + 4096 + rb1];
        bf16x8 b0l = *(bf16x8*)&stage[offc + 6144 + rb0];
        bf16x8 b1l = *(bf16x8*)&stage[offc + 6144 + rb1];
        asm volatile("s_waitcnt lgkmcnt(0)" ::: "memory");
        __builtin_amdgcn_sched_barrier(0);   // rule #18: pin reads before the reuse barrier
        __builtin_amdgcn_s_barrier();        // all waves done reading buf[kt&1]
        if (kt < 8) STG(kt+2, offc);         // overwrite just-freed buffer; lands in ~2 phases
        acc00 = __builtin_amdgcn_mfma_f32_16x16x32_bf16(a0h, b0h, acc00, 0, 0, 0);
        acc01 = __builtin_amdgcn_mfma_f32_16x16x32_bf16(a0h, b1h, acc01, 0, 0, 0);
        acc10 = __builtin_amdgcn_mfma_f32_16x16x32_bf16(a1h, b0h, acc10, 0, 0, 0);
        acc11 = __builtin_amdgcn_mfma_f32_16x16x32_bf16(a1h, b1h, acc11, 0, 0, 0);
        acc00 = __builtin_amdgcn_mfma_f32_16x16x32_bf16(a0l, b0h, acc00, 0, 0, 0);
        acc01 = __builtin_amdgcn_mfma_f32_16x16x32_bf16(a0l, b1h, acc01, 0, 0, 0);
        acc10 = __builtin_amdgcn_mfma_f32_16x16x32_bf16(a1l, b0h, acc10, 0, 0, 0);
        acc11 = __builtin_amdgcn_mfma_f32_16x16x32_bf16(a1l, b1h, acc11, 0, 0, 0);
        acc00 = __builtin_amdgcn_mfma_f32_16x16x32_bf16(a0h, b0l, acc00, 0, 0, 0);
        acc01 = __builtin_amdgcn_mfma_f32_16x16x32_bf16(a0h, b1l, acc01, 0, 0, 0);
        acc10 = __builtin_amdgcn_mfma_f32_16x16x32_bf16(a1h, b0l, acc10, 0, 0, 0);
        acc11 = __builtin_amdgcn_mfma_f32_16x16x32_bf16(a1h, b1l, acc11, 0, 0, 0);
    }
    #undef STG
    // epilogue: LDS transpose. kt=9's read-done barrier guarantees no wave still reads
    // the buffers, so Ct overlay is safe (MFMAs are register-only).
    #pragma unroll
    for (int r = 0; r < 4; ++r){
        int rl = wm*32 + quad*4 + r;         // channel = r (rl & 3 == r)
        Ct[rl*66 + wn*32 + l15]           = acc00[r];
        Ct[rl*66 + wn*32 + l15 + 16]      = acc01[r];
        Ct[(rl+16)*66 + wn*32 + l15]      = acc10[r];
        Ct[(rl+16)*66 + wn*32 + l15 + 16] = acc11[r];
    }
    __syncthreads();
    int tl = tid & 15, h = (tid >> 4) & 1, kq = tid >> 5;
    int t = t0 + tl;
    if (t < TT){
        float4* S4 = (float4*)S;
        for (int kk = kq; kk < 32; kk += 8){
            int kg = (col0 >> 1) + kk;
            if (kg < FB){
                float2 e0 = *(float2*)&Ct[(tl*4 + 2*h)*66 + 2*kk];
                float2 e1 = *(float2*)&Ct[(tl*4 + 2*h + 1)*66 + 2*kk];
                S4[((size_t)(b*FB + kg)*TT + t)*2 + h] = make_float4(e0.x, e0.y, e1.x, e1.y);
            }
        }
    }
}

// covariance recurrence update: R = a*R + wg*outer(X), a/wg handle first-frame
#define UPD(first) do{ \
    float aa = (first) ? 0.f : 0.05f; float wg = (first) ? 1.f : 0.95f; \
    float y0x=wg*x0.x, y0y=wg*x0.y, y1x=wg*x1.x, y1y=wg*x1.y; \
    float y2x=wg*x2.x, y2y=wg*x2.y, y3x=wg*x3.x, y3y=wg*x3.y; \
    d0 = aa*d0 + y0x*x0.x + y0y*x0.y; \
    d1 = aa*d1 + y1x*x1.x + y1y*x1.y; \
    d2 = aa*d2 + y2x*x2.x + y2y*x2.y; \
    d3 = aa*d3 + y3x*x3.x + y3y*x3.y; \
    r10.x = aa*r10.x + y1x*x0.x + y1y*x0.y;  r10.y = aa*r10.y + y1y*x0.x - y1x*x0.y; \
    r20.x = aa*r20.x + y2x*x0.x + y2y*x0.y;  r20.y = aa*r20.y + y2y*x0.x - y2x*x0.y; \
    r30.x = aa*r30.x + y3x*x0.x + y3y*x0.y;  r30.y = aa*r30.y + y3y*x0.x - y3x*x0.y; \
    r21.x = aa*r21.x + y2x*x1.x + y2y*x1.y;  r21.y = aa*r21.y + y2y*x1.x - y2x*x1.y; \
    r31.x = aa*r31.x + y3x*x1.x + y3y*x1.y;  r31.y = aa*r31.y + y3y*x1.x - y3x*x1.y; \
    r32.x = aa*r32.x + y3x*x2.x + y3y*x2.y;  r32.y = aa*r32.y + y3y*x2.x - y3x*x2.y; \
}while(0)

// ---------- LDS-staged chunked scan, half-strip; R16: CH=1 x 512 threads (2x TLP) ----------
// k_scan was latency-bound on dependent complex-FMA chains (VALUBusy 49%, occ 43%).
// Every output t gets exactly KWARM=4 warm-up frames (previously even-t outputs did;
// odd-t had 5 — both far below the bf16 error floor).
__global__ __launch_bounds__(512) void k_scan(const float* __restrict__ S, const float* __restrict__ htab,
                      float* __restrict__ S1, float* __restrict__ S2){
    __shared__ float4 tile[1008];     // 16,128 B: swizzled [tbase,te) strip; reused as output buffer
    int bid = blockIdx.x;
    int half = bid & 1;
    int bf = bid >> 1;                // b*FB + f
    int f  = bf % FB;
    int tid = threadIdx.x;
    int tbase = half*SCH;
    int te  = tbase + SCH; if (te > TT) te = TT;
    int nst = 2*(te - tbase);
    const float4* Sg = (const float4*)S + (size_t)bf*TT*2;
    const float4* Sp = Sg + (size_t)tbase*2;
    for (int i = tid; i < nst; i += 512)
        tile[i ^ ((i>>4)&7)] = Sp[i];                    // coalesced gmem read, swizzled LDS write
    __syncthreads();
    float2 out1, out2;
    int t0 = tbase + tid;
    bool act = (tid < SCH) && (t0 < TT);
    if (act){
        const float2* hp = (const float2*)htab;
        float2 ha0 = hp[f*4+0], ha1 = hp[f*4+1], ha2 = hp[f*4+2], ha3 = hp[f*4+3];
        float2 hb0 = hp[(FB+f)*4+0], hb1 = hp[(FB+f)*4+1], hb2 = hp[(FB+f)*4+2], hb3 = hp[(FB+f)*4+3];
        float d0=0,d1=0,d2=0,d3=0;
        float2 r10={0,0}, r20={0,0}, r30={0,0}, r21={0,0}, r31={0,0}, r32={0,0};
        int ts = t0 - KWARM; if (ts < 0) ts = 0;
        for (int tau = ts; tau < t0; ++tau){
            float4 v0, v1;
            if (tau >= tbase){
                int i0 = 2*(tau - tbase);
                v0 = tile[i0 ^ ((i0>>4)&7)];
                v1 = tile[(i0+1) ^ ((i0>>4)&7)];
            } else {
                v0 = Sg[2*tau];
                v1 = Sg[2*tau + 1];
            }
            float2 x0 = make_float2(v0.x, v0.y), x1 = make_float2(v0.z, v0.w);
            float2 x2 = make_float2(v1.x, v1.y), x3 = make_float2(v1.z, v1.w);
            UPD(tau == 0);
        }
        {
            int t = t0;
            int i0 = 2*(t - tbase);
            float4 v0 = tile[i0 ^ ((i0>>4)&7)];
            float4 v1 = tile[(i0+1) ^ ((i0>>4)&7)];
            float2 x0 = make_float2(v0.x, v0.y), x1 = make_float2(v0.z, v0.w);
            float2 x2 = make_float2(v1.x, v1.y), x3 = make_float2(v1.z, v1.w);
            UPD(t == 0);
            float trc = d0 + d1 + d2 + d3;
            float lam = trc * 0.25f;
            float e0 = d0 + lam, e1 = d1 + lam, e2 = d2 + lam, e3 = d3 + lam;
            float detP = e0*e1 - (r10.x*r10.x + r10.y*r10.y);
            float2 w00 = csub(cscale(r20, e1), cmulf(r10, r21));
            float2 w01 = csub(cscale(r30, e1), cmulf(r10, r31));
            float2 w10 = csub(cscale(r21, e0), cjmul(r10, r20));
            float2 w11 = csub(cscale(r31, e0), cjmul(r10, r30));
            float2 va = cjmul(r30, w00), vb = cjmul(r31, w10);
            float2 V10 = make_float2(va.x + vb.x, -(va.y + vb.y));
            float reV00 = r20.x*w00.x + r20.y*w00.y + r21.x*w10.x + r21.y*w10.y;
            float reV11 = r30.x*w01.x + r30.y*w01.y + r31.x*w11.x + r31.y*w11.y;
            float t00 = detP*e2 - reV00;
            float t11 = detP*e3 - reV11;
            float2 t10 = csub(cscale(r32, detP), V10);
            float detT = t00*t11 - (t10.x*t10.x + t10.y*t10.y);
            #pragma unroll
            for (int m = 0; m < 2; ++m){
                float2 h0 = m ? hb0 : ha0;
                float2 h1 = m ? hb1 : ha1;
                float2 h2 = m ? hb2 : ha2;
                float2 h3 = m ? hb3 : ha3;
                float2 g0 = csub(cscale(h0, e1), cjmul(r10, h1));
                float2 g1 = csub(cscale(h1, e0), cmulf(r10, h0));
                float2 ta = cmulf(r20, g0), tb = cmulf(r21, g1);
                float2 hh0 = make_float2(detP*h2.x - ta.x - tb.x, detP*h2.y - ta.y - tb.y);
                ta = cmulf(r30, g0); tb = cmulf(r31, g1);
                float2 hh1 = make_float2(detP*h3.x - ta.x - tb.x, detP*h3.y - ta.y - tb.y);
                float2 y20 = csub(cscale(hh0, t11), cjmul(t10, hh1));
                float2 y21 = csub(cscale(hh1, t00), cmulf(t10, hh0));
                float2 u20 = cscale(y20, detP), u21 = cscale(y21, detP);
                ta = cmulcj(y20, r20); tb = cmulcj(y21, r30);
                float2 q0 = make_float2(detT*h0.x - ta.x - tb.x, detT*h0.y - ta.y - tb.y);
                ta = cmulcj(y20, r21); tb = cmulcj(y21, r31);
                float2 q1 = make_float2(detT*h1.x - ta.x - tb.x, detT*h1.y - ta.y - tb.y);
                float2 u10 = csub(cscale(q0, e1), cjmul(r10, q1));
                float2 u11 = csub(cscale(q1, e0), cmulf(r10, q0));
                float2 den = cjmul(h0, u10), tmp;
                tmp = cjmul(h1, u11); den.x += tmp.x; den.y += tmp.y;
                tmp = cjmul(h2, u20); den.x += tmp.x; den.y += tmp.y;
                tmp = cjmul(h3, u21); den.x += tmp.x; den.y += tmp.y;
                float2 num = cjmul(u10, x0);
                tmp = cjmul(u11, x1); num.x += tmp.x; num.y += tmp.y;
                tmp = cjmul(u20, x2); num.x += tmp.x; num.y += tmp.y;
                tmp = cjmul(u21, x3); num.x += tmp.x; num.y += tmp.y;
                float2 s = cdivf(num, make_float2(den.x, -den.y));
                if (m) out2 = s; else out1 = s;
            }
        }
    }
    __syncthreads();                      // all tile reads done -> reuse as output buffers
    float2* o1 = (float2*)tile;           // [0..511]
    float2* o2 = ((float2*)tile) + 528;   // [528..1039] (ends at float4 520 <= 1008)
    if (act){
        int lt = t0 - tbase;
        int iw = lt ^ ((lt>>3)&7);        // bank-spread write
        o1[iw] = out1;
        o2[iw] = out2;
    }
    __syncthreads();
    int nout = te - tbase;
    float2* S1g = (float2*)S1 + (size_t)bf*TT + tbase;
    float2* S2g = (float2*)S2 + (size_t)bf*TT + tbase;
    for (int i = tid; i < nout; i += 512){
        int ir = i ^ ((i>>3)&7);
        S1g[i] = o1[ir];
        S2g[i] = o2[ir];
    }
}

// ---------- pack v2 (R8-verified): coalesced LDS transpose. block = (rb, 32-t tile) ----------
__global__ __launch_bounds__(256) void k_pack(const float* __restrict__ S1, const float* __restrict__ S2,
                                              short* __restrict__ A){
    __shared__ short tile[32*708];        // 45,312 B; row = t-in-tile, col = kk (hi 0..351 | lo 352..703)
    int bid = blockIdx.x;                 // rb*32 + tb
    int tb = bid & 31, rb = bid >> 5;
    int t0 = tb*32;
    int beam = rb >> 3, b = rb & 7;
    const float2* Sp = (const float2*)(beam ? S2 : S1) + (size_t)b*FB*TT;
    int tid = threadIdx.x;
    for (int idx = tid; idx < 32*176; idx += 256){
        int bin = idx >> 5, tq = idx & 31;
        int t = t0 + tq;
        float2 s = make_float2(0.f, 0.f);
        if (bin < FB && t < TT) s = Sp[(size_t)bin*TT + t];
        int c0 = 2*bin;
        tile[tq*708 + c0]            = bf_hi(s.x);
        tile[tq*708 + c0 + 1]        = bf_hi(s.y);
        tile[tq*708 + KSEC + c0]     = bf_lo(s.x);
        tile[tq*708 + KSEC + c0 + 1] = bf_lo(s.y);
    }
    __syncthreads();
    for (int idx = tid; idx < 32*176; idx += 256){
        int tq = idx / 176, k4 = idx % 176;
        int t = t0 + tq;
        if (t < TT)
            *(short4*)&A[(size_t)(rb*TT + t)*LDK + k4*4] = *(short4*)&tile[tq*708 + k4*4];
    }
}

// ---------- irfft MFMA GEMM, R16: 2-deep counted-vmcnt DMA pipeline ----------
// frames[GM,320] = 3-segment bf16 split product. Same swizzled-linear LDS scheme as
// k_gstft; 33 flat steps (seg 0..2 x kt 0..10), vmcnt(2) steady-state.
__global__ __launch_bounds__(256) void k_gemm(const short* __restrict__ A, const short* __restrict__ Bt,
                                              float* __restrict__ C){
    __shared__ short sb2[8192];            // 16 KB: 2 buffers x (A|B) x 2048 shorts
    int tid = threadIdx.x;
    int row0 = blockIdx.x * 64;
    int col0 = blockIdx.y * 64;
    int wave = tid >> 6, lane = tid & 63;
    int wm = wave >> 1, wn = wave & 1;
    int l15 = lane & 15, quad = lane >> 4;
    // staging (per lane)
    int rowS  = wave*16 + (lane >> 2);
    int chunk = (lane & 3) ^ ((lane >> 3) & 3);
    int grS = row0 + rowS; if (grS >= GM) grS = GM - 1;   // clamp; stores guarded
    const short* gA = A  + (size_t)grS*LDK + chunk*8;
    const short* gB = Bt + (size_t)(col0 + rowS)*LDK + chunk*8;
    short* lA = sb2 + wave*512;
    // reads
    int sw  = (l15 >> 1) & 3;
    int c0r = (quad ^ sw) * 8;
    int ra0 = (wm*32 + l15)*32 + c0r;
    int ra1 = (wm*32 + 16 + l15)*32 + c0r;
    int rb0 = (wn*32 + l15)*32 + c0r;
    int rb1 = (wn*32 + 16 + l15)*32 + c0r;
    f32x4 acc00 = {0.f,0.f,0.f,0.f}, acc01 = acc00, acc10 = acc00, acc11 = acc00;

    #define KOF(s_, ka_, kb_) { int sg_ = ((s_) >= 22) ? 2 : ((s_) >= 11) ? 1 : 0; \
        int kt_ = (s_) - sg_*11; \
        ka_ = ((sg_ == 1) ? KSEC : 0) + kt_*32; \
        kb_ = ((sg_ == 2) ? KSEC : 0) + kt_*32; }
    #define STG2(s_, off_) do{ int ka_, kb_; KOF(s_, ka_, kb_); \
        ldsdma16(gA + ka_, lA + (off_));        \
        ldsdma16(gB + kb_, lA + (off_) + 2048); \
    }while(0)

    STG2(0, 0);                             // 2-deep prologue
    STG2(1, 4096);
    #pragma unroll
    for (int s = 0; s < 33; ++s){
        int offc = (s & 1) ? 4096 : 0;
        if (s < 32) asm volatile("s_waitcnt vmcnt(2)" ::: "memory");
        else        asm volatile("s_waitcnt vmcnt(0)" ::: "memory");
        __builtin_amdgcn_s_barrier();
        bf16x8 a0 = *(bf16x8*)&sb2[offc + ra0];
        bf16x8 a1 = *(bf16x8*)&sb2[offc + ra1];
        bf16x8 b0 = *(bf16x8*)&sb2[offc + 2048 + rb0];
        bf16x8 b1 = *(bf16x8*)&sb2[offc + 2048 + rb1];
        asm volatile("s_waitcnt lgkmcnt(0)" ::: "memory");
        __builtin_amdgcn_sched_barrier(0);
        __builtin_amdgcn_s_barrier();
        if (s < 31) STG2(s+2, offc);
        acc00 = __builtin_amdgcn_mfma_f32_16x16x32_bf16(a0, b0, acc00, 0, 0, 0);
        acc01 = __builtin_amdgcn_mfma_f32_16x16x32_bf16(a0, b1, acc01, 0, 0, 0);
        acc10 = __builtin_amdgcn_mfma_f32_16x16x32_bf16(a1, b0, acc10, 0, 0, 0);
        acc11 = __builtin_amdgcn_mfma_f32_16x16x32_bf16(a1, b1, acc11, 0, 0, 0);
    }
    #undef STG2
    #undef KOF
    for (int r = 0; r < 4; ++r){
        int orow0 = row0 + wm*32 + quad*4 + r;
        int ocol0 = col0 + wn*32 + l15;
        if (orow0 < GM){
            C[(size_t)orow0*NFFT + ocol0]      = acc00[r];
            C[(size_t)orow0*NFFT + ocol0 + 16] = acc01[r];
        }
        if (orow0 + 16 < GM){
            C[(size_t)(orow0+16)*NFFT + ocol0]      = acc10[r];
            C[(size_t)(orow0+16)*NFFT + ocol0 + 16] = acc11[r];
        }
    }
}

// ---------- overlap-add, float4: 4 outputs/thread (wsum==2 in cropped interior) ----------
__global__ __launch_bounds__(256) void k_ola(const float* __restrict__ frames, float* __restrict__ out){
    int gid = blockIdx.x*256 + threadIdx.x;
    if (gid >= 2*BB*(LL/4)) return;
    int o4 = (gid % (LL/4))*4;
    int rb = gid / (LL/4);                 // beam*BB + b
    int i  = o4 + HOP;                     // mult of 4; r in {0,4,...,156}
    int t1 = i / HOP;
    int r  = i - t1*HOP;
    const float4* fb = (const float4*)(frames + (size_t)rb*TT*NFFT);
    float4 a = fb[(t1*NFFT + r) >> 2];
    float4 b = fb[((t1-1)*NFFT + r + HOP) >> 2];
    ((float4*)out)[gid] = make_float4(0.5f*(a.x+b.x), 0.5f*(a.y+b.y), 0.5f*(a.z+b.z), 0.5f*(a.w+b.w));
}

extern "C" void kernel_launch(void* const* d_in, const int* in_sizes, int n_in,
                              void* d_out, int out_size, void* d_ws, size_t ws_size,
                              hipStream_t stream){
    const float* in  = (const float*)d_in[0];   // [B, L, C] fp32
    const float* win = (const float*)d_in[1];   // [320] fp32
    float* ws = (float*)d_ws;
    // ws (floats): mean 32 | invmax 8 | htab 2576 | pad -> header 3072
    //              | S1 (2,578,576) | S2 (2,578,576) | S (10,314,304)   total ~62 MB
    // aliases: part -> S1 head (dead before k_anorm); Ahi/Alo -> S1+S2 (dead after k_gstft);
    //          Bts + Bt -> head of d_out (dead until k_ola fully overwrites; NOT in S — R13 bug);
    //          A_ir -> S (post-scan); frames -> S1/S2 (post-pack)
    float* mean   = ws;
    float* invmax = ws + 32;
    float* htab   = ws + 48;
    float* S1     = ws + 3072;
    size_t nS1 = (size_t)2*BB*FB*TT;            // 2,578,576 floats
    float* S2 = S1 + nS1;
    float* S  = S2 + nS1;                       // 10,314,304 floats
    float* part = S1;
    short* Ahi = (short*)S1;                    // 8*4*160320 = 5,130,240 shorts
    short* Alo = Ahi + (size_t)BB*CC*NPAD;      // total 10,260,480 shorts <= S1+S2 (10,314,304 short-equiv)
    short* Bts = (short*)d_out;                 // 245,760 shorts (= 122,880 floats)
    short* Bt  = (short*)((float*)d_out + 131072); // 225,280 shorts at float-offset 131072 (16B aligned)
    short* A  = (short*)S;                      // irfft A: 16016*704 bf16
    float* frames = S1;                         // 16016*320 floats over dead S1+S2

    int ngen = 2*FB*CC + 384*640 + NFFT*LDK;    // fused table generation
    k_gen<<<dim3((ngen + 255)/256), dim3(256), 0, stream>>>(win, htab, Bts, Bt);
    k_stats1<<<dim3(BB*RBLK), dim3(256), 0, stream>>>(in, part);
    k_stats2<<<dim3(BB), dim3(128), 0, stream>>>(part, mean, invmax);
    k_anorm<<<dim3((BB*CC*(NPAD/8) + 255)/256), dim3(256), 0, stream>>>(in, mean, invmax, Ahi, Alo);
    k_gstft<<<dim3(BB*TP*CC/64, 6), dim3(256), 0, stream>>>(Ahi, Alo, Bts, S);
    k_scan<<<dim3(2*BB*FB), dim3(512), 0, stream>>>(S, htab, S1, S2);
    k_pack<<<dim3(512), dim3(256), 0, stream>>>(S1, S2, A);
    k_gemm<<<dim3((GM + 63)/64, NFFT/64), dim3(256), 0, stream>>>(A, Bt, frames);
    k_ola<<<dim3((2*BB*(LL/4) + 255)/256), dim3(256), 0, stream>>>(frames, (float*)d_out);
}

// Round 5
// 209.471 us; speedup vs baseline: 1.4882x; 1.0522x over previous
//
#include <hip/hip_runtime.h>
#include <hip/hip_bf16.h>
#include <math.h>

#define BB 8
#define LL 160000
#define CC 4
#define NFFT 320
#define HOP 160
#define FB 161          // rfft bins
#define TT 1001         // frames
#define TP 1024         // padded frames per batch (t-slots) for STFT GEMM
#define RBLK 128        // stats blocks per batch
#define PI_D 3.14159265358979323846
#define NPAD 160320     // reflect-padded samples per (b,c): p in [-160, 160159]

#define SCH 504         // scan outputs per half-block (2 halves cover 1001); CH=1 x 512 threads
#define KWARM 4         // warm-up frames; tail weight 0.05^4 ~ 6e-6 rel << bf16 error floor (4.9e-4)

#define GM 16016        // irfft GEMM M = 2*BB*TT rows (beam,b,t)
#define KSEC 352        // irfft padded K per split-section (322 used)
#define LDK 704         // irfft A/Bt leading dim = 2 sections
#define KT 11           // irfft K-tiles of 32 per section
// R18 == R17 resubmitted (R17 bench died at container level; kernel re-audited: no
// barrier divergence, vmcnt bookkeeping sound, all accesses in-bounds, shfl epilogue
// lane math verified).
// R17: 128x128 tiles, 8 waves (4x2 wave grid, 32x64 per wave). R13/R15/R16 all sat at
// ~45us with MfmaUtil ~20% regardless of sync scheme -> bound was work-per-phase
// (58 cyc MFMA vs ~900 cyc phase). 128^2 gives 233 cyc MFMA/SIMD/phase + halves
// staged traffic. Epilogue: NO Ct LDS transpose — each lane's acc column holds all
// 4 channels of one t; (re,im) pairing via __shfl_xor(.,1) with the adjacent lane
// (partner shares t/kg guards -> shuffle-safe). S layout now [b][k][h][t] (plane-
// split) so stores keep full 64B-line utilization; k_scan stager reads 2 planes.
// Keep R16's 2-deep counted-vmcnt DMA pipeline (vmcnt BEFORE barrier: each wave
// drains its own oldest STG, barrier makes it collective).
// R14 lesson (direct-global gather, 47->115us): LDS staging is a latency-decoupling
// pipeline, not just a cache — do not remove it.
// LIFETIME NOTE (R13 bug): Bt/Bts must NOT live in the S region — k_gstft overwrites
// ALL of S. Both live in d_out's head (dead until k_ola fully overwrites at the end).

typedef __attribute__((ext_vector_type(8))) short bf16x8;
typedef __attribute__((ext_vector_type(4))) float f32x4;

__device__ __forceinline__ void ldsdma16(const short* g, short* l){
    // wave-level DMA: per-lane global src, wave-uniform LDS base + lane*16B
    __builtin_amdgcn_global_load_lds((const __attribute__((address_space(1))) void*)g,
                                     (__attribute__((address_space(3))) void*)l, 16, 0, 0);
}

__device__ __forceinline__ float2 cmulf(float2 a, float2 b){           // a*b
    return make_float2(a.x*b.x - a.y*b.y, a.x*b.y + a.y*b.x);
}
__device__ __forceinline__ float2 cmulcj(float2 a, float2 b){          // a*conj(b)
    return make_float2(a.x*b.x + a.y*b.y, a.y*b.x - a.x*b.y);
}
__device__ __forceinline__ float2 cjmul(float2 a, float2 b){           // conj(a)*b
    return make_float2(a.x*b.x + a.y*b.y, a.x*b.y - a.y*b.x);
}
__device__ __forceinline__ float2 csub(float2 a, float2 b){ return make_float2(a.x-b.x, a.y-b.y); }
__device__ __forceinline__ float2 cscale(float2 a, float s){ return make_float2(a.x*s, a.y*s); }
__device__ __forceinline__ float2 cdivf(float2 a, float2 b){           // a/b
    float inv = 1.0f/(b.x*b.x + b.y*b.y);
    return make_float2((a.x*b.x + a.y*b.y)*inv, (a.y*b.x - a.x*b.y)*inv);
}
__device__ __forceinline__ short bf_hi(float v){
    __hip_bfloat16 h = __float2bfloat16(v);
    short s; __builtin_memcpy(&s, &h, 2); return s;
}
__device__ __forceinline__ short bf_lo(float v){
    __hip_bfloat16 h = __float2bfloat16(v);
    float r = v - __bfloat162float(h);
    __hip_bfloat16 l = __float2bfloat16(r);
    short s; __builtin_memcpy(&s, &l, 2); return s;
}

// ---------- fused table generator: htab | Bts (STFT B) | Bt (irfft B) ----------
__global__ void k_gen(const float* __restrict__ win, float* __restrict__ htab,
                      short* __restrict__ Bts, short* __restrict__ Bt){
    int gid = blockIdx.x*256 + threadIdx.x;
    if (gid < 2*FB*CC){
        int i = gid;
        int c = i & 3;
        int k = (i >> 2) % FB;
        int m = i / (FB*CC);
        double coef = 2.0*PI_D*50.0*0.027*sin(40.0*PI_D/180.0)/340.0;
        double sgn = (m == 0) ? -1.0 : 1.0;
        double ph = sgn*coef*(double)k*(double)c;
        double s, c2;
        sincos(ph, &s, &c2);
        ((float2*)htab)[i] = make_float2((float)c2, (float)s);
        return;
    }
    gid -= 2*FB*CC;
    if (gid < 384*640){
        int col = gid / 640, kk = gid % 640;
        int n = (kk >= 320) ? kk - 320 : kk;
        int sec = (kk >= 320) ? 1 : 0;
        float v = 0.f;
        if (col < 2*FB){
            int k = col >> 1;
            double th = 2.0*PI_D*(double)k*(double)n/320.0;
            double s, co; sincos(th, &s, &co);
            double tw = (col & 1) ? -s : co;
            v = (float)((double)win[n]*tw);
        }
        Bts[gid] = sec ? bf_lo(v) : bf_hi(v);
        return;
    }
    gid -= 384*640;
    if (gid < NFFT*LDK){
        int n = gid / LDK, kk = gid % LDK;
        int sec = (kk >= KSEC) ? 1 : 0;
        int kk2 = kk - (sec ? KSEC : 0);
        float v = 0.f;
        if (kk2 < 2*FB){
            int bin = kk2 >> 1;
            double c = ((bin == 0 || bin == 160) ? 1.0 : 2.0) / 320.0;
            double th = 2.0*PI_D*(double)bin*(double)n/320.0;
            double s, co; sincos(th, &s, &co);
            v = (float)((kk2 & 1) ? -c*s : c*co);
        }
        Bt[(size_t)n*LDK + kk] = sec ? bf_lo(v) : bf_hi(v);
    }
}

// ---------- stage 1: per-(b,chunk) partial {sum4, min4, max4} ----------
__global__ __launch_bounds__(256) void k_stats1(const float* __restrict__ in, float* __restrict__ part){
    __shared__ float4 s4[256];
    __shared__ float4 mn4[256];
    __shared__ float4 mx4[256];
    int b = blockIdx.x / RBLK, chunk = blockIdx.x % RBLK;
    int tid = threadIdx.x;
    const float4* p = (const float4*)(in + (size_t)b*LL*CC);
    const int per = LL / RBLK;
    int start = chunk*per;
    float4 s  = make_float4(0.f,0.f,0.f,0.f);
    float4 mn = make_float4( 3.4e38f, 3.4e38f, 3.4e38f, 3.4e38f);
    float4 mx = make_float4(-3.4e38f,-3.4e38f,-3.4e38f,-3.4e38f);
    for (int i = start + tid; i < start + per; i += 256){
        float4 v = p[i];
        s.x += v.x; s.y += v.y; s.z += v.z; s.w += v.w;
        mn.x = fminf(mn.x, v.x); mn.y = fminf(mn.y, v.y); mn.z = fminf(mn.z, v.z); mn.w = fminf(mn.w, v.w);
        mx.x = fmaxf(mx.x, v.x); mx.y = fmaxf(mx.y, v.y); mx.z = fmaxf(mx.z, v.z); mx.w = fmaxf(mx.w, v.w);
    }
    s4[tid] = s; mn4[tid] = mn; mx4[tid] = mx;
    __syncthreads();
    for (int st = 128; st >= 1; st >>= 1){
        if (tid < st){
            float4 a = s4[tid], c = s4[tid+st];
            s4[tid] = make_float4(a.x+c.x, a.y+c.y, a.z+c.z, a.w+c.w);
            float4 d = mn4[tid], e = mn4[tid+st];
            mn4[tid] = make_float4(fminf(d.x,e.x), fminf(d.y,e.y), fminf(d.z,e.z), fminf(d.w,e.w));
            float4 f = mx4[tid], g = mx4[tid+st];
            mx4[tid] = make_float4(fmaxf(f.x,g.x), fmaxf(f.y,g.y), fmaxf(f.z,g.z), fmaxf(f.w,g.w));
        }
        __syncthreads();
    }
    if (tid == 0){
        float* dst = part + (size_t)(b*RBLK + chunk)*12;
        float4 a = s4[0], d = mn4[0], f = mx4[0];
        dst[0]=a.x; dst[1]=a.y; dst[2]=a.z; dst[3]=a.w;
        dst[4]=d.x; dst[5]=d.y; dst[6]=d.z; dst[7]=d.w;
        dst[8]=f.x; dst[9]=f.y; dst[10]=f.z; dst[11]=f.w;
    }
}

// ---------- stage 2: finalize mean + invmax per batch ----------
__global__ __launch_bounds__(128) void k_stats2(const float* __restrict__ part,
                                                float* __restrict__ mean, float* __restrict__ invmax){
    __shared__ float4 s4[128];
    __shared__ float4 mn4[128];
    __shared__ float4 mx4[128];
    int b = blockIdx.x, tid = threadIdx.x;
    const float* src = part + (size_t)(b*RBLK + tid)*12;
    s4[tid]  = make_float4(src[0], src[1], src[2], src[3]);
    mn4[tid] = make_float4(src[4], src[5], src[6], src[7]);
    mx4[tid] = make_float4(src[8], src[9], src[10], src[11]);
    __syncthreads();
    for (int st = 64; st >= 1; st >>= 1){
        if (tid < st){
            float4 a = s4[tid], c = s4[tid+st];
            s4[tid] = make_float4(a.x+c.x, a.y+c.y, a.z+c.z, a.w+c.w);
            float4 d = mn4[tid], e = mn4[tid+st];
            mn4[tid] = make_float4(fminf(d.x,e.x), fminf(d.y,e.y), fminf(d.z,e.z), fminf(d.w,e.w));
            float4 f = mx4[tid], g = mx4[tid+st];
            mx4[tid] = make_float4(fmaxf(f.x,g.x), fmaxf(f.y,g.y), fmaxf(f.z,g.z), fmaxf(f.w,g.w));
        }
        __syncthreads();
    }
    if (tid == 0){
        float4 sum = s4[0], mn = mn4[0], mx = mx4[0];
        float m0 = sum.x*(1.0f/LL), m1 = sum.y*(1.0f/LL), m2 = sum.z*(1.0f/LL), m3 = sum.w*(1.0f/LL);
        mean[b*4+0]=m0; mean[b*4+1]=m1; mean[b*4+2]=m2; mean[b*4+3]=m3;
        float a0 = fmaxf(mx.x - m0, m0 - mn.x);
        float a1 = fmaxf(mx.y - m1, m1 - mn.y);
        float a2 = fmaxf(mx.z - m2, m2 - mn.z);
        float a3 = fmaxf(mx.w - m3, m3 - mn.w);
        invmax[b] = 1.0f / fmaxf(fmaxf(a0, a1), fmaxf(a2, a3));
    }
}

// ---------- A-normalize: reflect-padded normalized bf16 hi/lo planes Ahi/Alo[b][c][NPAD] ----------
__global__ __launch_bounds__(256) void k_anorm(const float* __restrict__ in,
        const float* __restrict__ mean, const float* __restrict__ invmax,
        short* __restrict__ Ahi, short* __restrict__ Alo){
    int gid = blockIdx.x*256 + threadIdx.x;
    if (gid >= BB*CC*(NPAD/8)) return;
    int p8 = gid % (NPAD/8);
    int bc = gid / (NPAD/8);
    int b = bc >> 2;
    float mc = mean[bc];
    float iv = invmax[b];
    const float* px = in + (size_t)b*LL*CC + (bc & 3);
    bf16x8 h8, l8;
    #pragma unroll
    for (int j = 0; j < 8; ++j){
        int p = p8*8 + j - 160;
        int m2 = p < 0 ? -p : (p >= LL ? 2*LL - 2 - p : p);
        float v = (px[(size_t)m2*CC] - mc) * iv;
        __hip_bfloat16 h = __float2bfloat16(v);
        float r = v - __bfloat162float(h);
        __hip_bfloat16 l = __float2bfloat16(r);
        short hs, ls; __builtin_memcpy(&hs, &h, 2); __builtin_memcpy(&ls, &l, 2);
        h8[j] = hs; l8[j] = ls;
    }
    size_t o = (size_t)bc*NPAD + (size_t)p8*8;
    *(bf16x8*)&Ahi[o] = h8;
    *(bf16x8*)&Alo[o] = l8;
}

// ---------- STFT as MFMA GEMM, R17: 128x128 tile, 8 waves, shfl epilogue ----------
// rows=(b,t,c), cols=(k,ri). LDS per buffer: Ah|Al|Bh|Bl, each 128 rows x 32 shorts
// (64B linear rows, DMA-written). Swizzle: LDS slot s of row r holds k-chunk
// s ^ ((r>>1)&3); reader at (row r, chunk quad) reads slot quad ^ ((r>>1)&3)
// — for all row patterns here, (r>>1)&3 == (l15>>1)&3.
// S out layout: complex S[b][k][h][t] (h = channel-pair), float4 per (b,k,h,t)
__global__ __launch_bounds__(512, 4) void k_gstft(const short* __restrict__ Ahi, const short* __restrict__ Alo,
        const short* __restrict__ Bts, float* __restrict__ S){
    __shared__ short stage[32768];           // 64 KB: 2 buffers x (Ah|Al|Bh|Bl) x 4096 shorts
    int tid = threadIdx.x;
    int row0 = blockIdx.x*128;               // over b*TP*CC rows
    int col0 = blockIdx.y*128;
    int b  = row0 >> 12;                     // TP*CC = 4096 rows per batch
    int t0 = (row0 & 4095) >> 2;             // in {0,32,...,992} — always < TT
    int wave = tid >> 6, lane = tid & 63;
    int wm = wave >> 1, wn = wave & 1;       // 4x2 wave grid: 32 rows x 64 cols each
    int l15 = lane & 15, quad = lane >> 4;
    // ---- staging addresses (per lane): wave w stages rows w*16..w*16+15 ----
    int rowS  = wave*16 + (lane >> 2);       // staged LDS row 0..127
    int chunk = (lane & 3) ^ ((lane >> 3) & 3);   // pre-swizzled global k-chunk
    int tls = t0 + (rowS >> 2); if (tls >= TT) tls = TT - 1;   // clamp; stores guarded later
    size_t gao = (size_t)(b*4 + (rowS & 3))*NPAD + (size_t)tls*160 + chunk*8;
    const short* gAh = Ahi + gao;
    const short* gAl = Alo + gao;
    const short* gB  = Bts + (size_t)(col0 + rowS)*640 + chunk*8;   // hi; lo at +320
    short* lA = stage + wave*512;            // wave-uniform LDS bases (+plane/buffer offset)
    // ---- read addresses ----
    int sw  = (l15 >> 1) & 3;
    int c0r = (quad ^ sw) * 8;               // swizzled chunk offset (shorts)
    int ra0 = (wm*32 + l15)*32 + c0r;        // A row frag 0; frag 1 at +512
    int rb0 = (wn*64 + l15)*32 + c0r;        // B col frag j at + j*512
    f32x4 c00 = {0.f,0.f,0.f,0.f}, c01 = c00, c02 = c00, c03 = c00;
    f32x4 c10 = c00, c11 = c00, c12 = c00, c13 = c00;

    #define STG(kt_, off_) do{ \
        ldsdma16(gAh + (kt_)*32,       lA + (off_));         \
        ldsdma16(gAl + (kt_)*32,       lA + (off_) + 4096);  \
        ldsdma16(gB  + (kt_)*32,       lA + (off_) + 8192);  \
        ldsdma16(gB  + (kt_)*32 + 320, lA + (off_) + 12288); \
    }while(0)

    STG(0, 0);                               // 2-deep prologue
    STG(1, 16384);
    #pragma unroll
    for (int kt = 0; kt < 10; ++kt){
        int offc = (kt & 1) ? 16384 : 0;
        // wave-local: oldest STG (this kt's buffer) must land; newer stays in flight
        if (kt < 9) asm volatile("s_waitcnt vmcnt(4)" ::: "memory");
        else        asm volatile("s_waitcnt vmcnt(0)" ::: "memory");
        __builtin_amdgcn_s_barrier();        // all waves' data for buf[kt&1] present
        bf16x8 a0h = *(bf16x8*)&stage[offc + ra0];
        bf16x8 a1h = *(bf16x8*)&stage[offc + ra0 + 512];
        bf16x8 a0l = *(bf16x8*)&stage[offc + 4096 + ra0];
        bf16x8 a1l = *(bf16x8*)&stage[offc + 4096 + ra0 + 512];
        bf16x8 b0h = *(bf16x8*)&stage[offc + 8192 + rb0];
        bf16x8 b1h = *(bf16x8*)&stage[offc + 8192 + rb0 + 512];
        bf16x8 b2h = *(bf16x8*)&stage[offc + 8192 + rb0 + 1024];
        bf16x8 b3h = *(bf16x8*)&stage[offc + 8192 + rb0 + 1536];
        bf16x8 b0l = *(bf16x8*)&stage[offc + 12288 + rb0];
        bf16x8 b1l = *(bf16x8*)&stage[offc + 12288 + rb0 + 512];
        bf16x8 b2l = *(bf16x8*)&stage[offc + 12288 + rb0 + 1024];
        bf16x8 b3l = *(bf16x8*)&stage[offc + 12288 + rb0 + 1536];
        asm volatile("s_waitcnt lgkmcnt(0)" ::: "memory");
        __builtin_amdgcn_sched_barrier(0);   // rule #18: pin reads before the reuse barrier
        __builtin_amdgcn_s_barrier();        // all waves done reading buf[kt&1]
        if (kt < 8) STG(kt+2, offc);         // overwrite just-freed buffer; lands in ~2 phases
        c00 = __builtin_amdgcn_mfma_f32_16x16x32_bf16(a0h, b0h, c00, 0, 0, 0);
        c01 = __builtin_amdgcn_mfma_f32_16x16x32_bf16(a0h, b1h, c01, 0, 0, 0);
        c02 = __builtin_amdgcn_mfma_f32_16x16x32_bf16(a0h, b2h, c02, 0, 0, 0);
        c03 = __builtin_amdgcn_mfma_f32_16x16x32_bf16(a0h, b3h, c03, 0, 0, 0);
        c10 = __builtin_amdgcn_mfma_f32_16x16x32_bf16(a1h, b0h, c10, 0, 0, 0);
        c11 = __builtin_amdgcn_mfma_f32_16x16x32_bf16(a1h, b1h, c11, 0, 0, 0);
        c12 = __builtin_amdgcn_mfma_f32_16x16x32_bf16(a1h, b2h, c12, 0, 0, 0);
        c13 = __builtin_amdgcn_mfma_f32_16x16x32_bf16(a1h, b3h, c13, 0, 0, 0);
        c00 = __builtin_amdgcn_mfma_f32_16x16x32_bf16(a0l, b0h, c00, 0, 0, 0);
        c01 = __builtin_amdgcn_mfma_f32_16x16x32_bf16(a0l, b1h, c01, 0, 0, 0);
        c02 = __builtin_amdgcn_mfma_f32_16x16x32_bf16(a0l, b2h, c02, 0, 0, 0);
        c03 = __builtin_amdgcn_mfma_f32_16x16x32_bf16(a0l, b3h, c03, 0, 0, 0);
        c10 = __builtin_amdgcn_mfma_f32_16x16x32_bf16(a1l, b0h, c10, 0, 0, 0);
        c11 = __builtin_amdgcn_mfma_f32_16x16x32_bf16(a1l, b1h, c11, 0, 0, 0);
        c12 = __builtin_amdgcn_mfma_f32_16x16x32_bf16(a1l, b2h, c12, 0, 0, 0);
        c13 = __builtin_amdgcn_mfma_f32_16x16x32_bf16(a1l, b3h, c13, 0, 0, 0);
        c00 = __builtin_amdgcn_mfma_f32_16x16x32_bf16(a0h, b0l, c00, 0, 0, 0);
        c01 = __builtin_amdgcn_mfma_f32_16x16x32_bf16(a0h, b1l, c01, 0, 0, 0);
        c02 = __builtin_amdgcn_mfma_f32_16x16x32_bf16(a0h, b2l, c02, 0, 0, 0);
        c03 = __builtin_amdgcn_mfma_f32_16x16x32_bf16(a0h, b3l, c03, 0, 0, 0);
        c10 = __builtin_amdgcn_mfma_f32_16x16x32_bf16(a1h, b0l, c10, 0, 0, 0);
        c11 = __builtin_amdgcn_mfma_f32_16x16x32_bf16(a1h, b1l, c11, 0, 0, 0);
        c12 = __builtin_amdgcn_mfma_f32_16x16x32_bf16(a1h, b2l, c12, 0, 0, 0);
        c13 = __builtin_amdgcn_mfma_f32_16x16x32_bf16(a1h, b3l, c13, 0, 0, 0);
    }
    #undef STG
    // ---- epilogue: shfl-pair assembly, direct global store (no LDS) ----
    // acc row = wm*32 + quad*4 + r (+16 for c1j): r is the CHANNEL, t = t0+wm*8+quad(+4).
    // Lane pair (l15 even/odd) = (re, im) of bin kgb+8j; shfl_xor(.,1) exchanges.
    // Guards (t, kg) are identical for both lanes of a pair -> shuffle-safe.
    int tq  = t0 + wm*8 + quad;
    int kgb = (col0 >> 1) + wn*32 + (l15 >> 1);
    int h   = l15 & 1;
    float4* S4 = (float4*)S;
    #define EPI(cf, i_, j_) do{ \
        int t = tq + 4*(i_); \
        int kg = kgb + 8*(j_); \
        if (t < TT && kg < FB){ \
            float p0 = __shfl_xor(cf[0], 1); \
            float p1 = __shfl_xor(cf[1], 1); \
            float p2 = __shfl_xor(cf[2], 1); \
            float p3 = __shfl_xor(cf[3], 1); \
            float4 v = h ? make_float4(p2, cf[2], p3, cf[3]) \
                         : make_float4(cf[0], p0, cf[1], p1); \
            S4[((size_t)((b*FB + kg)*2 + h))*TT + t] = v; \
        } \
    }while(0)
    EPI(c00, 0, 0); EPI(c01, 0, 1); EPI(c02, 0, 2); EPI(c03, 0, 3);
    EPI(c10, 1, 0); EPI(c11, 1, 1); EPI(c12, 1, 2); EPI(c13, 1, 3);
    #undef EPI
}

// covariance recurrence update: R = a*R + wg*outer(X), a/wg handle first-frame
#define UPD(first) do{ \
    float aa = (first) ? 0.f : 0.05f; float wg = (first) ? 1.f : 0.95f; \
    float y0x=wg*x0.x, y0y=wg*x0.y, y1x=wg*x1.x, y1y=wg*x1.y; \
    float y2x=wg*x2.x, y2y=wg*x2.y, y3x=wg*x3.x, y3y=wg*x3.y; \
    d0 = aa*d0 + y0x*x0.x + y0y*x0.y; \
    d1 = aa*d1 + y1x*x1.x + y1y*x1.y; \
    d2 = aa*d2 + y2x*x2.x + y2y*x2.y; \
    d3 = aa*d3 + y3x*x3.x + y3y*x3.y; \
    r10.x = aa*r10.x + y1x*x0.x + y1y*x0.y;  r10.y = aa*r10.y + y1y*x0.x - y1x*x0.y; \
    r20.x = aa*r20.x + y2x*x0.x + y2y*x0.y;  r20.y = aa*r20.y + y2y*x0.x - y2x*x0.y; \
    r30.x = aa*r30.x + y3x*x0.x + y3y*x0.y;  r30.y = aa*r30.y + y3y*x0.x - y3x*x0.y; \
    r21.x = aa*r21.x + y2x*x1.x + y2y*x1.y;  r21.y = aa*r21.y + y2y*x1.x - y2x*x1.y; \
    r31.x = aa*r31.x + y3x*x1.x + y3y*x1.y;  r31.y = aa*r31.y + y3y*x1.x - y3x*x1.y; \
    r32.x = aa*r32.x + y3x*x2.x + y3y*x2.y;  r32.y = aa*r32.y + y3y*x2.x - y3x*x2.y; \
}while(0)

// ---------- LDS-staged chunked scan, half-strip; CH=1 x 512 threads ----------
// R17: S input layout is now [b][k][h][t] (two float4 planes per (b,k)).
__global__ __launch_bounds__(512) void k_scan(const float* __restrict__ S, const float* __restrict__ htab,
                      float* __restrict__ S1, float* __restrict__ S2){
    __shared__ float4 tile[1008];     // 16,128 B: swizzled [tbase,te) strip; reused as output buffer
    int bid = blockIdx.x;
    int half = bid & 1;
    int bf = bid >> 1;                // b*FB + f
    int f  = bf % FB;
    int tid = threadIdx.x;
    int tbase = half*SCH;
    int te  = tbase + SCH; if (te > TT) te = TT;
    int nst = 2*(te - tbase);
    const float4* P0 = (const float4*)S + (size_t)(bf*2)*TT;
    const float4* P1 = P0 + TT;
    for (int i = tid; i < nst; i += 512){
        int tt = tbase + (i >> 1);
        tile[i ^ ((i>>4)&7)] = (i & 1) ? P1[tt] : P0[tt];   // interleave planes into tile
    }
    __syncthreads();
    float2 out1, out2;
    int t0 = tbase + tid;
    bool act = (tid < SCH) && (t0 < TT);
    if (act){
        const float2* hp = (const float2*)htab;
        float2 ha0 = hp[f*4+0], ha1 = hp[f*4+1], ha2 = hp[f*4+2], ha3 = hp[f*4+3];
        float2 hb0 = hp[(FB+f)*4+0], hb1 = hp[(FB+f)*4+1], hb2 = hp[(FB+f)*4+2], hb3 = hp[(FB+f)*4+3];
        float d0=0,d1=0,d2=0,d3=0;
        float2 r10={0,0}, r20={0,0}, r30={0,0}, r21={0,0}, r31={0,0}, r32={0,0};
        int ts = t0 - KWARM; if (ts < 0) ts = 0;
        for (int tau = ts; tau < t0; ++tau){
            float4 v0, v1;
            if (tau >= tbase){
                int i0 = 2*(tau - tbase);
                v0 = tile[i0 ^ ((i0>>4)&7)];
                v1 = tile[(i0+1) ^ ((i0>>4)&7)];
            } else {
                v0 = P0[tau];
                v1 = P1[tau];
            }
            float2 x0 = make_float2(v0.x, v0.y), x1 = make_float2(v0.z, v0.w);
            float2 x2 = make_float2(v1.x, v1.y), x3 = make_float2(v1.z, v1.w);
            UPD(tau == 0);
        }
        {
            int t = t0;
            int i0 = 2*(t - tbase);
            float4 v0 = tile[i0 ^ ((i0>>4)&7)];
            float4 v1 = tile[(i0+1) ^ ((i0>>4)&7)];
            float2 x0 = make_float2(v0.x, v0.y), x1 = make_float2(v0.z, v0.w);
            float2 x2 = make_float2(v1.x, v1.y), x3 = make_float2(v1.z, v1.w);
            UPD(t == 0);
            float trc = d0 + d1 + d2 + d3;
            float lam = trc * 0.25f;
            float e0 = d0 + lam, e1 = d1 + lam, e2 = d2 + lam, e3 = d3 + lam;
            float detP = e0*e1 - (r10.x*r10.x + r10.y*r10.y);
            float2 w00 = csub(cscale(r20, e1), cmulf(r10, r21));
            float2 w01 = csub(cscale(r30, e1), cmulf(r10, r31));
            float2 w10 = csub(cscale(r21, e0), cjmul(r10, r20));
            float2 w11 = csub(cscale(r31, e0), cjmul(r10, r30));
            float2 va = cjmul(r30, w00), vb = cjmul(r31, w10);
            float2 V10 = make_float2(va.x + vb.x, -(va.y + vb.y));
            float reV00 = r20.x*w00.x + r20.y*w00.y + r21.x*w10.x + r21.y*w10.y;
            float reV11 = r30.x*w01.x + r30.y*w01.y + r31.x*w11.x + r31.y*w11.y;
            float t00 = detP*e2 - reV00;
            float t11 = detP*e3 - reV11;
            float2 t10 = csub(cscale(r32, detP), V10);
            float detT = t00*t11 - (t10.x*t10.x + t10.y*t10.y);
            #pragma unroll
            for (int m = 0; m < 2; ++m){
                float2 h0 = m ? hb0 : ha0;
                float2 h1 = m ? hb1 : ha1;
                float2 h2 = m ? hb2 : ha2;
                float2 h3 = m ? hb3 : ha3;
                float2 g0 = csub(cscale(h0, e1), cjmul(r10, h1));
                float2 g1 = csub(cscale(h1, e0), cmulf(r10, h0));
                float2 ta = cmulf(r20, g0), tb = cmulf(r21, g1);
                float2 hh0 = make_float2(detP*h2.x - ta.x - tb.x, detP*h2.y - ta.y - tb.y);
                ta = cmulf(r30, g0); tb = cmulf(r31, g1);
                float2 hh1 = make_float2(detP*h3.x - ta.x - tb.x, detP*h3.y - ta.y - tb.y);
                float2 y20 = csub(cscale(hh0, t11), cjmul(t10, hh1));
                float2 y21 = csub(cscale(hh1, t00), cmulf(t10, hh0));
                float2 u20 = cscale(y20, detP), u21 = cscale(y21, detP);
                ta = cmulcj(y20, r20); tb = cmulcj(y21, r30);
                float2 q0 = make_float2(detT*h0.x - ta.x - tb.x, detT*h0.y - ta.y - tb.y);
                ta = cmulcj(y20, r21); tb = cmulcj(y21, r31);
                float2 q1 = make_float2(detT*h1.x - ta.x - tb.x, detT*h1.y - ta.y - tb.y);
                float2 u10 = csub(cscale(q0, e1), cjmul(r10, q1));
                float2 u11 = csub(cscale(q1, e0), cmulf(r10, q0));
                float2 den = cjmul(h0, u10), tmp;
                tmp = cjmul(h1, u11); den.x += tmp.x; den.y += tmp.y;
                tmp = cjmul(h2, u20); den.x += tmp.x; den.y += tmp.y;
                tmp = cjmul(h3, u21); den.x += tmp.x; den.y += tmp.y;
                float2 num = cjmul(u10, x0);
                tmp = cjmul(u11, x1); num.x += tmp.x; num.y += tmp.y;
                tmp = cjmul(u20, x2); num.x += tmp.x; num.y += tmp.y;
                tmp = cjmul(u21, x3); num.x += tmp.x; num.y += tmp.y;
                float2 s = cdivf(num, make_float2(den.x, -den.y));
                if (m) out2 = s; else out1 = s;
            }
        }
    }
    __syncthreads();                      // all tile reads done -> reuse as output buffers
    float2* o1 = (float2*)tile;           // [0..511]
    float2* o2 = ((float2*)tile) + 528;   // [528..1039] (ends at float4 520 <= 1008)
    if (act){
        int lt = t0 - tbase;
        int iw = lt ^ ((lt>>3)&7);        // bank-spread write
        o1[iw] = out1;
        o2[iw] = out2;
    }
    __syncthreads();
    int nout = te - tbase;
    float2* S1g = (float2*)S1 + (size_t)bf*TT + tbase;
    float2* S2g = (float2*)S2 + (size_t)bf*TT + tbase;
    for (int i = tid; i < nout; i += 512){
        int ir = i ^ ((i>>3)&7);
        S1g[i] = o1[ir];
        S2g[i] = o2[ir];
    }
}

// ---------- pack v2 (R8-verified): coalesced LDS transpose. block = (rb, 32-t tile) ----------
__global__ __launch_bounds__(256) void k_pack(const float* __restrict__ S1, const float* __restrict__ S2,
                                              short* __restrict__ A){
    __shared__ short tile[32*708];        // 45,312 B; row = t-in-tile, col = kk (hi 0..351 | lo 352..703)
    int bid = blockIdx.x;                 // rb*32 + tb
    int tb = bid & 31, rb = bid >> 5;
    int t0 = tb*32;
    int beam = rb >> 3, b = rb & 7;
    const float2* Sp = (const float2*)(beam ? S2 : S1) + (size_t)b*FB*TT;
    int tid = threadIdx.x;
    for (int idx = tid; idx < 32*176; idx += 256){
        int bin = idx >> 5, tq = idx & 31;
        int t = t0 + tq;
        float2 s = make_float2(0.f, 0.f);
        if (bin < FB && t < TT) s = Sp[(size_t)bin*TT + t];
        int c0 = 2*bin;
        tile[tq*708 + c0]            = bf_hi(s.x);
        tile[tq*708 + c0 + 1]        = bf_hi(s.y);
        tile[tq*708 + KSEC + c0]     = bf_lo(s.x);
        tile[tq*708 + KSEC + c0 + 1] = bf_lo(s.y);
    }
    __syncthreads();
    for (int idx = tid; idx < 32*176; idx += 256){
        int tq = idx / 176, k4 = idx % 176;
        int t = t0 + tq;
        if (t < TT)
            *(short4*)&A[(size_t)(rb*TT + t)*LDK + k4*4] = *(short4*)&tile[tq*708 + k4*4];
    }
}

// ---------- irfft MFMA GEMM, R17: 128x128 tile, 8 waves, 2-deep counted-vmcnt ----------
// frames[GM,320] = 3-segment bf16 split product. 33 flat steps (seg 0..2 x kt 0..10),
// vmcnt(2) steady-state. Col tile 128 over NFFT=320 -> y=2 block half-wasted but
// amortized; B rows clamped to <NFFT, stores guarded.
__global__ __launch_bounds__(512, 4) void k_gemm(const short* __restrict__ A, const short* __restrict__ Bt,
                                                 float* __restrict__ C){
    __shared__ short sb2[16384];           // 32 KB: 2 buffers x (A|B) x 4096 shorts
    int tid = threadIdx.x;
    int row0 = blockIdx.x * 128;
    int col0 = blockIdx.y * 128;
    int wave = tid >> 6, lane = tid & 63;
    int wm = wave >> 1, wn = wave & 1;     // 4x2 wave grid: 32 rows x 64 cols each
    int l15 = lane & 15, quad = lane >> 4;
    // staging (per lane)
    int rowS  = wave*16 + (lane >> 2);
    int chunk = (lane & 3) ^ ((lane >> 3) & 3);
    int grS = row0 + rowS; if (grS >= GM) grS = GM - 1;       // clamp; stores guarded
    int grB = col0 + rowS; if (grB >= NFFT) grB = NFFT - 1;   // clamp; cols >=320 unused
    const short* gA = A  + (size_t)grS*LDK + chunk*8;
    const short* gB = Bt + (size_t)grB*LDK + chunk*8;
    short* lA = sb2 + wave*512;
    // reads
    int sw  = (l15 >> 1) & 3;
    int c0r = (quad ^ sw) * 8;
    int ra0 = (wm*32 + l15)*32 + c0r;      // frag 1 at +512
    int rb0 = (wn*64 + l15)*32 + c0r;      // frag j at +j*512
    f32x4 c00 = {0.f,0.f,0.f,0.f}, c01 = c00, c02 = c00, c03 = c00;
    f32x4 c10 = c00, c11 = c00, c12 = c00, c13 = c00;

    #define KOF(s_, ka_, kb_) { int sg_ = ((s_) >= 22) ? 2 : ((s_) >= 11) ? 1 : 0; \
        int kt_ = (s_) - sg_*11; \
        ka_ = ((sg_ == 1) ? KSEC : 0) + kt_*32; \
        kb_ = ((sg_ == 2) ? KSEC : 0) + kt_*32; }
    #define STG2(s_, off_) do{ int ka_, kb_; KOF(s_, ka_, kb_); \
        ldsdma16(gA + ka_, lA + (off_));        \
        ldsdma16(gB + kb_, lA + (off_) + 4096); \
    }while(0)

    STG2(0, 0);                            // 2-deep prologue
    STG2(1, 8192);
    #pragma unroll
    for (int s = 0; s < 33; ++s){
        int offc = (s & 1) ? 8192 : 0;
        if (s < 32) asm volatile("s_waitcnt vmcnt(2)" ::: "memory");
        else        asm volatile("s_waitcnt vmcnt(0)" ::: "memory");
        __builtin_amdgcn_s_barrier();
        bf16x8 a0 = *(bf16x8*)&sb2[offc + ra0];
        bf16x8 a1 = *(bf16x8*)&sb2[offc + ra0 + 512];
        bf16x8 b0 = *(bf16x8*)&sb2[offc + 4096 + rb0];
        bf16x8 b1 = *(bf16x8*)&sb2[offc + 4096 + rb0 + 512];
        bf16x8 b2 = *(bf16x8*)&sb2[offc + 4096 + rb0 + 1024];
        bf16x8 b3 = *(bf16x8*)&sb2[offc + 4096 + rb0 + 1536];
        asm volatile("s_waitcnt lgkmcnt(0)" ::: "memory");
        __builtin_amdgcn_sched_barrier(0);
        __builtin_amdgcn_s_barrier();
        if (s < 31) STG2(s+2, offc);
        c00 = __builtin_amdgcn_mfma_f32_16x16x32_bf16(a0, b0, c00, 0, 0, 0);
        c01 = __builtin_amdgcn_mfma_f32_16x16x32_bf16(a0, b1, c01, 0, 0, 0);
        c02 = __builtin_amdgcn_mfma_f32_16x16x32_bf16(a0, b2, c02, 0, 0, 0);
        c03 = __builtin_amdgcn_mfma_f32_16x16x32_bf16(a0, b3, c03, 0, 0, 0);
        c10 = __builtin_amdgcn_mfma_f32_16x16x32_bf16(a1, b0, c10, 0, 0, 0);
        c11 = __builtin_amdgcn_mfma_f32_16x16x32_bf16(a1, b1, c11, 0, 0, 0);
        c12 = __builtin_amdgcn_mfma_f32_16x16x32_bf16(a1, b2, c12, 0, 0, 0);
        c13 = __builtin_amdgcn_mfma_f32_16x16x32_bf16(a1, b3, c13, 0, 0, 0);
    }
    #undef STG2
    #undef KOF
    #pragma unroll
    for (int r = 0; r < 4; ++r){
        int orow0 = row0 + wm*32 + quad*4 + r;
        int oc = col0 + wn*64 + l15;
        if (orow0 < GM){
            if (oc      < NFFT) C[(size_t)orow0*NFFT + oc]      = c00[r];
            if (oc + 16 < NFFT) C[(size_t)orow0*NFFT + oc + 16] = c01[r];
            if (oc + 32 < NFFT) C[(size_t)orow0*NFFT + oc + 32] = c02[r];
            if (oc + 48 < NFFT) C[(size_t)orow0*NFFT + oc + 48] = c03[r];
        }
        if (orow0 + 16 < GM){
            if (oc      < NFFT) C[(size_t)(orow0+16)*NFFT + oc]      = c10[r];
            if (oc + 16 < NFFT) C[(size_t)(orow0+16)*NFFT + oc + 16] = c11[r];
            if (oc + 32 < NFFT) C[(size_t)(orow0+16)*NFFT + oc + 32] = c12[r];
            if (oc + 48 < NFFT) C[(size_t)(orow0+16)*NFFT + oc + 48] = c13[r];
        }
    }
}

// ---------- overlap-add, float4: 4 outputs/thread (wsum==2 in cropped interior) ----------
__global__ __launch_bounds__(256) void k_ola(const float* __restrict__ frames, float* __restrict__ out){
    int gid = blockIdx.x*256 + threadIdx.x;
    if (gid >= 2*BB*(LL/4)) return;
    int o4 = (gid % (LL/4))*4;
    int rb = gid / (LL/4);                 // beam*BB + b
    int i  = o4 + HOP;                     // mult of 4; r in {0,4,...,156}
    int t1 = i / HOP;
    int r  = i - t1*HOP;
    const float4* fb = (const float4*)(frames + (size_t)rb*TT*NFFT);
    float4 a = fb[(t1*NFFT + r) >> 2];
    float4 b = fb[((t1-1)*NFFT + r + HOP) >> 2];
    ((float4*)out)[gid] = make_float4(0.5f*(a.x+b.x), 0.5f*(a.y+b.y), 0.5f*(a.z+b.z), 0.5f*(a.w+b.w));
}

extern "C" void kernel_launch(void* const* d_in, const int* in_sizes, int n_in,
                              void* d_out, int out_size, void* d_ws, size_t ws_size,
                              hipStream_t stream){
    const float* in  = (const float*)d_in[0];   // [B, L, C] fp32
    const float* win = (const float*)d_in[1];   // [320] fp32
    float* ws = (float*)d_ws;
    // ws (floats): mean 32 | invmax 8 | htab 2576 | pad -> header 3072
    //              | S1 (2,578,576) | S2 (2,578,576) | S (10,314,304)   total ~62 MB
    // aliases: part -> S1 head (dead before k_anorm); Ahi/Alo -> S1+S2 (dead after k_gstft);
    //          Bts + Bt -> head of d_out (dead until k_ola fully overwrites; NOT in S — R13 bug);
    //          A_ir -> S (post-scan); frames -> S1/S2 (post-pack)
    float* mean   = ws;
    float* invmax = ws + 32;
    float* htab   = ws + 48;
    float* S1     = ws + 3072;
    size_t nS1 = (size_t)2*BB*FB*TT;            // 2,578,576 floats
    float* S2 = S1 + nS1;
    float* S  = S2 + nS1;                       // 10,314,304 floats
    float* part = S1;
    short* Ahi = (short*)S1;                    // 8*4*160320 = 5,130,240 shorts
    short* Alo = Ahi + (size_t)BB*CC*NPAD;      // total 10,260,480 shorts <= S1+S2 (10,314,304 short-equiv)
    short* Bts = (short*)d_out;                 // 245,760 shorts (= 122,880 floats)
    short* Bt  = (short*)((float*)d_out + 131072); // 225,280 shorts at float-offset 131072 (16B aligned)
    short* A  = (short*)S;                      // irfft A: 16016*704 bf16
    float* frames = S1;                         // 16016*320 floats over dead S1+S2

    int ngen = 2*FB*CC + 384*640 + NFFT*LDK;    // fused table generation
    k_gen<<<dim3((ngen + 255)/256), dim3(256), 0, stream>>>(win, htab, Bts, Bt);
    k_stats1<<<dim3(BB*RBLK), dim3(256), 0, stream>>>(in, part);
    k_stats2<<<dim3(BB), dim3(128), 0, stream>>>(part, mean, invmax);
    k_anorm<<<dim3((BB*CC*(NPAD/8) + 255)/256), dim3(256), 0, stream>>>(in, mean, invmax, Ahi, Alo);
    k_gstft<<<dim3(BB*TP*CC/128, 3), dim3(512), 0, stream>>>(Ahi, Alo, Bts, S);
    k_scan<<<dim3(2*BB*FB), dim3(512), 0, stream>>>(S, htab, S1, S2);
    k_pack<<<dim3(512), dim3(256), 0, stream>>>(S1, S2, A);
    k_gemm<<<dim3((GM + 127)/128, (NFFT + 127)/128), dim3(512), 0, stream>>>(A, Bt, frames);
    k_ola<<<dim3((2*BB*(LL/4) + 255)/256), dim3(256), 0, stream>>>(frames, (float*)d_out);
}

// Round 6
// 194.754 us; speedup vs baseline: 1.6007x; 1.0756x over previous
//
#include <hip/hip_runtime.h>
#include <hip/hip_bf16.h>
#include <math.h>

#define BB 8
#define LL 160000
#define CC 4
#define NFFT 320
#define HOP 160
#define FB 161          // rfft bins
#define TT 1001         // frames
#define TP 1024         // padded frames per batch (t-slots) for STFT GEMM
#define RBLK 128        // stats blocks per batch
#define PI_D 3.14159265358979323846
#define NPAD 160320     // reflect-padded samples per (b,c): p in [-160, 160159]

#define SCH 504         // scan outputs per half-block (2 halves cover 1001); CH=1 x 512 threads
#define KWARM 4         // warm-up frames; tail weight 0.05^4 ~ 6e-6 rel << bf16 error floor (4.9e-4)

#define GM 16016        // irfft GEMM M = 2*BB*TT rows (beam,b,t)
#define KSEC 352        // irfft padded K per split-section (322 used)
#define LDK 704         // irfft A/Bt leading dim = 2 sections
#define KT 11           // irfft K-tiles of 32 per section
// R19: (1) k_anorm coalesced rewrite — old version read 1 channel at stride 16B
//      (4B/16B line = 4x over-fetch); now each thread reads 8 full float4 samples
//      and emits all 4 channel planes (bit-identical math). (2) k_scan: direct
//      coalesced output stores (the LDS o1/o2 bounce was an identity mapping with
//      CH=1) + Q-recurrence (Q = R/0.95, no 0.95 weight mults; solve is scale-
//      invariant) for the 99% of threads with t0>=5. (3) k_gemm: wn=1 waves of the
//      y=2 col-block own cols 320..383 (past NFFT) — skip their ds-reads+MFMAs
//      (wave-uniform branch, barriers uniform).
// R17/R18: 128x128 tiles, 8 waves. R13/R15/R16 sat at ~45us, MfmaUtil ~20%
// regardless of sync scheme -> bound was work-per-phase; 128^2 fixed it (-11us).
// Keep 2-deep counted-vmcnt DMA pipeline (vmcnt BEFORE barrier).
// R14 lesson (direct-global gather, 47->115us): LDS staging is a latency-decoupling
// pipeline, not just a cache — do not remove it.
// LIFETIME NOTE (R13 bug): Bt/Bts must NOT live in the S region — k_gstft overwrites
// ALL of S. Both live in d_out's head (dead until k_ola fully overwrites at the end).

typedef __attribute__((ext_vector_type(8))) short bf16x8;
typedef __attribute__((ext_vector_type(4))) float f32x4;

__device__ __forceinline__ void ldsdma16(const short* g, short* l){
    // wave-level DMA: per-lane global src, wave-uniform LDS base + lane*16B
    __builtin_amdgcn_global_load_lds((const __attribute__((address_space(1))) void*)g,
                                     (__attribute__((address_space(3))) void*)l, 16, 0, 0);
}

__device__ __forceinline__ float2 cmulf(float2 a, float2 b){           // a*b
    return make_float2(a.x*b.x - a.y*b.y, a.x*b.y + a.y*b.x);
}
__device__ __forceinline__ float2 cmulcj(float2 a, float2 b){          // a*conj(b)
    return make_float2(a.x*b.x + a.y*b.y, a.y*b.x - a.x*b.y);
}
__device__ __forceinline__ float2 cjmul(float2 a, float2 b){           // conj(a)*b
    return make_float2(a.x*b.x + a.y*b.y, a.x*b.y - a.y*b.x);
}
__device__ __forceinline__ float2 csub(float2 a, float2 b){ return make_float2(a.x-b.x, a.y-b.y); }
__device__ __forceinline__ float2 cscale(float2 a, float s){ return make_float2(a.x*s, a.y*s); }
__device__ __forceinline__ float2 cdivf(float2 a, float2 b){           // a/b
    float inv = 1.0f/(b.x*b.x + b.y*b.y);
    return make_float2((a.x*b.x + a.y*b.y)*inv, (a.y*b.x - a.x*b.y)*inv);
}
__device__ __forceinline__ short bf_hi(float v){
    __hip_bfloat16 h = __float2bfloat16(v);
    short s; __builtin_memcpy(&s, &h, 2); return s;
}
__device__ __forceinline__ short bf_lo(float v){
    __hip_bfloat16 h = __float2bfloat16(v);
    float r = v - __bfloat162float(h);
    __hip_bfloat16 l = __float2bfloat16(r);
    short s; __builtin_memcpy(&s, &l, 2); return s;
}

// ---------- fused table generator: htab | Bts (STFT B) | Bt (irfft B) ----------
__global__ void k_gen(const float* __restrict__ win, float* __restrict__ htab,
                      short* __restrict__ Bts, short* __restrict__ Bt){
    int gid = blockIdx.x*256 + threadIdx.x;
    if (gid < 2*FB*CC){
        int i = gid;
        int c = i & 3;
        int k = (i >> 2) % FB;
        int m = i / (FB*CC);
        double coef = 2.0*PI_D*50.0*0.027*sin(40.0*PI_D/180.0)/340.0;
        double sgn = (m == 0) ? -1.0 : 1.0;
        double ph = sgn*coef*(double)k*(double)c;
        double s, c2;
        sincos(ph, &s, &c2);
        ((float2*)htab)[i] = make_float2((float)c2, (float)s);
        return;
    }
    gid -= 2*FB*CC;
    if (gid < 384*640){
        int col = gid / 640, kk = gid % 640;
        int n = (kk >= 320) ? kk - 320 : kk;
        int sec = (kk >= 320) ? 1 : 0;
        float v = 0.f;
        if (col < 2*FB){
            int k = col >> 1;
            double th = 2.0*PI_D*(double)k*(double)n/320.0;
            double s, co; sincos(th, &s, &co);
            double tw = (col & 1) ? -s : co;
            v = (float)((double)win[n]*tw);
        }
        Bts[gid] = sec ? bf_lo(v) : bf_hi(v);
        return;
    }
    gid -= 384*640;
    if (gid < NFFT*LDK){
        int n = gid / LDK, kk = gid % LDK;
        int sec = (kk >= KSEC) ? 1 : 0;
        int kk2 = kk - (sec ? KSEC : 0);
        float v = 0.f;
        if (kk2 < 2*FB){
            int bin = kk2 >> 1;
            double c = ((bin == 0 || bin == 160) ? 1.0 : 2.0) / 320.0;
            double th = 2.0*PI_D*(double)bin*(double)n/320.0;
            double s, co; sincos(th, &s, &co);
            v = (float)((kk2 & 1) ? -c*s : c*co);
        }
        Bt[(size_t)n*LDK + kk] = sec ? bf_lo(v) : bf_hi(v);
    }
}

// ---------- stage 1: per-(b,chunk) partial {sum4, min4, max4} ----------
__global__ __launch_bounds__(256) void k_stats1(const float* __restrict__ in, float* __restrict__ part){
    __shared__ float4 s4[256];
    __shared__ float4 mn4[256];
    __shared__ float4 mx4[256];
    int b = blockIdx.x / RBLK, chunk = blockIdx.x % RBLK;
    int tid = threadIdx.x;
    const float4* p = (const float4*)(in + (size_t)b*LL*CC);
    const int per = LL / RBLK;
    int start = chunk*per;
    float4 s  = make_float4(0.f,0.f,0.f,0.f);
    float4 mn = make_float4( 3.4e38f, 3.4e38f, 3.4e38f, 3.4e38f);
    float4 mx = make_float4(-3.4e38f,-3.4e38f,-3.4e38f,-3.4e38f);
    for (int i = start + tid; i < start + per; i += 256){
        float4 v = p[i];
        s.x += v.x; s.y += v.y; s.z += v.z; s.w += v.w;
        mn.x = fminf(mn.x, v.x); mn.y = fminf(mn.y, v.y); mn.z = fminf(mn.z, v.z); mn.w = fminf(mn.w, v.w);
        mx.x = fmaxf(mx.x, v.x); mx.y = fmaxf(mx.y, v.y); mx.z = fmaxf(mx.z, v.z); mx.w = fmaxf(mx.w, v.w);
    }
    s4[tid] = s; mn4[tid] = mn; mx4[tid] = mx;
    __syncthreads();
    for (int st = 128; st >= 1; st >>= 1){
        if (tid < st){
            float4 a = s4[tid], c = s4[tid+st];
            s4[tid] = make_float4(a.x+c.x, a.y+c.y, a.z+c.z, a.w+c.w);
            float4 d = mn4[tid], e = mn4[tid+st];
            mn4[tid] = make_float4(fminf(d.x,e.x), fminf(d.y,e.y), fminf(d.z,e.z), fminf(d.w,e.w));
            float4 f = mx4[tid], g = mx4[tid+st];
            mx4[tid] = make_float4(fmaxf(f.x,g.x), fmaxf(f.y,g.y), fmaxf(f.z,g.z), fmaxf(f.w,g.w));
        }
        __syncthreads();
    }
    if (tid == 0){
        float* dst = part + (size_t)(b*RBLK + chunk)*12;
        float4 a = s4[0], d = mn4[0], f = mx4[0];
        dst[0]=a.x; dst[1]=a.y; dst[2]=a.z; dst[3]=a.w;
        dst[4]=d.x; dst[5]=d.y; dst[6]=d.z; dst[7]=d.w;
        dst[8]=f.x; dst[9]=f.y; dst[10]=f.z; dst[11]=f.w;
    }
}

// ---------- stage 2: finalize mean + invmax per batch ----------
__global__ __launch_bounds__(128) void k_stats2(const float* __restrict__ part,
                                                float* __restrict__ mean, float* __restrict__ invmax){
    __shared__ float4 s4[128];
    __shared__ float4 mn4[128];
    __shared__ float4 mx4[128];
    int b = blockIdx.x, tid = threadIdx.x;
    const float* src = part + (size_t)(b*RBLK + tid)*12;
    s4[tid]  = make_float4(src[0], src[1], src[2], src[3]);
    mn4[tid] = make_float4(src[4], src[5], src[6], src[7]);
    mx4[tid] = make_float4(src[8], src[9], src[10], src[11]);
    __syncthreads();
    for (int st = 64; st >= 1; st >>= 1){
        if (tid < st){
            float4 a = s4[tid], c = s4[tid+st];
            s4[tid] = make_float4(a.x+c.x, a.y+c.y, a.z+c.z, a.w+c.w);
            float4 d = mn4[tid], e = mn4[tid+st];
            mn4[tid] = make_float4(fminf(d.x,e.x), fminf(d.y,e.y), fminf(d.z,e.z), fminf(d.w,e.w));
            float4 f = mx4[tid], g = mx4[tid+st];
            mx4[tid] = make_float4(fmaxf(f.x,g.x), fmaxf(f.y,g.y), fmaxf(f.z,g.z), fmaxf(f.w,g.w));
        }
        __syncthreads();
    }
    if (tid == 0){
        float4 sum = s4[0], mn = mn4[0], mx = mx4[0];
        float m0 = sum.x*(1.0f/LL), m1 = sum.y*(1.0f/LL), m2 = sum.z*(1.0f/LL), m3 = sum.w*(1.0f/LL);
        mean[b*4+0]=m0; mean[b*4+1]=m1; mean[b*4+2]=m2; mean[b*4+3]=m3;
        float a0 = fmaxf(mx.x - m0, m0 - mn.x);
        float a1 = fmaxf(mx.y - m1, m1 - mn.y);
        float a2 = fmaxf(mx.z - m2, m2 - mn.z);
        float a3 = fmaxf(mx.w - m3, m3 - mn.w);
        invmax[b] = 1.0f / fmaxf(fmaxf(a0, a1), fmaxf(a2, a3));
    }
}

// ---------- A-normalize, R19: coalesced — thread = 8 consecutive samples x 4 channels ----------
// Old version read 1 channel at stride 16B (4x over-fetch). Same arithmetic exactly.
__global__ __launch_bounds__(256) void k_anorm(const float* __restrict__ in,
        const float* __restrict__ mean, const float* __restrict__ invmax,
        short* __restrict__ Ahi, short* __restrict__ Alo){
    int gid = blockIdx.x*256 + threadIdx.x;
    if (gid >= BB*(NPAD/8)) return;
    int p8 = gid % (NPAD/8);
    int b  = gid / (NPAD/8);
    float4 mc = *(const float4*)&mean[b*4];
    float iv = invmax[b];
    const float4* px = (const float4*)(in + (size_t)b*LL*CC);   // [LL][4ch]
    bf16x8 h0{}, h1{}, h2{}, h3{}, l0{}, l1{}, l2{}, l3{};
    #pragma unroll
    for (int j = 0; j < 8; ++j){
        int p = p8*8 + j - 160;
        int m2 = p < 0 ? -p : (p >= LL ? 2*LL - 2 - p : p);
        float4 v = px[m2];
        float v0 = (v.x - mc.x)*iv, v1 = (v.y - mc.y)*iv;
        float v2 = (v.z - mc.z)*iv, v3 = (v.w - mc.w)*iv;
        h0[j] = bf_hi(v0); l0[j] = bf_lo(v0);
        h1[j] = bf_hi(v1); l1[j] = bf_lo(v1);
        h2[j] = bf_hi(v2); l2[j] = bf_lo(v2);
        h3[j] = bf_hi(v3); l3[j] = bf_lo(v3);
    }
    size_t o = (size_t)(b*4)*NPAD + (size_t)p8*8;
    *(bf16x8*)&Ahi[o]          = h0;  *(bf16x8*)&Alo[o]          = l0;
    *(bf16x8*)&Ahi[o +   NPAD] = h1;  *(bf16x8*)&Alo[o +   NPAD] = l1;
    *(bf16x8*)&Ahi[o + 2*NPAD] = h2;  *(bf16x8*)&Alo[o + 2*NPAD] = l2;
    *(bf16x8*)&Ahi[o + 3*NPAD] = h3;  *(bf16x8*)&Alo[o + 3*NPAD] = l3;
}

// ---------- STFT as MFMA GEMM: 128x128 tile, 8 waves, shfl epilogue ----------
// rows=(b,t,c), cols=(k,ri). LDS per buffer: Ah|Al|Bh|Bl, each 128 rows x 32 shorts
// (64B linear rows, DMA-written). Swizzle: LDS slot s of row r holds k-chunk
// s ^ ((r>>1)&3); reader at (row r, chunk quad) reads slot quad ^ ((r>>1)&3)
// — for all row patterns here, (r>>1)&3 == (l15>>1)&3.
// S out layout: complex S[b][k][h][t] (h = channel-pair), float4 per (b,k,h,t)
__global__ __launch_bounds__(512, 4) void k_gstft(const short* __restrict__ Ahi, const short* __restrict__ Alo,
        const short* __restrict__ Bts, float* __restrict__ S){
    __shared__ short stage[32768];           // 64 KB: 2 buffers x (Ah|Al|Bh|Bl) x 4096 shorts
    int tid = threadIdx.x;
    int row0 = blockIdx.x*128;               // over b*TP*CC rows
    int col0 = blockIdx.y*128;
    int b  = row0 >> 12;                     // TP*CC = 4096 rows per batch
    int t0 = (row0 & 4095) >> 2;             // in {0,32,...,992} — always < TT
    int wave = tid >> 6, lane = tid & 63;
    int wm = wave >> 1, wn = wave & 1;       // 4x2 wave grid: 32 rows x 64 cols each
    int l15 = lane & 15, quad = lane >> 4;
    // ---- staging addresses (per lane): wave w stages rows w*16..w*16+15 ----
    int rowS  = wave*16 + (lane >> 2);       // staged LDS row 0..127
    int chunk = (lane & 3) ^ ((lane >> 3) & 3);   // pre-swizzled global k-chunk
    int tls = t0 + (rowS >> 2); if (tls >= TT) tls = TT - 1;   // clamp; stores guarded later
    size_t gao = (size_t)(b*4 + (rowS & 3))*NPAD + (size_t)tls*160 + chunk*8;
    const short* gAh = Ahi + gao;
    const short* gAl = Alo + gao;
    const short* gB  = Bts + (size_t)(col0 + rowS)*640 + chunk*8;   // hi; lo at +320
    short* lA = stage + wave*512;            // wave-uniform LDS bases (+plane/buffer offset)
    // ---- read addresses ----
    int sw  = (l15 >> 1) & 3;
    int c0r = (quad ^ sw) * 8;               // swizzled chunk offset (shorts)
    int ra0 = (wm*32 + l15)*32 + c0r;        // A row frag 0; frag 1 at +512
    int rb0 = (wn*64 + l15)*32 + c0r;        // B col frag j at + j*512
    f32x4 c00 = {0.f,0.f,0.f,0.f}, c01 = c00, c02 = c00, c03 = c00;
    f32x4 c10 = c00, c11 = c00, c12 = c00, c13 = c00;

    #define STG(kt_, off_) do{ \
        ldsdma16(gAh + (kt_)*32,       lA + (off_));         \
        ldsdma16(gAl + (kt_)*32,       lA + (off_) + 4096);  \
        ldsdma16(gB  + (kt_)*32,       lA + (off_) + 8192);  \
        ldsdma16(gB  + (kt_)*32 + 320, lA + (off_) + 12288); \
    }while(0)

    STG(0, 0);                               // 2-deep prologue
    STG(1, 16384);
    #pragma unroll
    for (int kt = 0; kt < 10; ++kt){
        int offc = (kt & 1) ? 16384 : 0;
        // wave-local: oldest STG (this kt's buffer) must land; newer stays in flight
        if (kt < 9) asm volatile("s_waitcnt vmcnt(4)" ::: "memory");
        else        asm volatile("s_waitcnt vmcnt(0)" ::: "memory");
        __builtin_amdgcn_s_barrier();        // all waves' data for buf[kt&1] present
        bf16x8 a0h = *(bf16x8*)&stage[offc + ra0];
        bf16x8 a1h = *(bf16x8*)&stage[offc + ra0 + 512];
        bf16x8 a0l = *(bf16x8*)&stage[offc + 4096 + ra0];
        bf16x8 a1l = *(bf16x8*)&stage[offc + 4096 + ra0 + 512];
        bf16x8 b0h = *(bf16x8*)&stage[offc + 8192 + rb0];
        bf16x8 b1h = *(bf16x8*)&stage[offc + 8192 + rb0 + 512];
        bf16x8 b2h = *(bf16x8*)&stage[offc + 8192 + rb0 + 1024];
        bf16x8 b3h = *(bf16x8*)&stage[offc + 8192 + rb0 + 1536];
        bf16x8 b0l = *(bf16x8*)&stage[offc + 12288 + rb0];
        bf16x8 b1l = *(bf16x8*)&stage[offc + 12288 + rb0 + 512];
        bf16x8 b2l = *(bf16x8*)&stage[offc + 12288 + rb0 + 1024];
        bf16x8 b3l = *(bf16x8*)&stage[offc + 12288 + rb0 + 1536];
        asm volatile("s_waitcnt lgkmcnt(0)" ::: "memory");
        __builtin_amdgcn_sched_barrier(0);   // rule #18: pin reads before the reuse barrier
        __builtin_amdgcn_s_barrier();        // all waves done reading buf[kt&1]
        if (kt < 8) STG(kt+2, offc);         // overwrite just-freed buffer; lands in ~2 phases
        c00 = __builtin_amdgcn_mfma_f32_16x16x32_bf16(a0h, b0h, c00, 0, 0, 0);
        c01 = __builtin_amdgcn_mfma_f32_16x16x32_bf16(a0h, b1h, c01, 0, 0, 0);
        c02 = __builtin_amdgcn_mfma_f32_16x16x32_bf16(a0h, b2h, c02, 0, 0, 0);
        c03 = __builtin_amdgcn_mfma_f32_16x16x32_bf16(a0h, b3h, c03, 0, 0, 0);
        c10 = __builtin_amdgcn_mfma_f32_16x16x32_bf16(a1h, b0h, c10, 0, 0, 0);
        c11 = __builtin_amdgcn_mfma_f32_16x16x32_bf16(a1h, b1h, c11, 0, 0, 0);
        c12 = __builtin_amdgcn_mfma_f32_16x16x32_bf16(a1h, b2h, c12, 0, 0, 0);
        c13 = __builtin_amdgcn_mfma_f32_16x16x32_bf16(a1h, b3h, c13, 0, 0, 0);
        c00 = __builtin_amdgcn_mfma_f32_16x16x32_bf16(a0l, b0h, c00, 0, 0, 0);
        c01 = __builtin_amdgcn_mfma_f32_16x16x32_bf16(a0l, b1h, c01, 0, 0, 0);
        c02 = __builtin_amdgcn_mfma_f32_16x16x32_bf16(a0l, b2h, c02, 0, 0, 0);
        c03 = __builtin_amdgcn_mfma_f32_16x16x32_bf16(a0l, b3h, c03, 0, 0, 0);
        c10 = __builtin_amdgcn_mfma_f32_16x16x32_bf16(a1l, b0h, c10, 0, 0, 0);
        c11 = __builtin_amdgcn_mfma_f32_16x16x32_bf16(a1l, b1h, c11, 0, 0, 0);
        c12 = __builtin_amdgcn_mfma_f32_16x16x32_bf16(a1l, b2h, c12, 0, 0, 0);
        c13 = __builtin_amdgcn_mfma_f32_16x16x32_bf16(a1l, b3h, c13, 0, 0, 0);
        c00 = __builtin_amdgcn_mfma_f32_16x16x32_bf16(a0h, b0l, c00, 0, 0, 0);
        c01 = __builtin_amdgcn_mfma_f32_16x16x32_bf16(a0h, b1l, c01, 0, 0, 0);
        c02 = __builtin_amdgcn_mfma_f32_16x16x32_bf16(a0h, b2l, c02, 0, 0, 0);
        c03 = __builtin_amdgcn_mfma_f32_16x16x32_bf16(a0h, b3l, c03, 0, 0, 0);
        c10 = __builtin_amdgcn_mfma_f32_16x16x32_bf16(a1h, b0l, c10, 0, 0, 0);
        c11 = __builtin_amdgcn_mfma_f32_16x16x32_bf16(a1h, b1l, c11, 0, 0, 0);
        c12 = __builtin_amdgcn_mfma_f32_16x16x32_bf16(a1h, b2l, c12, 0, 0, 0);
        c13 = __builtin_amdgcn_mfma_f32_16x16x32_bf16(a1h, b3l, c13, 0, 0, 0);
    }
    #undef STG
    // ---- epilogue: shfl-pair assembly, direct global store (no LDS) ----
    int tq  = t0 + wm*8 + quad;
    int kgb = (col0 >> 1) + wn*32 + (l15 >> 1);
    int h   = l15 & 1;
    float4* S4 = (float4*)S;
    #define EPI(cf, i_, j_) do{ \
        int t = tq + 4*(i_); \
        int kg = kgb + 8*(j_); \
        if (t < TT && kg < FB){ \
            float p0 = __shfl_xor(cf[0], 1); \
            float p1 = __shfl_xor(cf[1], 1); \
            float p2 = __shfl_xor(cf[2], 1); \
            float p3 = __shfl_xor(cf[3], 1); \
            float4 v = h ? make_float4(p2, cf[2], p3, cf[3]) \
                         : make_float4(cf[0], p0, cf[1], p1); \
            S4[((size_t)((b*FB + kg)*2 + h))*TT + t] = v; \
        } \
    }while(0)
    EPI(c00, 0, 0); EPI(c01, 0, 1); EPI(c02, 0, 2); EPI(c03, 0, 3);
    EPI(c10, 1, 0); EPI(c11, 1, 1); EPI(c12, 1, 2); EPI(c13, 1, 3);
    #undef EPI
}

// covariance recurrence, original weighted form (first-frame handling): R = a*R + wg*outer(X)
#define UPD(first) do{ \
    float aa = (first) ? 0.f : 0.05f; float wg = (first) ? 1.f : 0.95f; \
    float y0x=wg*x0.x, y0y=wg*x0.y, y1x=wg*x1.x, y1y=wg*x1.y; \
    float y2x=wg*x2.x, y2y=wg*x2.y, y3x=wg*x3.x, y3y=wg*x3.y; \
    d0 = aa*d0 + y0x*x0.x + y0y*x0.y; \
    d1 = aa*d1 + y1x*x1.x + y1y*x1.y; \
    d2 = aa*d2 + y2x*x2.x + y2y*x2.y; \
    d3 = aa*d3 + y3x*x3.x + y3y*x3.y; \
    r10.x = aa*r10.x + y1x*x0.x + y1y*x0.y;  r10.y = aa*r10.y + y1y*x0.x - y1x*x0.y; \
    r20.x = aa*r20.x + y2x*x0.x + y2y*x0.y;  r20.y = aa*r20.y + y2y*x0.x - y2x*x0.y; \
    r30.x = aa*r30.x + y3x*x0.x + y3y*x0.y;  r30.y = aa*r30.y + y3y*x0.x - y3x*x0.y; \
    r21.x = aa*r21.x + y2x*x1.x + y2y*x1.y;  r21.y = aa*r21.y + y2y*x1.x - y2x*x1.y; \
    r31.x = aa*r31.x + y3x*x1.x + y3y*x1.y;  r31.y = aa*r31.y + y3y*x1.x - y3x*x1.y; \
    r32.x = aa*r32.x + y3x*x2.x + y3y*x2.y;  r32.y = aa*r32.y + y3y*x2.x - y3x*x2.y; \
}while(0)

// Q-form (R19): Q = 0.05*Q + outer(X); Q = R/0.95 exactly when every frame in the
// truncated window has weight 0.95 (t0 >= 5 -> no first-frame in window). The solve
// is scale-invariant in R, so outputs are identical (up to fp rounding).
#define UPDQ do{ \
    d0 = 0.05f*d0 + x0.x*x0.x + x0.y*x0.y; \
    d1 = 0.05f*d1 + x1.x*x1.x + x1.y*x1.y; \
    d2 = 0.05f*d2 + x2.x*x2.x + x2.y*x2.y; \
    d3 = 0.05f*d3 + x3.x*x3.x + x3.y*x3.y; \
    r10.x = 0.05f*r10.x + x1.x*x0.x + x1.y*x0.y;  r10.y = 0.05f*r10.y + x1.y*x0.x - x1.x*x0.y; \
    r20.x = 0.05f*r20.x + x2.x*x0.x + x2.y*x0.y;  r20.y = 0.05f*r20.y + x2.y*x0.x - x2.x*x0.y; \
    r30.x = 0.05f*r30.x + x3.x*x0.x + x3.y*x0.y;  r30.y = 0.05f*r30.y + x3.y*x0.x - x3.x*x0.y; \
    r21.x = 0.05f*r21.x + x2.x*x1.x + x2.y*x1.y;  r21.y = 0.05f*r21.y + x2.y*x1.x - x2.x*x1.y; \
    r31.x = 0.05f*r31.x + x3.x*x1.x + x3.y*x1.y;  r31.y = 0.05f*r31.y + x3.y*x1.x - x3.x*x1.y; \
    r32.x = 0.05f*r32.x + x3.x*x2.x + x3.y*x2.y;  r32.y = 0.05f*r32.y + x3.y*x2.x - x3.x*x2.y; \
}while(0)

// ---------- LDS-staged chunked scan, half-strip; CH=1 x 512 threads ----------
// S input layout [b][k][h][t] (two float4 planes per (b,k)). R19: direct coalesced
// output stores (dropped LDS bounce + 2 barriers); Q-recurrence for t0>=5.
__global__ __launch_bounds__(512) void k_scan(const float* __restrict__ S, const float* __restrict__ htab,
                      float* __restrict__ S1, float* __restrict__ S2){
    __shared__ float4 tile[1008];     // swizzled [tbase,te) strip
    int bid = blockIdx.x;
    int half = bid & 1;
    int bf = bid >> 1;                // b*FB + f
    int f  = bf % FB;
    int tid = threadIdx.x;
    int tbase = half*SCH;
    int te  = tbase + SCH; if (te > TT) te = TT;
    int nst = 2*(te - tbase);
    const float4* P0 = (const float4*)S + (size_t)(bf*2)*TT;
    const float4* P1 = P0 + TT;
    for (int i = tid; i < nst; i += 512){
        int tt = tbase + (i >> 1);
        tile[i ^ ((i>>4)&7)] = (i & 1) ? P1[tt] : P0[tt];   // interleave planes into tile
    }
    __syncthreads();
    int t0 = tbase + tid;
    bool act = (tid < SCH) && (t0 < TT);
    if (act){
        const float2* hp = (const float2*)htab;
        float2 ha0 = hp[f*4+0], ha1 = hp[f*4+1], ha2 = hp[f*4+2], ha3 = hp[f*4+3];
        float2 hb0 = hp[(FB+f)*4+0], hb1 = hp[(FB+f)*4+1], hb2 = hp[(FB+f)*4+2], hb3 = hp[(FB+f)*4+3];
        float d0=0,d1=0,d2=0,d3=0;
        float2 r10={0,0}, r20={0,0}, r30={0,0}, r21={0,0}, r31={0,0}, r32={0,0};
        float2 x0, x1, x2, x3;
        #define LOADX(tau_) do{ float4 v0_, v1_; \
            if ((tau_) >= tbase){ int i0_ = 2*((tau_) - tbase); \
                v0_ = tile[i0_ ^ ((i0_>>4)&7)]; v1_ = tile[(i0_+1) ^ ((i0_>>4)&7)]; } \
            else { v0_ = P0[tau_]; v1_ = P1[tau_]; } \
            x0 = make_float2(v0_.x, v0_.y); x1 = make_float2(v0_.z, v0_.w); \
            x2 = make_float2(v1_.x, v1_.y); x3 = make_float2(v1_.z, v1_.w); \
        }while(0)
        if (t0 >= KWARM + 1){
            #pragma unroll
            for (int u = 0; u <= KWARM; ++u){ LOADX(t0 - KWARM + u); UPDQ; }
        } else {
            for (int tau = 0; tau <= t0; ++tau){ LOADX(tau); UPD(tau == 0); }
        }
        #undef LOADX
        {
            float trc = d0 + d1 + d2 + d3;
            float lam = trc * 0.25f;
            float e0 = d0 + lam, e1 = d1 + lam, e2 = d2 + lam, e3 = d3 + lam;
            float detP = e0*e1 - (r10.x*r10.x + r10.y*r10.y);
            float2 w00 = csub(cscale(r20, e1), cmulf(r10, r21));
            float2 w01 = csub(cscale(r30, e1), cmulf(r10, r31));
            float2 w10 = csub(cscale(r21, e0), cjmul(r10, r20));
            float2 w11 = csub(cscale(r31, e0), cjmul(r10, r30));
            float2 va = cjmul(r30, w00), vb = cjmul(r31, w10);
            float2 V10 = make_float2(va.x + vb.x, -(va.y + vb.y));
            float reV00 = r20.x*w00.x + r20.y*w00.y + r21.x*w10.x + r21.y*w10.y;
            float reV11 = r30.x*w01.x + r30.y*w01.y + r31.x*w11.x + r31.y*w11.y;
            float t00 = detP*e2 - reV00;
            float t11 = detP*e3 - reV11;
            float2 t10 = csub(cscale(r32, detP), V10);
            float detT = t00*t11 - (t10.x*t10.x + t10.y*t10.y);
            float2* S1g = (float2*)S1 + (size_t)bf*TT;
            float2* S2g = (float2*)S2 + (size_t)bf*TT;
            #pragma unroll
            for (int m = 0; m < 2; ++m){
                float2 h0 = m ? hb0 : ha0;
                float2 h1 = m ? hb1 : ha1;
                float2 h2 = m ? hb2 : ha2;
                float2 h3 = m ? hb3 : ha3;
                float2 g0 = csub(cscale(h0, e1), cjmul(r10, h1));
                float2 g1 = csub(cscale(h1, e0), cmulf(r10, h0));
                float2 ta = cmulf(r20, g0), tb = cmulf(r21, g1);
                float2 hh0 = make_float2(detP*h2.x - ta.x - tb.x, detP*h2.y - ta.y - tb.y);
                ta = cmulf(r30, g0); tb = cmulf(r31, g1);
                float2 hh1 = make_float2(detP*h3.x - ta.x - tb.x, detP*h3.y - ta.y - tb.y);
                float2 y20 = csub(cscale(hh0, t11), cjmul(t10, hh1));
                float2 y21 = csub(cscale(hh1, t00), cmulf(t10, hh0));
                float2 u20 = cscale(y20, detP), u21 = cscale(y21, detP);
                ta = cmulcj(y20, r20); tb = cmulcj(y21, r30);
                float2 q0 = make_float2(detT*h0.x - ta.x - tb.x, detT*h0.y - ta.y - tb.y);
                ta = cmulcj(y20, r21); tb = cmulcj(y21, r31);
                float2 q1 = make_float2(detT*h1.x - ta.x - tb.x, detT*h1.y - ta.y - tb.y);
                float2 u10 = csub(cscale(q0, e1), cjmul(r10, q1));
                float2 u11 = csub(cscale(q1, e0), cmulf(r10, q0));
                float2 den = cjmul(h0, u10), tmp;
                tmp = cjmul(h1, u11); den.x += tmp.x; den.y += tmp.y;
                tmp = cjmul(h2, u20); den.x += tmp.x; den.y += tmp.y;
                tmp = cjmul(h3, u21); den.x += tmp.x; den.y += tmp.y;
                float2 num = cjmul(u10, x0);
                tmp = cjmul(u11, x1); num.x += tmp.x; num.y += tmp.y;
                tmp = cjmul(u20, x2); num.x += tmp.x; num.y += tmp.y;
                tmp = cjmul(u21, x3); num.x += tmp.x; num.y += tmp.y;
                float2 s = cdivf(num, make_float2(den.x, -den.y));
                if (m) S2g[t0] = s; else S1g[t0] = s;   // coalesced: tid-consecutive
            }
        }
    }
}

// ---------- pack v2 (R8-verified): coalesced LDS transpose. block = (rb, 32-t tile) ----------
__global__ __launch_bounds__(256) void k_pack(const float* __restrict__ S1, const float* __restrict__ S2,
                                              short* __restrict__ A){
    __shared__ short tile[32*708];        // 45,312 B; row = t-in-tile, col = kk (hi 0..351 | lo 352..703)
    int bid = blockIdx.x;                 // rb*32 + tb
    int tb = bid & 31, rb = bid >> 5;
    int t0 = tb*32;
    int beam = rb >> 3, b = rb & 7;
    const float2* Sp = (const float2*)(beam ? S2 : S1) + (size_t)b*FB*TT;
    int tid = threadIdx.x;
    for (int idx = tid; idx < 32*176; idx += 256){
        int bin = idx >> 5, tq = idx & 31;
        int t = t0 + tq;
        float2 s = make_float2(0.f, 0.f);
        if (bin < FB && t < TT) s = Sp[(size_t)bin*TT + t];
        int c0 = 2*bin;
        tile[tq*708 + c0]            = bf_hi(s.x);
        tile[tq*708 + c0 + 1]        = bf_hi(s.y);
        tile[tq*708 + KSEC + c0]     = bf_lo(s.x);
        tile[tq*708 + KSEC + c0 + 1] = bf_lo(s.y);
    }
    __syncthreads();
    for (int idx = tid; idx < 32*176; idx += 256){
        int tq = idx / 176, k4 = idx % 176;
        int t = t0 + tq;
        if (t < TT)
            *(short4*)&A[(size_t)(rb*TT + t)*LDK + k4*4] = *(short4*)&tile[tq*708 + k4*4];
    }
}

// ---------- irfft MFMA GEMM: 128x128 tile, 8 waves, 2-deep counted-vmcnt ----------
// frames[GM,320] = 3-segment bf16 split product. 33 flat steps (seg 0..2 x kt 0..10),
// vmcnt(2) steady-state. R19: wn=1 waves of the y=2 block own cols 320..383 (past
// NFFT) — skip their reads+MFMAs (wave-uniform; barriers stay uniform).
__global__ __launch_bounds__(512, 4) void k_gemm(const short* __restrict__ A, const short* __restrict__ Bt,
                                                 float* __restrict__ C){
    __shared__ short sb2[16384];           // 32 KB: 2 buffers x (A|B) x 4096 shorts
    int tid = threadIdx.x;
    int row0 = blockIdx.x * 128;
    int col0 = blockIdx.y * 128;
    int wave = tid >> 6, lane = tid & 63;
    int wm = wave >> 1, wn = wave & 1;     // 4x2 wave grid: 32 rows x 64 cols each
    int l15 = lane & 15, quad = lane >> 4;
    bool wlive = (col0 + wn*64) < NFFT;    // y=2,wn=1 waves are fully past NFFT
    // staging (per lane)
    int rowS  = wave*16 + (lane >> 2);
    int chunk = (lane & 3) ^ ((lane >> 3) & 3);
    int grS = row0 + rowS; if (grS >= GM) grS = GM - 1;       // clamp; stores guarded
    int grB = col0 + rowS; if (grB >= NFFT) grB = NFFT - 1;   // clamp; cols >=320 unused
    const short* gA = A  + (size_t)grS*LDK + chunk*8;
    const short* gB = Bt + (size_t)grB*LDK + chunk*8;
    short* lA = sb2 + wave*512;
    // reads
    int sw  = (l15 >> 1) & 3;
    int c0r = (quad ^ sw) * 8;
    int ra0 = (wm*32 + l15)*32 + c0r;      // frag 1 at +512
    int rb0 = (wn*64 + l15)*32 + c0r;      // frag j at +j*512
    f32x4 c00 = {0.f,0.f,0.f,0.f}, c01 = c00, c02 = c00, c03 = c00;
    f32x4 c10 = c00, c11 = c00, c12 = c00, c13 = c00;

    #define KOF(s_, ka_, kb_) { int sg_ = ((s_) >= 22) ? 2 : ((s_) >= 11) ? 1 : 0; \
        int kt_ = (s_) - sg_*11; \
        ka_ = ((sg_ == 1) ? KSEC : 0) + kt_*32; \
        kb_ = ((sg_ == 2) ? KSEC : 0) + kt_*32; }
    #define STG2(s_, off_) do{ int ka_, kb_; KOF(s_, ka_, kb_); \
        ldsdma16(gA + ka_, lA + (off_));        \
        ldsdma16(gB + kb_, lA + (off_) + 4096); \
    }while(0)

    STG2(0, 0);                            // 2-deep prologue
    STG2(1, 8192);
    #pragma unroll
    for (int s = 0; s < 33; ++s){
        int offc = (s & 1) ? 8192 : 0;
        if (s < 32) asm volatile("s_waitcnt vmcnt(2)" ::: "memory");
        else        asm volatile("s_waitcnt vmcnt(0)" ::: "memory");
        __builtin_amdgcn_s_barrier();
        bf16x8 a0{}, a1{}, b0{}, b1{}, b2{}, b3{};
        if (wlive){
            a0 = *(bf16x8*)&sb2[offc + ra0];
            a1 = *(bf16x8*)&sb2[offc + ra0 + 512];
            b0 = *(bf16x8*)&sb2[offc + 4096 + rb0];
            b1 = *(bf16x8*)&sb2[offc + 4096 + rb0 + 512];
            b2 = *(bf16x8*)&sb2[offc + 4096 + rb0 + 1024];
            b3 = *(bf16x8*)&sb2[offc + 4096 + rb0 + 1536];
            asm volatile("s_waitcnt lgkmcnt(0)" ::: "memory");
            __builtin_amdgcn_sched_barrier(0);
        }
        __builtin_amdgcn_s_barrier();
        if (s < 31) STG2(s+2, offc);
        if (wlive){
            c00 = __builtin_amdgcn_mfma_f32_16x16x32_bf16(a0, b0, c00, 0, 0, 0);
            c01 = __builtin_amdgcn_mfma_f32_16x16x32_bf16(a0, b1, c01, 0, 0, 0);
            c02 = __builtin_amdgcn_mfma_f32_16x16x32_bf16(a0, b2, c02, 0, 0, 0);
            c03 = __builtin_amdgcn_mfma_f32_16x16x32_bf16(a0, b3, c03, 0, 0, 0);
            c10 = __builtin_amdgcn_mfma_f32_16x16x32_bf16(a1, b0, c10, 0, 0, 0);
            c11 = __builtin_amdgcn_mfma_f32_16x16x32_bf16(a1, b1, c11, 0, 0, 0);
            c12 = __builtin_amdgcn_mfma_f32_16x16x32_bf16(a1, b2, c12, 0, 0, 0);
            c13 = __builtin_amdgcn_mfma_f32_16x16x32_bf16(a1, b3, c13, 0, 0, 0);
        }
    }
    #undef STG2
    #undef KOF
    if (wlive){
        #pragma unroll
        for (int r = 0; r < 4; ++r){
            int orow0 = row0 + wm*32 + quad*4 + r;
            int oc = col0 + wn*64 + l15;
            if (orow0 < GM){
                if (oc      < NFFT) C[(size_t)orow0*NFFT + oc]      = c00[r];
                if (oc + 16 < NFFT) C[(size_t)orow0*NFFT + oc + 16] = c01[r];
                if (oc + 32 < NFFT) C[(size_t)orow0*NFFT + oc + 32] = c02[r];
                if (oc + 48 < NFFT) C[(size_t)orow0*NFFT + oc + 48] = c03[r];
            }
            if (orow0 + 16 < GM){
                if (oc      < NFFT) C[(size_t)(orow0+16)*NFFT + oc]      = c10[r];
                if (oc + 16 < NFFT) C[(size_t)(orow0+16)*NFFT + oc + 16] = c11[r];
                if (oc + 32 < NFFT) C[(size_t)(orow0+16)*NFFT + oc + 32] = c12[r];
                if (oc + 48 < NFFT) C[(size_t)(orow0+16)*NFFT + oc + 48] = c13[r];
            }
        }
    }
}

// ---------- overlap-add, float4: 4 outputs/thread (wsum==2 in cropped interior) ----------
__global__ __launch_bounds__(256) void k_ola(const float* __restrict__ frames, float* __restrict__ out){
    int gid = blockIdx.x*256 + threadIdx.x;
    if (gid >= 2*BB*(LL/4)) return;
    int o4 = (gid % (LL/4))*4;
    int rb = gid / (LL/4);                 // beam*BB + b
    int i  = o4 + HOP;                     // mult of 4; r in {0,4,...,156}
    int t1 = i / HOP;
    int r  = i - t1*HOP;
    const float4* fb = (const float4*)(frames + (size_t)rb*TT*NFFT);
    float4 a = fb[(t1*NFFT + r) >> 2];
    float4 b = fb[((t1-1)*NFFT + r + HOP) >> 2];
    ((float4*)out)[gid] = make_float4(0.5f*(a.x+b.x), 0.5f*(a.y+b.y), 0.5f*(a.z+b.z), 0.5f*(a.w+b.w));
}

extern "C" void kernel_launch(void* const* d_in, const int* in_sizes, int n_in,
                              void* d_out, int out_size, void* d_ws, size_t ws_size,
                              hipStream_t stream){
    const float* in  = (const float*)d_in[0];   // [B, L, C] fp32
    const float* win = (const float*)d_in[1];   // [320] fp32
    float* ws = (float*)d_ws;
    // ws (floats): mean 32 | invmax 8 | htab 2576 | pad -> header 3072
    //              | S1 (2,578,576) | S2 (2,578,576) | S (10,314,304)   total ~62 MB
    // aliases: part -> S1 head (dead before k_anorm); Ahi/Alo -> S1+S2 (dead after k_gstft);
    //          Bts + Bt -> head of d_out (dead until k_ola fully overwrites; NOT in S — R13 bug);
    //          A_ir -> S (post-scan); frames -> S1/S2 (post-pack)
    float* mean   = ws;
    float* invmax = ws + 32;
    float* htab   = ws + 48;
    float* S1     = ws + 3072;
    size_t nS1 = (size_t)2*BB*FB*TT;            // 2,578,576 floats
    float* S2 = S1 + nS1;
    float* S  = S2 + nS1;                       // 10,314,304 floats
    float* part = S1;
    short* Ahi = (short*)S1;                    // 8*4*160320 = 5,130,240 shorts
    short* Alo = Ahi + (size_t)BB*CC*NPAD;      // total 10,260,480 shorts <= S1+S2 (10,314,304 short-equiv)
    short* Bts = (short*)d_out;                 // 245,760 shorts (= 122,880 floats)
    short* Bt  = (short*)((float*)d_out + 131072); // 225,280 shorts at float-offset 131072 (16B aligned)
    short* A  = (short*)S;                      // irfft A: 16016*704 bf16
    float* frames = S1;                         // 16016*320 floats over dead S1+S2

    int ngen = 2*FB*CC + 384*640 + NFFT*LDK;    // fused table generation
    k_gen<<<dim3((ngen + 255)/256), dim3(256), 0, stream>>>(win, htab, Bts, Bt);
    k_stats1<<<dim3(BB*RBLK), dim3(256), 0, stream>>>(in, part);
    k_stats2<<<dim3(BB), dim3(128), 0, stream>>>(part, mean, invmax);
    k_anorm<<<dim3((BB*(NPAD/8) + 255)/256), dim3(256), 0, stream>>>(in, mean, invmax, Ahi, Alo);
    k_gstft<<<dim3(BB*TP*CC/128, 3), dim3(512), 0, stream>>>(Ahi, Alo, Bts, S);
    k_scan<<<dim3(2*BB*FB), dim3(512), 0, stream>>>(S, htab, S1, S2);
    k_pack<<<dim3(512), dim3(256), 0, stream>>>(S1, S2, A);
    k_gemm<<<dim3((GM + 127)/128, (NFFT + 127)/128), dim3(512), 0, stream>>>(A, Bt, frames);
    k_ola<<<dim3((2*BB*(LL/4) + 255)/256), dim3(256), 0, stream>>>(frames, (float*)d_out);
}

// Round 7
// 192.449 us; speedup vs baseline: 1.6199x; 1.0120x over previous
//
#include <hip/hip_runtime.h>
#include <hip/hip_bf16.h>
#include <math.h>

#define BB 8
#define LL 160000
#define CC 4
#define NFFT 320
#define HOP 160
#define FB 161          // rfft bins
#define TT 1001         // frames
#define TP 1024         // padded frames per batch (t-slots) for STFT GEMM
#define RBLK 128        // stats blocks per batch
#define PI_D 3.14159265358979323846
#define NPAD 160320     // reflect-padded samples per (b,c): p in [-160, 160159]

#define KWARM 4         // warm-up frames; tail weight 0.05^5 ~ 3e-7 rel << bf16 error floor (4.9e-4)

#define GM 16016        // irfft GEMM M = 2*BB*TT rows (beam,b,t)
#define KSEC 352        // irfft padded K per split-section (322 used)
#define LDK 704         // irfft A/Bt leading dim = 2 sections
#define KT 11           // irfft K-tiles of 32 per section
// R20: (1) k_scan full-strip: 1 block per (b,f), 512 threads, 2 outputs/thread ->
//      6 UPDs per 2 outputs (was 5 per 1): total UPD work -40%; 32KB LDS = 4 blk/CU.
//      (2) k_gemm 3-buffer ring: data-ready barrier at step s proves all waves
//      finished s-1 ds_reads (own lgkmcnt precedes own s-1 MFMAs) -> STG(s+2) into
//      buf[(s-1)%3] safe with ONE barrier/step (66->33). 48KB LDS, 3 blk/CU.
//      (3) k_gstft: y=2/wn=1 waves cover cols 320..383, real only 320..321 ->
//      guard B-frags 1..3 (wave-uniform) = -12% MFMA work, bit-exact.
// R19: anorm coalesced; scan direct stores + Q-form (scale-invariant solve).
// R17/R18: 128x128 tiles, 8 waves; fixed the work-per-phase bound (~45us -> ~33us).
// Keep 2-deep counted-vmcnt DMA pipeline (vmcnt BEFORE barrier).
// R14 lesson (direct-global gather, 47->115us): LDS staging is a latency-decoupling
// pipeline, not just a cache — do not remove it.
// LIFETIME NOTE (R13 bug): Bt/Bts must NOT live in the S region — k_gstft overwrites
// ALL of S. Both live in d_out's head (dead until k_ola fully overwrites at the end).

typedef __attribute__((ext_vector_type(8))) short bf16x8;
typedef __attribute__((ext_vector_type(4))) float f32x4;

__device__ __forceinline__ void ldsdma16(const short* g, short* l){
    // wave-level DMA: per-lane global src, wave-uniform LDS base + lane*16B
    __builtin_amdgcn_global_load_lds((const __attribute__((address_space(1))) void*)g,
                                     (__attribute__((address_space(3))) void*)l, 16, 0, 0);
}

__device__ __forceinline__ float2 cmulf(float2 a, float2 b){           // a*b
    return make_float2(a.x*b.x - a.y*b.y, a.x*b.y + a.y*b.x);
}
__device__ __forceinline__ float2 cmulcj(float2 a, float2 b){          // a*conj(b)
    return make_float2(a.x*b.x + a.y*b.y, a.y*b.x - a.x*b.y);
}
__device__ __forceinline__ float2 cjmul(float2 a, float2 b){           // conj(a)*b
    return make_float2(a.x*b.x + a.y*b.y, a.x*b.y - a.y*b.x);
}
__device__ __forceinline__ float2 csub(float2 a, float2 b){ return make_float2(a.x-b.x, a.y-b.y); }
__device__ __forceinline__ float2 cscale(float2 a, float s){ return make_float2(a.x*s, a.y*s); }
__device__ __forceinline__ float2 cdivf(float2 a, float2 b){           // a/b
    float inv = 1.0f/(b.x*b.x + b.y*b.y);
    return make_float2((a.x*b.x + a.y*b.y)*inv, (a.y*b.x - a.x*b.y)*inv);
}
__device__ __forceinline__ short bf_hi(float v){
    __hip_bfloat16 h = __float2bfloat16(v);
    short s; __builtin_memcpy(&s, &h, 2); return s;
}
__device__ __forceinline__ short bf_lo(float v){
    __hip_bfloat16 h = __float2bfloat16(v);
    float r = v - __bfloat162float(h);
    __hip_bfloat16 l = __float2bfloat16(r);
    short s; __builtin_memcpy(&s, &l, 2); return s;
}

// ---------- fused table generator: htab | Bts (STFT B) | Bt (irfft B) ----------
__global__ void k_gen(const float* __restrict__ win, float* __restrict__ htab,
                      short* __restrict__ Bts, short* __restrict__ Bt){
    int gid = blockIdx.x*256 + threadIdx.x;
    if (gid < 2*FB*CC){
        int i = gid;
        int c = i & 3;
        int k = (i >> 2) % FB;
        int m = i / (FB*CC);
        double coef = 2.0*PI_D*50.0*0.027*sin(40.0*PI_D/180.0)/340.0;
        double sgn = (m == 0) ? -1.0 : 1.0;
        double ph = sgn*coef*(double)k*(double)c;
        double s, c2;
        sincos(ph, &s, &c2);
        ((float2*)htab)[i] = make_float2((float)c2, (float)s);
        return;
    }
    gid -= 2*FB*CC;
    if (gid < 384*640){
        int col = gid / 640, kk = gid % 640;
        int n = (kk >= 320) ? kk - 320 : kk;
        int sec = (kk >= 320) ? 1 : 0;
        float v = 0.f;
        if (col < 2*FB){
            int k = col >> 1;
            double th = 2.0*PI_D*(double)k*(double)n/320.0;
            double s, co; sincos(th, &s, &co);
            double tw = (col & 1) ? -s : co;
            v = (float)((double)win[n]*tw);
        }
        Bts[gid] = sec ? bf_lo(v) : bf_hi(v);
        return;
    }
    gid -= 384*640;
    if (gid < NFFT*LDK){
        int n = gid / LDK, kk = gid % LDK;
        int sec = (kk >= KSEC) ? 1 : 0;
        int kk2 = kk - (sec ? KSEC : 0);
        float v = 0.f;
        if (kk2 < 2*FB){
            int bin = kk2 >> 1;
            double c = ((bin == 0 || bin == 160) ? 1.0 : 2.0) / 320.0;
            double th = 2.0*PI_D*(double)bin*(double)n/320.0;
            double s, co; sincos(th, &s, &co);
            v = (float)((kk2 & 1) ? -c*s : c*co);
        }
        Bt[(size_t)n*LDK + kk] = sec ? bf_lo(v) : bf_hi(v);
    }
}

// ---------- stage 1: per-(b,chunk) partial {sum4, min4, max4} ----------
__global__ __launch_bounds__(256) void k_stats1(const float* __restrict__ in, float* __restrict__ part){
    __shared__ float4 s4[256];
    __shared__ float4 mn4[256];
    __shared__ float4 mx4[256];
    int b = blockIdx.x / RBLK, chunk = blockIdx.x % RBLK;
    int tid = threadIdx.x;
    const float4* p = (const float4*)(in + (size_t)b*LL*CC);
    const int per = LL / RBLK;
    int start = chunk*per;
    float4 s  = make_float4(0.f,0.f,0.f,0.f);
    float4 mn = make_float4( 3.4e38f, 3.4e38f, 3.4e38f, 3.4e38f);
    float4 mx = make_float4(-3.4e38f,-3.4e38f,-3.4e38f,-3.4e38f);
    for (int i = start + tid; i < start + per; i += 256){
        float4 v = p[i];
        s.x += v.x; s.y += v.y; s.z += v.z; s.w += v.w;
        mn.x = fminf(mn.x, v.x); mn.y = fminf(mn.y, v.y); mn.z = fminf(mn.z, v.z); mn.w = fminf(mn.w, v.w);
        mx.x = fmaxf(mx.x, v.x); mx.y = fmaxf(mx.y, v.y); mx.z = fmaxf(mx.z, v.z); mx.w = fmaxf(mx.w, v.w);
    }
    s4[tid] = s; mn4[tid] = mn; mx4[tid] = mx;
    __syncthreads();
    for (int st = 128; st >= 1; st >>= 1){
        if (tid < st){
            float4 a = s4[tid], c = s4[tid+st];
            s4[tid] = make_float4(a.x+c.x, a.y+c.y, a.z+c.z, a.w+c.w);
            float4 d = mn4[tid], e = mn4[tid+st];
            mn4[tid] = make_float4(fminf(d.x,e.x), fminf(d.y,e.y), fminf(d.z,e.z), fminf(d.w,e.w));
            float4 f = mx4[tid], g = mx4[tid+st];
            mx4[tid] = make_float4(fmaxf(f.x,g.x), fmaxf(f.y,g.y), fmaxf(f.z,g.z), fmaxf(f.w,g.w));
        }
        __syncthreads();
    }
    if (tid == 0){
        float* dst = part + (size_t)(b*RBLK + chunk)*12;
        float4 a = s4[0], d = mn4[0], f = mx4[0];
        dst[0]=a.x; dst[1]=a.y; dst[2]=a.z; dst[3]=a.w;
        dst[4]=d.x; dst[5]=d.y; dst[6]=d.z; dst[7]=d.w;
        dst[8]=f.x; dst[9]=f.y; dst[10]=f.z; dst[11]=f.w;
    }
}

// ---------- stage 2: finalize mean + invmax per batch ----------
__global__ __launch_bounds__(128) void k_stats2(const float* __restrict__ part,
                                                float* __restrict__ mean, float* __restrict__ invmax){
    __shared__ float4 s4[128];
    __shared__ float4 mn4[128];
    __shared__ float4 mx4[128];
    int b = blockIdx.x, tid = threadIdx.x;
    const float* src = part + (size_t)(b*RBLK + tid)*12;
    s4[tid]  = make_float4(src[0], src[1], src[2], src[3]);
    mn4[tid] = make_float4(src[4], src[5], src[6], src[7]);
    mx4[tid] = make_float4(src[8], src[9], src[10], src[11]);
    __syncthreads();
    for (int st = 64; st >= 1; st >>= 1){
        if (tid < st){
            float4 a = s4[tid], c = s4[tid+st];
            s4[tid] = make_float4(a.x+c.x, a.y+c.y, a.z+c.z, a.w+c.w);
            float4 d = mn4[tid], e = mn4[tid+st];
            mn4[tid] = make_float4(fminf(d.x,e.x), fminf(d.y,e.y), fminf(d.z,e.z), fminf(d.w,e.w));
            float4 f = mx4[tid], g = mx4[tid+st];
            mx4[tid] = make_float4(fmaxf(f.x,g.x), fmaxf(f.y,g.y), fmaxf(f.z,g.z), fmaxf(f.w,g.w));
        }
        __syncthreads();
    }
    if (tid == 0){
        float4 sum = s4[0], mn = mn4[0], mx = mx4[0];
        float m0 = sum.x*(1.0f/LL), m1 = sum.y*(1.0f/LL), m2 = sum.z*(1.0f/LL), m3 = sum.w*(1.0f/LL);
        mean[b*4+0]=m0; mean[b*4+1]=m1; mean[b*4+2]=m2; mean[b*4+3]=m3;
        float a0 = fmaxf(mx.x - m0, m0 - mn.x);
        float a1 = fmaxf(mx.y - m1, m1 - mn.y);
        float a2 = fmaxf(mx.z - m2, m2 - mn.z);
        float a3 = fmaxf(mx.w - m3, m3 - mn.w);
        invmax[b] = 1.0f / fmaxf(fmaxf(a0, a1), fmaxf(a2, a3));
    }
}

// ---------- A-normalize (R19): coalesced — thread = 8 consecutive samples x 4 channels ----------
__global__ __launch_bounds__(256) void k_anorm(const float* __restrict__ in,
        const float* __restrict__ mean, const float* __restrict__ invmax,
        short* __restrict__ Ahi, short* __restrict__ Alo){
    int gid = blockIdx.x*256 + threadIdx.x;
    if (gid >= BB*(NPAD/8)) return;
    int p8 = gid % (NPAD/8);
    int b  = gid / (NPAD/8);
    float4 mc = *(const float4*)&mean[b*4];
    float iv = invmax[b];
    const float4* px = (const float4*)(in + (size_t)b*LL*CC);   // [LL][4ch]
    bf16x8 h0{}, h1{}, h2{}, h3{}, l0{}, l1{}, l2{}, l3{};
    #pragma unroll
    for (int j = 0; j < 8; ++j){
        int p = p8*8 + j - 160;
        int m2 = p < 0 ? -p : (p >= LL ? 2*LL - 2 - p : p);
        float4 v = px[m2];
        float v0 = (v.x - mc.x)*iv, v1 = (v.y - mc.y)*iv;
        float v2 = (v.z - mc.z)*iv, v3 = (v.w - mc.w)*iv;
        h0[j] = bf_hi(v0); l0[j] = bf_lo(v0);
        h1[j] = bf_hi(v1); l1[j] = bf_lo(v1);
        h2[j] = bf_hi(v2); l2[j] = bf_lo(v2);
        h3[j] = bf_hi(v3); l3[j] = bf_lo(v3);
    }
    size_t o = (size_t)(b*4)*NPAD + (size_t)p8*8;
    *(bf16x8*)&Ahi[o]          = h0;  *(bf16x8*)&Alo[o]          = l0;
    *(bf16x8*)&Ahi[o +   NPAD] = h1;  *(bf16x8*)&Alo[o +   NPAD] = l1;
    *(bf16x8*)&Ahi[o + 2*NPAD] = h2;  *(bf16x8*)&Alo[o + 2*NPAD] = l2;
    *(bf16x8*)&Ahi[o + 3*NPAD] = h3;  *(bf16x8*)&Alo[o + 3*NPAD] = l3;
}

// ---------- STFT as MFMA GEMM: 128x128 tile, 8 waves, shfl epilogue ----------
// R20: dead B-frag skip for y=2/wn=1 waves (cols 336+ are past 2*FB=322).
// S out layout: complex S[b][k][h][t] (h = channel-pair), float4 per (b,k,h,t)
__global__ __launch_bounds__(512, 4) void k_gstft(const short* __restrict__ Ahi, const short* __restrict__ Alo,
        const short* __restrict__ Bts, float* __restrict__ S){
    __shared__ short stage[32768];           // 64 KB: 2 buffers x (Ah|Al|Bh|Bl) x 4096 shorts
    int tid = threadIdx.x;
    int row0 = blockIdx.x*128;               // over b*TP*CC rows
    int col0 = blockIdx.y*128;
    int b  = row0 >> 12;                     // TP*CC = 4096 rows per batch
    int t0 = (row0 & 4095) >> 2;             // in {0,32,...,992} — always < TT
    int wave = tid >> 6, lane = tid & 63;
    int wm = wave >> 1, wn = wave & 1;       // 4x2 wave grid: 32 rows x 64 cols each
    int l15 = lane & 15, quad = lane >> 4;
    int colb = col0 + wn*64;
    bool bl1 = (colb + 16) < 2*FB;           // frag-level liveness (wave-uniform)
    bool bl2 = (colb + 32) < 2*FB;
    bool bl3 = (colb + 48) < 2*FB;
    // ---- staging addresses (per lane): wave w stages rows w*16..w*16+15 ----
    int rowS  = wave*16 + (lane >> 2);       // staged LDS row 0..127
    int chunk = (lane & 3) ^ ((lane >> 3) & 3);   // pre-swizzled global k-chunk
    int tls = t0 + (rowS >> 2); if (tls >= TT) tls = TT - 1;   // clamp; stores guarded later
    size_t gao = (size_t)(b*4 + (rowS & 3))*NPAD + (size_t)tls*160 + chunk*8;
    const short* gAh = Ahi + gao;
    const short* gAl = Alo + gao;
    const short* gB  = Bts + (size_t)(col0 + rowS)*640 + chunk*8;   // hi; lo at +320
    short* lA = stage + wave*512;            // wave-uniform LDS bases (+plane/buffer offset)
    // ---- read addresses ----
    int sw  = (l15 >> 1) & 3;
    int c0r = (quad ^ sw) * 8;               // swizzled chunk offset (shorts)
    int ra0 = (wm*32 + l15)*32 + c0r;        // A row frag 0; frag 1 at +512
    int rb0 = (wn*64 + l15)*32 + c0r;        // B col frag j at + j*512
    f32x4 c00 = {0.f,0.f,0.f,0.f}, c01 = c00, c02 = c00, c03 = c00;
    f32x4 c10 = c00, c11 = c00, c12 = c00, c13 = c00;

    #define STG(kt_, off_) do{ \
        ldsdma16(gAh + (kt_)*32,       lA + (off_));         \
        ldsdma16(gAl + (kt_)*32,       lA + (off_) + 4096);  \
        ldsdma16(gB  + (kt_)*32,       lA + (off_) + 8192);  \
        ldsdma16(gB  + (kt_)*32 + 320, lA + (off_) + 12288); \
    }while(0)

    STG(0, 0);                               // 2-deep prologue
    STG(1, 16384);
    #pragma unroll
    for (int kt = 0; kt < 10; ++kt){
        int offc = (kt & 1) ? 16384 : 0;
        // wave-local: oldest STG (this kt's buffer) must land; newer stays in flight
        if (kt < 9) asm volatile("s_waitcnt vmcnt(4)" ::: "memory");
        else        asm volatile("s_waitcnt vmcnt(0)" ::: "memory");
        __builtin_amdgcn_s_barrier();        // all waves' data for buf[kt&1] present
        bf16x8 a0h = *(bf16x8*)&stage[offc + ra0];
        bf16x8 a1h = *(bf16x8*)&stage[offc + ra0 + 512];
        bf16x8 a0l = *(bf16x8*)&stage[offc + 4096 + ra0];
        bf16x8 a1l = *(bf16x8*)&stage[offc + 4096 + ra0 + 512];
        bf16x8 b0h = *(bf16x8*)&stage[offc + 8192 + rb0];
        bf16x8 b0l = *(bf16x8*)&stage[offc + 12288 + rb0];
        bf16x8 b1h{}, b2h{}, b3h{}, b1l{}, b2l{}, b3l{};
        if (bl1){ b1h = *(bf16x8*)&stage[offc + 8192 + rb0 + 512];
                  b1l = *(bf16x8*)&stage[offc + 12288 + rb0 + 512]; }
        if (bl2){ b2h = *(bf16x8*)&stage[offc + 8192 + rb0 + 1024];
                  b2l = *(bf16x8*)&stage[offc + 12288 + rb0 + 1024]; }
        if (bl3){ b3h = *(bf16x8*)&stage[offc + 8192 + rb0 + 1536];
                  b3l = *(bf16x8*)&stage[offc + 12288 + rb0 + 1536]; }
        asm volatile("s_waitcnt lgkmcnt(0)" ::: "memory");
        __builtin_amdgcn_sched_barrier(0);   // rule #18: pin reads before the reuse barrier
        __builtin_amdgcn_s_barrier();        // all waves done reading buf[kt&1]
        if (kt < 8) STG(kt+2, offc);         // overwrite just-freed buffer; lands in ~2 phases
        // grouped per-acc (same per-acc order as before: hh, lh, hl)
        c00 = __builtin_amdgcn_mfma_f32_16x16x32_bf16(a0h, b0h, c00, 0, 0, 0);
        c00 = __builtin_amdgcn_mfma_f32_16x16x32_bf16(a0l, b0h, c00, 0, 0, 0);
        c00 = __builtin_amdgcn_mfma_f32_16x16x32_bf16(a0h, b0l, c00, 0, 0, 0);
        c10 = __builtin_amdgcn_mfma_f32_16x16x32_bf16(a1h, b0h, c10, 0, 0, 0);
        c10 = __builtin_amdgcn_mfma_f32_16x16x32_bf16(a1l, b0h, c10, 0, 0, 0);
        c10 = __builtin_amdgcn_mfma_f32_16x16x32_bf16(a1h, b0l, c10, 0, 0, 0);
        if (bl1){
            c01 = __builtin_amdgcn_mfma_f32_16x16x32_bf16(a0h, b1h, c01, 0, 0, 0);
            c01 = __builtin_amdgcn_mfma_f32_16x16x32_bf16(a0l, b1h, c01, 0, 0, 0);
            c01 = __builtin_amdgcn_mfma_f32_16x16x32_bf16(a0h, b1l, c01, 0, 0, 0);
            c11 = __builtin_amdgcn_mfma_f32_16x16x32_bf16(a1h, b1h, c11, 0, 0, 0);
            c11 = __builtin_amdgcn_mfma_f32_16x16x32_bf16(a1l, b1h, c11, 0, 0, 0);
            c11 = __builtin_amdgcn_mfma_f32_16x16x32_bf16(a1h, b1l, c11, 0, 0, 0);
        }
        if (bl2){
            c02 = __builtin_amdgcn_mfma_f32_16x16x32_bf16(a0h, b2h, c02, 0, 0, 0);
            c02 = __builtin_amdgcn_mfma_f32_16x16x32_bf16(a0l, b2h, c02, 0, 0, 0);
            c02 = __builtin_amdgcn_mfma_f32_16x16x32_bf16(a0h, b2l, c02, 0, 0, 0);
            c12 = __builtin_amdgcn_mfma_f32_16x16x32_bf16(a1h, b2h, c12, 0, 0, 0);
            c12 = __builtin_amdgcn_mfma_f32_16x16x32_bf16(a1l, b2h, c12, 0, 0, 0);
            c12 = __builtin_amdgcn_mfma_f32_16x16x32_bf16(a1h, b2l, c12, 0, 0, 0);
        }
        if (bl3){
            c03 = __builtin_amdgcn_mfma_f32_16x16x32_bf16(a0h, b3h, c03, 0, 0, 0);
            c03 = __builtin_amdgcn_mfma_f32_16x16x32_bf16(a0l, b3h, c03, 0, 0, 0);
            c03 = __builtin_amdgcn_mfma_f32_16x16x32_bf16(a0h, b3l, c03, 0, 0, 0);
            c13 = __builtin_amdgcn_mfma_f32_16x16x32_bf16(a1h, b3h, c13, 0, 0, 0);
            c13 = __builtin_amdgcn_mfma_f32_16x16x32_bf16(a1l, b3h, c13, 0, 0, 0);
            c13 = __builtin_amdgcn_mfma_f32_16x16x32_bf16(a1h, b3l, c13, 0, 0, 0);
        }
    }
    #undef STG
    // ---- epilogue: shfl-pair assembly, direct global store (no LDS) ----
    int tq  = t0 + wm*8 + quad;
    int kgb = (col0 >> 1) + wn*32 + (l15 >> 1);
    int h   = l15 & 1;
    float4* S4 = (float4*)S;
    #define EPI(cf, i_, j_) do{ \
        int t = tq + 4*(i_); \
        int kg = kgb + 8*(j_); \
        if (t < TT && kg < FB){ \
            float p0 = __shfl_xor(cf[0], 1); \
            float p1 = __shfl_xor(cf[1], 1); \
            float p2 = __shfl_xor(cf[2], 1); \
            float p3 = __shfl_xor(cf[3], 1); \
            float4 v = h ? make_float4(p2, cf[2], p3, cf[3]) \
                         : make_float4(cf[0], p0, cf[1], p1); \
            S4[((size_t)((b*FB + kg)*2 + h))*TT + t] = v; \
        } \
    }while(0)
    EPI(c00, 0, 0); EPI(c01, 0, 1); EPI(c02, 0, 2); EPI(c03, 0, 3);
    EPI(c10, 1, 0); EPI(c11, 1, 1); EPI(c12, 1, 2); EPI(c13, 1, 3);
    #undef EPI
}

// covariance recurrence, original weighted form (first-frame handling): R = a*R + wg*outer(X)
#define UPD(first) do{ \
    float aa = (first) ? 0.f : 0.05f; float wg = (first) ? 1.f : 0.95f; \
    float y0x=wg*x0.x, y0y=wg*x0.y, y1x=wg*x1.x, y1y=wg*x1.y; \
    float y2x=wg*x2.x, y2y=wg*x2.y, y3x=wg*x3.x, y3y=wg*x3.y; \
    d0 = aa*d0 + y0x*x0.x + y0y*x0.y; \
    d1 = aa*d1 + y1x*x1.x + y1y*x1.y; \
    d2 = aa*d2 + y2x*x2.x + y2y*x2.y; \
    d3 = aa*d3 + y3x*x3.x + y3y*x3.y; \
    r10.x = aa*r10.x + y1x*x0.x + y1y*x0.y;  r10.y = aa*r10.y + y1y*x0.x - y1x*x0.y; \
    r20.x = aa*r20.x + y2x*x0.x + y2y*x0.y;  r20.y = aa*r20.y + y2y*x0.x - y2x*x0.y; \
    r30.x = aa*r30.x + y3x*x0.x + y3y*x0.y;  r30.y = aa*r30.y + y3y*x0.x - y3x*x0.y; \
    r21.x = aa*r21.x + y2x*x1.x + y2y*x1.y;  r21.y = aa*r21.y + y2y*x1.x - y2x*x1.y; \
    r31.x = aa*r31.x + y3x*x1.x + y3y*x1.y;  r31.y = aa*r31.y + y3y*x1.x - y3x*x1.y; \
    r32.x = aa*r32.x + y3x*x2.x + y3y*x2.y;  r32.y = aa*r32.y + y3y*x2.x - y3x*x2.y; \
}while(0)

// Q-form (R19): Q = 0.05*Q + outer(X); Q = R/0.95 exactly when no first-frame is in
// the truncated window. The solve is scale-invariant in R -> outputs identical.
#define UPDQ do{ \
    d0 = 0.05f*d0 + x0.x*x0.x + x0.y*x0.y; \
    d1 = 0.05f*d1 + x1.x*x1.x + x1.y*x1.y; \
    d2 = 0.05f*d2 + x2.x*x2.x + x2.y*x2.y; \
    d3 = 0.05f*d3 + x3.x*x3.x + x3.y*x3.y; \
    r10.x = 0.05f*r10.x + x1.x*x0.x + x1.y*x0.y;  r10.y = 0.05f*r10.y + x1.y*x0.x - x1.x*x0.y; \
    r20.x = 0.05f*r20.x + x2.x*x0.x + x2.y*x0.y;  r20.y = 0.05f*r20.y + x2.y*x0.x - x2.x*x0.y; \
    r30.x = 0.05f*r30.x + x3.x*x0.x + x3.y*x0.y;  r30.y = 0.05f*r30.y + x3.y*x0.x - x3.x*x0.y; \
    r21.x = 0.05f*r21.x + x2.x*x1.x + x2.y*x1.y;  r21.y = 0.05f*r21.y + x2.y*x1.x - x2.x*x1.y; \
    r31.x = 0.05f*r31.x + x3.x*x1.x + x3.y*x1.y;  r31.y = 0.05f*r31.y + x3.y*x1.x - x3.x*x1.y; \
    r32.x = 0.05f*r32.x + x3.x*x2.x + x3.y*x2.y;  r32.y = 0.05f*r32.y + x3.y*x2.x - x3.x*x2.y; \
}while(0)

// ---------- scan, R20: full-strip (1 block per (b,f)), 512 threads, 2 outputs/thread ----------
// 6 UPDs per 2 outputs (was 5 per 1): -40% recurrence work. Output t0+1's window has
// one extra tail frame (weight 0.05^6 — more accurate than before). 32KB LDS.
__global__ __launch_bounds__(512) void k_scan(const float* __restrict__ S, const float* __restrict__ htab,
                      float* __restrict__ S1, float* __restrict__ S2){
    __shared__ float4 tile[2016];     // swizzled full strip (2*TT=2002 used; swz stays in-group)
    int bf = blockIdx.x;              // b*FB + f
    int f  = bf % FB;
    int tid = threadIdx.x;
    const float4* P0 = (const float4*)S + (size_t)(bf*2)*TT;
    const float4* P1 = P0 + TT;
    for (int i = tid; i < 2*TT; i += 512){
        int tt = i >> 1;
        tile[i ^ ((i>>4)&7)] = (i & 1) ? P1[tt] : P0[tt];   // interleave planes into tile
    }
    __syncthreads();
    int t0 = tid*2;
    if (t0 < TT){
        const float2* hp = (const float2*)htab;
        float2 ha0 = hp[f*4+0], ha1 = hp[f*4+1], ha2 = hp[f*4+2], ha3 = hp[f*4+3];
        float2 hb0 = hp[(FB+f)*4+0], hb1 = hp[(FB+f)*4+1], hb2 = hp[(FB+f)*4+2], hb3 = hp[(FB+f)*4+3];
        float d0=0,d1=0,d2=0,d3=0;
        float2 r10={0,0}, r20={0,0}, r30={0,0}, r21={0,0}, r31={0,0}, r32={0,0};
        float2 x0, x1, x2, x3;
        #define LOADX(tau_) do{ int i0_ = 2*(tau_); \
            float4 v0_ = tile[i0_ ^ ((i0_>>4)&7)]; \
            float4 v1_ = tile[(i0_+1) ^ (((i0_+1)>>4)&7)]; \
            x0 = make_float2(v0_.x, v0_.y); x1 = make_float2(v0_.z, v0_.w); \
            x2 = make_float2(v1_.x, v1_.y); x3 = make_float2(v1_.z, v1_.w); \
        }while(0)
        bool qform = (t0 >= KWARM + 1);   // no frame-0 special in any window
        int ts = t0 - KWARM; if (ts < 0) ts = 0;
        if (qform){
            #pragma unroll
            for (int u = 0; u < KWARM; ++u){ LOADX(ts + u); UPDQ; }
        } else {
            for (int tau = 0; tau < t0; ++tau){ LOADX(tau); UPD(tau == 0); }
        }
        float2* S1g = (float2*)S1 + (size_t)bf*TT;
        float2* S2g = (float2*)S2 + (size_t)bf*TT;
        #pragma unroll
        for (int j = 0; j < 2; ++j){
            int t = t0 + j;
            if (t >= TT) break;
            LOADX(t);
            if (qform) UPDQ; else UPD(t == 0);
            float trc = d0 + d1 + d2 + d3;
            float lam = trc * 0.25f;
            float e0 = d0 + lam, e1 = d1 + lam, e2 = d2 + lam, e3 = d3 + lam;
            float detP = e0*e1 - (r10.x*r10.x + r10.y*r10.y);
            float2 w00 = csub(cscale(r20, e1), cmulf(r10, r21));
            float2 w01 = csub(cscale(r30, e1), cmulf(r10, r31));
            float2 w10 = csub(cscale(r21, e0), cjmul(r10, r20));
            float2 w11 = csub(cscale(r31, e0), cjmul(r10, r30));
            float2 va = cjmul(r30, w00), vb = cjmul(r31, w10);
            float2 V10 = make_float2(va.x + vb.x, -(va.y + vb.y));
            float reV00 = r20.x*w00.x + r20.y*w00.y + r21.x*w10.x + r21.y*w10.y;
            float reV11 = r30.x*w01.x + r30.y*w01.y + r31.x*w11.x + r31.y*w11.y;
            float t00 = detP*e2 - reV00;
            float t11 = detP*e3 - reV11;
            float2 t10 = csub(cscale(r32, detP), V10);
            float detT = t00*t11 - (t10.x*t10.x + t10.y*t10.y);
            #pragma unroll
            for (int m = 0; m < 2; ++m){
                float2 h0 = m ? hb0 : ha0;
                float2 h1 = m ? hb1 : ha1;
                float2 h2 = m ? hb2 : ha2;
                float2 h3 = m ? hb3 : ha3;
                float2 g0 = csub(cscale(h0, e1), cjmul(r10, h1));
                float2 g1 = csub(cscale(h1, e0), cmulf(r10, h0));
                float2 ta = cmulf(r20, g0), tb = cmulf(r21, g1);
                float2 hh0 = make_float2(detP*h2.x - ta.x - tb.x, detP*h2.y - ta.y - tb.y);
                ta = cmulf(r30, g0); tb = cmulf(r31, g1);
                float2 hh1 = make_float2(detP*h3.x - ta.x - tb.x, detP*h3.y - ta.y - tb.y);
                float2 y20 = csub(cscale(hh0, t11), cjmul(t10, hh1));
                float2 y21 = csub(cscale(hh1, t00), cmulf(t10, hh0));
                float2 u20 = cscale(y20, detP), u21 = cscale(y21, detP);
                ta = cmulcj(y20, r20); tb = cmulcj(y21, r30);
                float2 q0 = make_float2(detT*h0.x - ta.x - tb.x, detT*h0.y - ta.y - tb.y);
                ta = cmulcj(y20, r21); tb = cmulcj(y21, r31);
                float2 q1 = make_float2(detT*h1.x - ta.x - tb.x, detT*h1.y - ta.y - tb.y);
                float2 u10 = csub(cscale(q0, e1), cjmul(r10, q1));
                float2 u11 = csub(cscale(q1, e0), cmulf(r10, q0));
                float2 den = cjmul(h0, u10), tmp;
                tmp = cjmul(h1, u11); den.x += tmp.x; den.y += tmp.y;
                tmp = cjmul(h2, u20); den.x += tmp.x; den.y += tmp.y;
                tmp = cjmul(h3, u21); den.x += tmp.x; den.y += tmp.y;
                float2 num = cjmul(u10, x0);
                tmp = cjmul(u11, x1); num.x += tmp.x; num.y += tmp.y;
                tmp = cjmul(u20, x2); num.x += tmp.x; num.y += tmp.y;
                tmp = cjmul(u21, x3); num.x += tmp.x; num.y += tmp.y;
                float2 s = cdivf(num, make_float2(den.x, -den.y));
                if (m) S2g[t] = s; else S1g[t] = s;
            }
        }
        #undef LOADX
    }
}

// ---------- pack v2 (R8-verified): coalesced LDS transpose. block = (rb, 32-t tile) ----------
__global__ __launch_bounds__(256) void k_pack(const float* __restrict__ S1, const float* __restrict__ S2,
                                              short* __restrict__ A){
    __shared__ short tile[32*708];        // 45,312 B; row = t-in-tile, col = kk (hi 0..351 | lo 352..703)
    int bid = blockIdx.x;                 // rb*32 + tb
    int tb = bid & 31, rb = bid >> 5;
    int t0 = tb*32;
    int beam = rb >> 3, b = rb & 7;
    const float2* Sp = (const float2*)(beam ? S2 : S1) + (size_t)b*FB*TT;
    int tid = threadIdx.x;
    for (int idx = tid; idx < 32*176; idx += 256){
        int bin = idx >> 5, tq = idx & 31;
        int t = t0 + tq;
        float2 s = make_float2(0.f, 0.f);
        if (bin < FB && t < TT) s = Sp[(size_t)bin*TT + t];
        int c0 = 2*bin;
        tile[tq*708 + c0]            = bf_hi(s.x);
        tile[tq*708 + c0 + 1]        = bf_hi(s.y);
        tile[tq*708 + KSEC + c0]     = bf_lo(s.x);
        tile[tq*708 + KSEC + c0 + 1] = bf_lo(s.y);
    }
    __syncthreads();
    for (int idx = tid; idx < 32*176; idx += 256){
        int tq = idx / 176, k4 = idx % 176;
        int t = t0 + tq;
        if (t < TT)
            *(short4*)&A[(size_t)(rb*TT + t)*LDK + k4*4] = *(short4*)&tile[tq*708 + k4*4];
    }
}

// ---------- irfft MFMA GEMM, R20: 3-buffer ring, ONE barrier per step ----------
// The data-ready barrier at step s proves all waves completed s-1's ds_reads (their
// own lgkmcnt(0) precedes their s-1 MFMAs), so STG(s+2) into buf[(s-1)%3] is safe.
// 33 steps, vmcnt(2) steady-state. wn=1 waves of y=2 block fully dead (skip work).
__global__ __launch_bounds__(512, 4) void k_gemm(const short* __restrict__ A, const short* __restrict__ Bt,
                                                 float* __restrict__ C){
    __shared__ short sb2[24576];           // 48 KB: 3 buffers x (A|B) x 4096 shorts
    int tid = threadIdx.x;
    int row0 = blockIdx.x * 128;
    int col0 = blockIdx.y * 128;
    int wave = tid >> 6, lane = tid & 63;
    int wm = wave >> 1, wn = wave & 1;     // 4x2 wave grid: 32 rows x 64 cols each
    int l15 = lane & 15, quad = lane >> 4;
    bool wlive = (col0 + wn*64) < NFFT;    // y=2,wn=1 waves are fully past NFFT
    // staging (per lane)
    int rowS  = wave*16 + (lane >> 2);
    int chunk = (lane & 3) ^ ((lane >> 3) & 3);
    int grS = row0 + rowS; if (grS >= GM) grS = GM - 1;       // clamp; stores guarded
    int grB = col0 + rowS; if (grB >= NFFT) grB = NFFT - 1;   // clamp; cols >=320 unused
    const short* gA = A  + (size_t)grS*LDK + chunk*8;
    const short* gB = Bt + (size_t)grB*LDK + chunk*8;
    short* lA = sb2 + wave*512;
    // reads
    int sw  = (l15 >> 1) & 3;
    int c0r = (quad ^ sw) * 8;
    int ra0 = (wm*32 + l15)*32 + c0r;      // frag 1 at +512
    int rb0 = (wn*64 + l15)*32 + c0r;      // frag j at +j*512
    f32x4 c00 = {0.f,0.f,0.f,0.f}, c01 = c00, c02 = c00, c03 = c00;
    f32x4 c10 = c00, c11 = c00, c12 = c00, c13 = c00;

    #define KOF(s_, ka_, kb_) { int sg_ = ((s_) >= 22) ? 2 : ((s_) >= 11) ? 1 : 0; \
        int kt_ = (s_) - sg_*11; \
        ka_ = ((sg_ == 1) ? KSEC : 0) + kt_*32; \
        kb_ = ((sg_ == 2) ? KSEC : 0) + kt_*32; }
    #define STG2(s_, off_) do{ int ka_, kb_; KOF(s_, ka_, kb_); \
        ldsdma16(gA + ka_, lA + (off_));        \
        ldsdma16(gB + kb_, lA + (off_) + 4096); \
    }while(0)

    STG2(0, 0);                            // 2-deep prologue into ring slots 0,1
    STG2(1, 8192);
    #pragma unroll
    for (int s = 0; s < 33; ++s){
        int offc = (s % 3) * 8192;
        if (s < 32) asm volatile("s_waitcnt vmcnt(2)" ::: "memory");
        else        asm volatile("s_waitcnt vmcnt(0)" ::: "memory");
        __builtin_amdgcn_s_barrier();      // buf[s%3] ready; also: all s-1 reads done
        if (s < 31) STG2(s+2, ((s+2) % 3) * 8192);   // writes buf[(s-1)%3] — freed above
        bf16x8 a0{}, a1{}, b0{}, b1{}, b2{}, b3{};
        if (wlive){
            a0 = *(bf16x8*)&sb2[offc + ra0];
            a1 = *(bf16x8*)&sb2[offc + ra0 + 512];
            b0 = *(bf16x8*)&sb2[offc + 4096 + rb0];
            b1 = *(bf16x8*)&sb2[offc + 4096 + rb0 + 512];
            b2 = *(bf16x8*)&sb2[offc + 4096 + rb0 + 1024];
            b3 = *(bf16x8*)&sb2[offc + 4096 + rb0 + 1536];
            asm volatile("s_waitcnt lgkmcnt(0)" ::: "memory");
            __builtin_amdgcn_sched_barrier(0);
            c00 = __builtin_amdgcn_mfma_f32_16x16x32_bf16(a0, b0, c00, 0, 0, 0);
            c01 = __builtin_amdgcn_mfma_f32_16x16x32_bf16(a0, b1, c01, 0, 0, 0);
            c02 = __builtin_amdgcn_mfma_f32_16x16x32_bf16(a0, b2, c02, 0, 0, 0);
            c03 = __builtin_amdgcn_mfma_f32_16x16x32_bf16(a0, b3, c03, 0, 0, 0);
            c10 = __builtin_amdgcn_mfma_f32_16x16x32_bf16(a1, b0, c10, 0, 0, 0);
            c11 = __builtin_amdgcn_mfma_f32_16x16x32_bf16(a1, b1, c11, 0, 0, 0);
            c12 = __builtin_amdgcn_mfma_f32_16x16x32_bf16(a1, b2, c12, 0, 0, 0);
            c13 = __builtin_amdgcn_mfma_f32_16x16x32_bf16(a1, b3, c13, 0, 0, 0);
        }
    }
    #undef STG2
    #undef KOF
    if (wlive){
        #pragma unroll
        for (int r = 0; r < 4; ++r){
            int orow0 = row0 + wm*32 + quad*4 + r;
            int oc = col0 + wn*64 + l15;
            if (orow0 < GM){
                if (oc      < NFFT) C[(size_t)orow0*NFFT + oc]      = c00[r];
                if (oc + 16 < NFFT) C[(size_t)orow0*NFFT + oc + 16] = c01[r];
                if (oc + 32 < NFFT) C[(size_t)orow0*NFFT + oc + 32] = c02[r];
                if (oc + 48 < NFFT) C[(size_t)orow0*NFFT + oc + 48] = c03[r];
            }
            if (orow0 + 16 < GM){
                if (oc      < NFFT) C[(size_t)(orow0+16)*NFFT + oc]      = c10[r];
                if (oc + 16 < NFFT) C[(size_t)(orow0+16)*NFFT + oc + 16] = c11[r];
                if (oc + 32 < NFFT) C[(size_t)(orow0+16)*NFFT + oc + 32] = c12[r];
                if (oc + 48 < NFFT) C[(size_t)(orow0+16)*NFFT + oc + 48] = c13[r];
            }
        }
    }
}

// ---------- overlap-add, float4: 4 outputs/thread (wsum==2 in cropped interior) ----------
__global__ __launch_bounds__(256) void k_ola(const float* __restrict__ frames, float* __restrict__ out){
    int gid = blockIdx.x*256 + threadIdx.x;
    if (gid >= 2*BB*(LL/4)) return;
    int o4 = (gid % (LL/4))*4;
    int rb = gid / (LL/4);                 // beam*BB + b
    int i  = o4 + HOP;                     // mult of 4; r in {0,4,...,156}
    int t1 = i / HOP;
    int r  = i - t1*HOP;
    const float4* fb = (const float4*)(frames + (size_t)rb*TT*NFFT);
    float4 a = fb[(t1*NFFT + r) >> 2];
    float4 b = fb[((t1-1)*NFFT + r + HOP) >> 2];
    ((float4*)out)[gid] = make_float4(0.5f*(a.x+b.x), 0.5f*(a.y+b.y), 0.5f*(a.z+b.z), 0.5f*(a.w+b.w));
}

extern "C" void kernel_launch(void* const* d_in, const int* in_sizes, int n_in,
                              void* d_out, int out_size, void* d_ws, size_t ws_size,
                              hipStream_t stream){
    const float* in  = (const float*)d_in[0];   // [B, L, C] fp32
    const float* win = (const float*)d_in[1];   // [320] fp32
    float* ws = (float*)d_ws;
    // ws (floats): mean 32 | invmax 8 | htab 2576 | pad -> header 3072
    //              | S1 (2,578,576) | S2 (2,578,576) | S (10,314,304)   total ~62 MB
    // aliases: part -> S1 head (dead before k_anorm); Ahi/Alo -> S1+S2 (dead after k_gstft);
    //          Bts + Bt -> head of d_out (dead until k_ola fully overwrites; NOT in S — R13 bug);
    //          A_ir -> S (post-scan); frames -> S1/S2 (post-pack)
    float* mean   = ws;
    float* invmax = ws + 32;
    float* htab   = ws + 48;
    float* S1     = ws + 3072;
    size_t nS1 = (size_t)2*BB*FB*TT;            // 2,578,576 floats
    float* S2 = S1 + nS1;
    float* S  = S2 + nS1;                       // 10,314,304 floats
    float* part = S1;
    short* Ahi = (short*)S1;                    // 8*4*160320 = 5,130,240 shorts
    short* Alo = Ahi + (size_t)BB*CC*NPAD;      // total 10,260,480 shorts <= S1+S2 (10,314,304 short-equiv)
    short* Bts = (short*)d_out;                 // 245,760 shorts (= 122,880 floats)
    short* Bt  = (short*)((float*)d_out + 131072); // 225,280 shorts at float-offset 131072 (16B aligned)
    short* A  = (short*)S;                      // irfft A: 16016*704 bf16
    float* frames = S1;                         // 16016*320 floats over dead S1+S2

    int ngen = 2*FB*CC + 384*640 + NFFT*LDK;    // fused table generation
    k_gen<<<dim3((ngen + 255)/256), dim3(256), 0, stream>>>(win, htab, Bts, Bt);
    k_stats1<<<dim3(BB*RBLK), dim3(256), 0, stream>>>(in, part);
    k_stats2<<<dim3(BB), dim3(128), 0, stream>>>(part, mean, invmax);
    k_anorm<<<dim3((BB*(NPAD/8) + 255)/256), dim3(256), 0, stream>>>(in, mean, invmax, Ahi, Alo);
    k_gstft<<<dim3(BB*TP*CC/128, 3), dim3(512), 0, stream>>>(Ahi, Alo, Bts, S);
    k_scan<<<dim3(BB*FB), dim3(512), 0, stream>>>(S, htab, S1, S2);
    k_pack<<<dim3(512), dim3(256), 0, stream>>>(S1, S2, A);
    k_gemm<<<dim3((GM + 127)/128, (NFFT + 127)/128), dim3(512), 0, stream>>>(A, Bt, frames);
    k_ola<<<dim3((2*BB*(LL/4) + 255)/256), dim3(256), 0, stream>>>(frames, (float*)d_out);
}

// Round 8
// 190.242 us; speedup vs baseline: 1.6386x; 1.0116x over previous
//
#include <hip/hip_runtime.h>
#include <hip/hip_bf16.h>
#include <math.h>

#define BB 8
#define LL 160000
#define CC 4
#define NFFT 320
#define HOP 160
#define FB 161          // rfft bins
#define TT 1001         // frames
#define TP 1024         // padded frames per batch (t-slots) for STFT GEMM
#define RBLK 128        // stats blocks per batch
#define PI_D 3.14159265358979323846
#define NPAD 160320     // reflect-padded samples per (b,c): p in [-160, 160159]

#define KWARM 4         // warm-up frames; tail weight 0.05^5 ~ 3e-7 rel << bf16 error floor (4.9e-4)

#define GM 16016        // irfft GEMM M = 2*BB*TT rows (beam,b,t)
#define KSEC 352        // irfft padded K per split-section (322 used)
#define LDK 704         // irfft A/Bt leading dim = 2 sections
#define KT 11           // irfft K-tiles of 32 per section
// R21: (1) REVERT R20's k_gstft per-acc MFMA grouping + frag guards (regressed
//      42->47us: 3-deep dependent-MFMA chains can't hide latency at 2 blk/CU;
//      guards cost ~10% VALU/sched to save ~2% MFMA). Lesson: keep MFMA issue
//      acc-rotating; dead-work skip not worth breaking the interleave.
//      (2) k_gen: exact integer mod-320 phase reduction + f32 sincosf for the two
//      big tables (was 471K double sincos). Reduced-arg f32 error ~2e-7 << bf16-pair
//      floor. htab (1288 elems) stays double.
// R20: k_scan full-strip 2 outputs/thread (-40% UPD); k_gemm 3-buffer ring, one
//      barrier/step; both delivered (~-7us).
// R19: anorm coalesced; scan direct stores + Q-form (scale-invariant solve).
// R17/R18: 128x128 tiles, 8 waves; fixed the work-per-phase bound (~45us -> ~42us).
// Keep 2-deep counted-vmcnt DMA pipeline (vmcnt BEFORE barrier).
// R14 lesson (direct-global gather, 47->115us): LDS staging is a latency-decoupling
// pipeline, not just a cache — do not remove it.
// LIFETIME NOTE (R13 bug): Bt/Bts must NOT live in the S region — k_gstft overwrites
// ALL of S. Both live in d_out's head (dead until k_ola fully overwrites at the end).

typedef __attribute__((ext_vector_type(8))) short bf16x8;
typedef __attribute__((ext_vector_type(4))) float f32x4;

__device__ __forceinline__ void ldsdma16(const short* g, short* l){
    // wave-level DMA: per-lane global src, wave-uniform LDS base + lane*16B
    __builtin_amdgcn_global_load_lds((const __attribute__((address_space(1))) void*)g,
                                     (__attribute__((address_space(3))) void*)l, 16, 0, 0);
}

__device__ __forceinline__ float2 cmulf(float2 a, float2 b){           // a*b
    return make_float2(a.x*b.x - a.y*b.y, a.x*b.y + a.y*b.x);
}
__device__ __forceinline__ float2 cmulcj(float2 a, float2 b){          // a*conj(b)
    return make_float2(a.x*b.x + a.y*b.y, a.y*b.x - a.x*b.y);
}
__device__ __forceinline__ float2 cjmul(float2 a, float2 b){           // conj(a)*b
    return make_float2(a.x*b.x + a.y*b.y, a.x*b.y - a.y*b.x);
}
__device__ __forceinline__ float2 csub(float2 a, float2 b){ return make_float2(a.x-b.x, a.y-b.y); }
__device__ __forceinline__ float2 cscale(float2 a, float s){ return make_float2(a.x*s, a.y*s); }
__device__ __forceinline__ float2 cdivf(float2 a, float2 b){           // a/b
    float inv = 1.0f/(b.x*b.x + b.y*b.y);
    return make_float2((a.x*b.x + a.y*b.y)*inv, (a.y*b.x - a.x*b.y)*inv);
}
__device__ __forceinline__ short bf_hi(float v){
    __hip_bfloat16 h = __float2bfloat16(v);
    short s; __builtin_memcpy(&s, &h, 2); return s;
}
__device__ __forceinline__ short bf_lo(float v){
    __hip_bfloat16 h = __float2bfloat16(v);
    float r = v - __bfloat162float(h);
    __hip_bfloat16 l = __float2bfloat16(r);
    short s; __builtin_memcpy(&s, &l, 2); return s;
}

// ---------- fused table generator: htab | Bts (STFT B) | Bt (irfft B) ----------
// R21: big sections use exact mod-320 int reduction + f32 sincosf (tables are bf16
// hi/lo targets; reduced-arg f32 error ~2e-7 << 1.5e-5 pair floor).
__global__ void k_gen(const float* __restrict__ win, float* __restrict__ htab,
                      short* __restrict__ Bts, short* __restrict__ Bt){
    int gid = blockIdx.x*256 + threadIdx.x;
    const float W0 = (float)(2.0*PI_D/320.0);
    if (gid < 2*FB*CC){
        int i = gid;
        int c = i & 3;
        int k = (i >> 2) % FB;
        int m = i / (FB*CC);
        double coef = 2.0*PI_D*50.0*0.027*sin(40.0*PI_D/180.0)/340.0;
        double sgn = (m == 0) ? -1.0 : 1.0;
        double ph = sgn*coef*(double)k*(double)c;
        double s, c2;
        sincos(ph, &s, &c2);
        ((float2*)htab)[i] = make_float2((float)c2, (float)s);
        return;
    }
    gid -= 2*FB*CC;
    if (gid < 384*640){
        int col = gid / 640, kk = gid % 640;
        int n = (kk >= 320) ? kk - 320 : kk;
        int sec = (kk >= 320) ? 1 : 0;
        float v = 0.f;
        if (col < 2*FB){
            int k = col >> 1;
            int mr = (k*n) % 320;                    // exact reduction
            float s, co; sincosf(W0*(float)mr, &s, &co);
            v = win[n] * ((col & 1) ? -s : co);
        }
        Bts[gid] = sec ? bf_lo(v) : bf_hi(v);
        return;
    }
    gid -= 384*640;
    if (gid < NFFT*LDK){
        int n = gid / LDK, kk = gid % LDK;
        int sec = (kk >= KSEC) ? 1 : 0;
        int kk2 = kk - (sec ? KSEC : 0);
        float v = 0.f;
        if (kk2 < 2*FB){
            int bin = kk2 >> 1;
            float c = ((bin == 0 || bin == 160) ? 1.0f : 2.0f) * (1.0f/320.0f);
            int mr = (bin*n) % 320;                  // exact reduction
            float s, co; sincosf(W0*(float)mr, &s, &co);
            v = (kk2 & 1) ? -c*s : c*co;
        }
        Bt[(size_t)n*LDK + kk] = sec ? bf_lo(v) : bf_hi(v);
    }
}

// ---------- stage 1: per-(b,chunk) partial {sum4, min4, max4} ----------
__global__ __launch_bounds__(256) void k_stats1(const float* __restrict__ in, float* __restrict__ part){
    __shared__ float4 s4[256];
    __shared__ float4 mn4[256];
    __shared__ float4 mx4[256];
    int b = blockIdx.x / RBLK, chunk = blockIdx.x % RBLK;
    int tid = threadIdx.x;
    const float4* p = (const float4*)(in + (size_t)b*LL*CC);
    const int per = LL / RBLK;
    int start = chunk*per;
    float4 s  = make_float4(0.f,0.f,0.f,0.f);
    float4 mn = make_float4( 3.4e38f, 3.4e38f, 3.4e38f, 3.4e38f);
    float4 mx = make_float4(-3.4e38f,-3.4e38f,-3.4e38f,-3.4e38f);
    for (int i = start + tid; i < start + per; i += 256){
        float4 v = p[i];
        s.x += v.x; s.y += v.y; s.z += v.z; s.w += v.w;
        mn.x = fminf(mn.x, v.x); mn.y = fminf(mn.y, v.y); mn.z = fminf(mn.z, v.z); mn.w = fminf(mn.w, v.w);
        mx.x = fmaxf(mx.x, v.x); mx.y = fmaxf(mx.y, v.y); mx.z = fmaxf(mx.z, v.z); mx.w = fmaxf(mx.w, v.w);
    }
    s4[tid] = s; mn4[tid] = mn; mx4[tid] = mx;
    __syncthreads();
    for (int st = 128; st >= 1; st >>= 1){
        if (tid < st){
            float4 a = s4[tid], c = s4[tid+st];
            s4[tid] = make_float4(a.x+c.x, a.y+c.y, a.z+c.z, a.w+c.w);
            float4 d = mn4[tid], e = mn4[tid+st];
            mn4[tid] = make_float4(fminf(d.x,e.x), fminf(d.y,e.y), fminf(d.z,e.z), fminf(d.w,e.w));
            float4 f = mx4[tid], g = mx4[tid+st];
            mx4[tid] = make_float4(fmaxf(f.x,g.x), fmaxf(f.y,g.y), fmaxf(f.z,g.z), fmaxf(f.w,g.w));
        }
        __syncthreads();
    }
    if (tid == 0){
        float* dst = part + (size_t)(b*RBLK + chunk)*12;
        float4 a = s4[0], d = mn4[0], f = mx4[0];
        dst[0]=a.x; dst[1]=a.y; dst[2]=a.z; dst[3]=a.w;
        dst[4]=d.x; dst[5]=d.y; dst[6]=d.z; dst[7]=d.w;
        dst[8]=f.x; dst[9]=f.y; dst[10]=f.z; dst[11]=f.w;
    }
}

// ---------- stage 2: finalize mean + invmax per batch ----------
__global__ __launch_bounds__(128) void k_stats2(const float* __restrict__ part,
                                                float* __restrict__ mean, float* __restrict__ invmax){
    __shared__ float4 s4[128];
    __shared__ float4 mn4[128];
    __shared__ float4 mx4[128];
    int b = blockIdx.x, tid = threadIdx.x;
    const float* src = part + (size_t)(b*RBLK + tid)*12;
    s4[tid]  = make_float4(src[0], src[1], src[2], src[3]);
    mn4[tid] = make_float4(src[4], src[5], src[6], src[7]);
    mx4[tid] = make_float4(src[8], src[9], src[10], src[11]);
    __syncthreads();
    for (int st = 64; st >= 1; st >>= 1){
        if (tid < st){
            float4 a = s4[tid], c = s4[tid+st];
            s4[tid] = make_float4(a.x+c.x, a.y+c.y, a.z+c.z, a.w+c.w);
            float4 d = mn4[tid], e = mn4[tid+st];
            mn4[tid] = make_float4(fminf(d.x,e.x), fminf(d.y,e.y), fminf(d.z,e.z), fminf(d.w,e.w));
            float4 f = mx4[tid], g = mx4[tid+st];
            mx4[tid] = make_float4(fmaxf(f.x,g.x), fmaxf(f.y,g.y), fmaxf(f.z,g.z), fmaxf(f.w,g.w));
        }
        __syncthreads();
    }
    if (tid == 0){
        float4 sum = s4[0], mn = mn4[0], mx = mx4[0];
        float m0 = sum.x*(1.0f/LL), m1 = sum.y*(1.0f/LL), m2 = sum.z*(1.0f/LL), m3 = sum.w*(1.0f/LL);
        mean[b*4+0]=m0; mean[b*4+1]=m1; mean[b*4+2]=m2; mean[b*4+3]=m3;
        float a0 = fmaxf(mx.x - m0, m0 - mn.x);
        float a1 = fmaxf(mx.y - m1, m1 - mn.y);
        float a2 = fmaxf(mx.z - m2, m2 - mn.z);
        float a3 = fmaxf(mx.w - m3, m3 - mn.w);
        invmax[b] = 1.0f / fmaxf(fmaxf(a0, a1), fmaxf(a2, a3));
    }
}

// ---------- A-normalize (R19): coalesced — thread = 8 consecutive samples x 4 channels ----------
__global__ __launch_bounds__(256) void k_anorm(const float* __restrict__ in,
        const float* __restrict__ mean, const float* __restrict__ invmax,
        short* __restrict__ Ahi, short* __restrict__ Alo){
    int gid = blockIdx.x*256 + threadIdx.x;
    if (gid >= BB*(NPAD/8)) return;
    int p8 = gid % (NPAD/8);
    int b  = gid / (NPAD/8);
    float4 mc = *(const float4*)&mean[b*4];
    float iv = invmax[b];
    const float4* px = (const float4*)(in + (size_t)b*LL*CC);   // [LL][4ch]
    bf16x8 h0{}, h1{}, h2{}, h3{}, l0{}, l1{}, l2{}, l3{};
    #pragma unroll
    for (int j = 0; j < 8; ++j){
        int p = p8*8 + j - 160;
        int m2 = p < 0 ? -p : (p >= LL ? 2*LL - 2 - p : p);
        float4 v = px[m2];
        float v0 = (v.x - mc.x)*iv, v1 = (v.y - mc.y)*iv;
        float v2 = (v.z - mc.z)*iv, v3 = (v.w - mc.w)*iv;
        h0[j] = bf_hi(v0); l0[j] = bf_lo(v0);
        h1[j] = bf_hi(v1); l1[j] = bf_lo(v1);
        h2[j] = bf_hi(v2); l2[j] = bf_lo(v2);
        h3[j] = bf_hi(v3); l3[j] = bf_lo(v3);
    }
    size_t o = (size_t)(b*4)*NPAD + (size_t)p8*8;
    *(bf16x8*)&Ahi[o]          = h0;  *(bf16x8*)&Alo[o]          = l0;
    *(bf16x8*)&Ahi[o +   NPAD] = h1;  *(bf16x8*)&Alo[o +   NPAD] = l1;
    *(bf16x8*)&Ahi[o + 2*NPAD] = h2;  *(bf16x8*)&Alo[o + 2*NPAD] = l2;
    *(bf16x8*)&Ahi[o + 3*NPAD] = h3;  *(bf16x8*)&Alo[o + 3*NPAD] = l3;
}

// ---------- STFT as MFMA GEMM: 128x128 tile, 8 waves, shfl epilogue (R18 body) ----------
// MFMA order: acc-ROTATING (8 independent accs per input-pair phase) — do NOT group
// per-acc (R20 regression: dependent chains stall the matrix pipe at 2 blk/CU).
// S out layout: complex S[b][k][h][t] (h = channel-pair), float4 per (b,k,h,t)
__global__ __launch_bounds__(512, 4) void k_gstft(const short* __restrict__ Ahi, const short* __restrict__ Alo,
        const short* __restrict__ Bts, float* __restrict__ S){
    __shared__ short stage[32768];           // 64 KB: 2 buffers x (Ah|Al|Bh|Bl) x 4096 shorts
    int tid = threadIdx.x;
    int row0 = blockIdx.x*128;               // over b*TP*CC rows
    int col0 = blockIdx.y*128;
    int b  = row0 >> 12;                     // TP*CC = 4096 rows per batch
    int t0 = (row0 & 4095) >> 2;             // in {0,32,...,992} — always < TT
    int wave = tid >> 6, lane = tid & 63;
    int wm = wave >> 1, wn = wave & 1;       // 4x2 wave grid: 32 rows x 64 cols each
    int l15 = lane & 15, quad = lane >> 4;
    // ---- staging addresses (per lane): wave w stages rows w*16..w*16+15 ----
    int rowS  = wave*16 + (lane >> 2);       // staged LDS row 0..127
    int chunk = (lane & 3) ^ ((lane >> 3) & 3);   // pre-swizzled global k-chunk
    int tls = t0 + (rowS >> 2); if (tls >= TT) tls = TT - 1;   // clamp; stores guarded later
    size_t gao = (size_t)(b*4 + (rowS & 3))*NPAD + (size_t)tls*160 + chunk*8;
    const short* gAh = Ahi + gao;
    const short* gAl = Alo + gao;
    const short* gB  = Bts + (size_t)(col0 + rowS)*640 + chunk*8;   // hi; lo at +320
    short* lA = stage + wave*512;            // wave-uniform LDS bases (+plane/buffer offset)
    // ---- read addresses ----
    int sw  = (l15 >> 1) & 3;
    int c0r = (quad ^ sw) * 8;               // swizzled chunk offset (shorts)
    int ra0 = (wm*32 + l15)*32 + c0r;        // A row frag 0; frag 1 at +512
    int rb0 = (wn*64 + l15)*32 + c0r;        // B col frag j at + j*512
    f32x4 c00 = {0.f,0.f,0.f,0.f}, c01 = c00, c02 = c00, c03 = c00;
    f32x4 c10 = c00, c11 = c00, c12 = c00, c13 = c00;

    #define STG(kt_, off_) do{ \
        ldsdma16(gAh + (kt_)*32,       lA + (off_));         \
        ldsdma16(gAl + (kt_)*32,       lA + (off_) + 4096);  \
        ldsdma16(gB  + (kt_)*32,       lA + (off_) + 8192);  \
        ldsdma16(gB  + (kt_)*32 + 320, lA + (off_) + 12288); \
    }while(0)

    STG(0, 0);                               // 2-deep prologue
    STG(1, 16384);
    #pragma unroll
    for (int kt = 0; kt < 10; ++kt){
        int offc = (kt & 1) ? 16384 : 0;
        // wave-local: oldest STG (this kt's buffer) must land; newer stays in flight
        if (kt < 9) asm volatile("s_waitcnt vmcnt(4)" ::: "memory");
        else        asm volatile("s_waitcnt vmcnt(0)" ::: "memory");
        __builtin_amdgcn_s_barrier();        // all waves' data for buf[kt&1] present
        bf16x8 a0h = *(bf16x8*)&stage[offc + ra0];
        bf16x8 a1h = *(bf16x8*)&stage[offc + ra0 + 512];
        bf16x8 a0l = *(bf16x8*)&stage[offc + 4096 + ra0];
        bf16x8 a1l = *(bf16x8*)&stage[offc + 4096 + ra0 + 512];
        bf16x8 b0h = *(bf16x8*)&stage[offc + 8192 + rb0];
        bf16x8 b1h = *(bf16x8*)&stage[offc + 8192 + rb0 + 512];
        bf16x8 b2h = *(bf16x8*)&stage[offc + 8192 + rb0 + 1024];
        bf16x8 b3h = *(bf16x8*)&stage[offc + 8192 + rb0 + 1536];
        bf16x8 b0l = *(bf16x8*)&stage[offc + 12288 + rb0];
        bf16x8 b1l = *(bf16x8*)&stage[offc + 12288 + rb0 + 512];
        bf16x8 b2l = *(bf16x8*)&stage[offc + 12288 + rb0 + 1024];
        bf16x8 b3l = *(bf16x8*)&stage[offc + 12288 + rb0 + 1536];
        asm volatile("s_waitcnt lgkmcnt(0)" ::: "memory");
        __builtin_amdgcn_sched_barrier(0);   // rule #18: pin reads before the reuse barrier
        __builtin_amdgcn_s_barrier();        // all waves done reading buf[kt&1]
        if (kt < 8) STG(kt+2, offc);         // overwrite just-freed buffer; lands in ~2 phases
        c00 = __builtin_amdgcn_mfma_f32_16x16x32_bf16(a0h, b0h, c00, 0, 0, 0);
        c01 = __builtin_amdgcn_mfma_f32_16x16x32_bf16(a0h, b1h, c01, 0, 0, 0);
        c02 = __builtin_amdgcn_mfma_f32_16x16x32_bf16(a0h, b2h, c02, 0, 0, 0);
        c03 = __builtin_amdgcn_mfma_f32_16x16x32_bf16(a0h, b3h, c03, 0, 0, 0);
        c10 = __builtin_amdgcn_mfma_f32_16x16x32_bf16(a1h, b0h, c10, 0, 0, 0);
        c11 = __builtin_amdgcn_mfma_f32_16x16x32_bf16(a1h, b1h, c11, 0, 0, 0);
        c12 = __builtin_amdgcn_mfma_f32_16x16x32_bf16(a1h, b2h, c12, 0, 0, 0);
        c13 = __builtin_amdgcn_mfma_f32_16x16x32_bf16(a1h, b3h, c13, 0, 0, 0);
        c00 = __builtin_amdgcn_mfma_f32_16x16x32_bf16(a0l, b0h, c00, 0, 0, 0);
        c01 = __builtin_amdgcn_mfma_f32_16x16x32_bf16(a0l, b1h, c01, 0, 0, 0);
        c02 = __builtin_amdgcn_mfma_f32_16x16x32_bf16(a0l, b2h, c02, 0, 0, 0);
        c03 = __builtin_amdgcn_mfma_f32_16x16x32_bf16(a0l, b3h, c03, 0, 0, 0);
        c10 = __builtin_amdgcn_mfma_f32_16x16x32_bf16(a1l, b0h, c10, 0, 0, 0);
        c11 = __builtin_amdgcn_mfma_f32_16x16x32_bf16(a1l, b1h, c11, 0, 0, 0);
        c12 = __builtin_amdgcn_mfma_f32_16x16x32_bf16(a1l, b2h, c12, 0, 0, 0);
        c13 = __builtin_amdgcn_mfma_f32_16x16x32_bf16(a1l, b3h, c13, 0, 0, 0);
        c00 = __builtin_amdgcn_mfma_f32_16x16x32_bf16(a0h, b0l, c00, 0, 0, 0);
        c01 = __builtin_amdgcn_mfma_f32_16x16x32_bf16(a0h, b1l, c01, 0, 0, 0);
        c02 = __builtin_amdgcn_mfma_f32_16x16x32_bf16(a0h, b2l, c02, 0, 0, 0);
        c03 = __builtin_amdgcn_mfma_f32_16x16x32_bf16(a0h, b3l, c03, 0, 0, 0);
        c10 = __builtin_amdgcn_mfma_f32_16x16x32_bf16(a1h, b0l, c10, 0, 0, 0);
        c11 = __builtin_amdgcn_mfma_f32_16x16x32_bf16(a1h, b1l, c11, 0, 0, 0);
        c12 = __builtin_amdgcn_mfma_f32_16x16x32_bf16(a1h, b2l, c12, 0, 0, 0);
        c13 = __builtin_amdgcn_mfma_f32_16x16x32_bf16(a1h, b3l, c13, 0, 0, 0);
    }
    #undef STG
    // ---- epilogue: shfl-pair assembly, direct global store (no LDS) ----
    int tq  = t0 + wm*8 + quad;
    int kgb = (col0 >> 1) + wn*32 + (l15 >> 1);
    int h   = l15 & 1;
    float4* S4 = (float4*)S;
    #define EPI(cf, i_, j_) do{ \
        int t = tq + 4*(i_); \
        int kg = kgb + 8*(j_); \
        if (t < TT && kg < FB){ \
            float p0 = __shfl_xor(cf[0], 1); \
            float p1 = __shfl_xor(cf[1], 1); \
            float p2 = __shfl_xor(cf[2], 1); \
            float p3 = __shfl_xor(cf[3], 1); \
            float4 v = h ? make_float4(p2, cf[2], p3, cf[3]) \
                         : make_float4(cf[0], p0, cf[1], p1); \
            S4[((size_t)((b*FB + kg)*2 + h))*TT + t] = v; \
        } \
    }while(0)
    EPI(c00, 0, 0); EPI(c01, 0, 1); EPI(c02, 0, 2); EPI(c03, 0, 3);
    EPI(c10, 1, 0); EPI(c11, 1, 1); EPI(c12, 1, 2); EPI(c13, 1, 3);
    #undef EPI
}

// covariance recurrence, original weighted form (first-frame handling): R = a*R + wg*outer(X)
#define UPD(first) do{ \
    float aa = (first) ? 0.f : 0.05f; float wg = (first) ? 1.f : 0.95f; \
    float y0x=wg*x0.x, y0y=wg*x0.y, y1x=wg*x1.x, y1y=wg*x1.y; \
    float y2x=wg*x2.x, y2y=wg*x2.y, y3x=wg*x3.x, y3y=wg*x3.y; \
    d0 = aa*d0 + y0x*x0.x + y0y*x0.y; \
    d1 = aa*d1 + y1x*x1.x + y1y*x1.y; \
    d2 = aa*d2 + y2x*x2.x + y2y*x2.y; \
    d3 = aa*d3 + y3x*x3.x + y3y*x3.y; \
    r10.x = aa*r10.x + y1x*x0.x + y1y*x0.y;  r10.y = aa*r10.y + y1y*x0.x - y1x*x0.y; \
    r20.x = aa*r20.x + y2x*x0.x + y2y*x0.y;  r20.y = aa*r20.y + y2y*x0.x - y2x*x0.y; \
    r30.x = aa*r30.x + y3x*x0.x + y3y*x0.y;  r30.y = aa*r30.y + y3y*x0.x - y3x*x0.y; \
    r21.x = aa*r21.x + y2x*x1.x + y2y*x1.y;  r21.y = aa*r21.y + y2y*x1.x - y2x*x1.y; \
    r31.x = aa*r31.x + y3x*x1.x + y3y*x1.y;  r31.y = aa*r31.y + y3y*x1.x - y3x*x1.y; \
    r32.x = aa*r32.x + y3x*x2.x + y3y*x2.y;  r32.y = aa*r32.y + y3y*x2.x - y3x*x2.y; \
}while(0)

// Q-form (R19): Q = 0.05*Q + outer(X); Q = R/0.95 exactly when no first-frame is in
// the truncated window. The solve is scale-invariant in R -> outputs identical.
#define UPDQ do{ \
    d0 = 0.05f*d0 + x0.x*x0.x + x0.y*x0.y; \
    d1 = 0.05f*d1 + x1.x*x1.x + x1.y*x1.y; \
    d2 = 0.05f*d2 + x2.x*x2.x + x2.y*x2.y; \
    d3 = 0.05f*d3 + x3.x*x3.x + x3.y*x3.y; \
    r10.x = 0.05f*r10.x + x1.x*x0.x + x1.y*x0.y;  r10.y = 0.05f*r10.y + x1.y*x0.x - x1.x*x0.y; \
    r20.x = 0.05f*r20.x + x2.x*x0.x + x2.y*x0.y;  r20.y = 0.05f*r20.y + x2.y*x0.x - x2.x*x0.y; \
    r30.x = 0.05f*r30.x + x3.x*x0.x + x3.y*x0.y;  r30.y = 0.05f*r30.y + x3.y*x0.x - x3.x*x0.y; \
    r21.x = 0.05f*r21.x + x2.x*x1.x + x2.y*x1.y;  r21.y = 0.05f*r21.y + x2.y*x1.x - x2.x*x1.y; \
    r31.x = 0.05f*r31.x + x3.x*x1.x + x3.y*x1.y;  r31.y = 0.05f*r31.y + x3.y*x1.x - x3.x*x1.y; \
    r32.x = 0.05f*r32.x + x3.x*x2.x + x3.y*x2.y;  r32.y = 0.05f*r32.y + x3.y*x2.x - x3.x*x2.y; \
}while(0)

// ---------- scan (R20): full-strip (1 block per (b,f)), 512 threads, 2 outputs/thread ----------
__global__ __launch_bounds__(512) void k_scan(const float* __restrict__ S, const float* __restrict__ htab,
                      float* __restrict__ S1, float* __restrict__ S2){
    __shared__ float4 tile[2016];     // swizzled full strip (2*TT=2002 used; swz stays in-group)
    int bf = blockIdx.x;              // b*FB + f
    int f  = bf % FB;
    int tid = threadIdx.x;
    const float4* P0 = (const float4*)S + (size_t)(bf*2)*TT;
    const float4* P1 = P0 + TT;
    for (int i = tid; i < 2*TT; i += 512){
        int tt = i >> 1;
        tile[i ^ ((i>>4)&7)] = (i & 1) ? P1[tt] : P0[tt];   // interleave planes into tile
    }
    __syncthreads();
    int t0 = tid*2;
    if (t0 < TT){
        const float2* hp = (const float2*)htab;
        float2 ha0 = hp[f*4+0], ha1 = hp[f*4+1], ha2 = hp[f*4+2], ha3 = hp[f*4+3];
        float2 hb0 = hp[(FB+f)*4+0], hb1 = hp[(FB+f)*4+1], hb2 = hp[(FB+f)*4+2], hb3 = hp[(FB+f)*4+3];
        float d0=0,d1=0,d2=0,d3=0;
        float2 r10={0,0}, r20={0,0}, r30={0,0}, r21={0,0}, r31={0,0}, r32={0,0};
        float2 x0, x1, x2, x3;
        #define LOADX(tau_) do{ int i0_ = 2*(tau_); \
            float4 v0_ = tile[i0_ ^ ((i0_>>4)&7)]; \
            float4 v1_ = tile[(i0_+1) ^ (((i0_+1)>>4)&7)]; \
            x0 = make_float2(v0_.x, v0_.y); x1 = make_float2(v0_.z, v0_.w); \
            x2 = make_float2(v1_.x, v1_.y); x3 = make_float2(v1_.z, v1_.w); \
        }while(0)
        bool qform = (t0 >= KWARM + 1);   // no frame-0 special in any window
        int ts = t0 - KWARM; if (ts < 0) ts = 0;
        if (qform){
            #pragma unroll
            for (int u = 0; u < KWARM; ++u){ LOADX(ts + u); UPDQ; }
        } else {
            for (int tau = 0; tau < t0; ++tau){ LOADX(tau); UPD(tau == 0); }
        }
        float2* S1g = (float2*)S1 + (size_t)bf*TT;
        float2* S2g = (float2*)S2 + (size_t)bf*TT;
        #pragma unroll
        for (int j = 0; j < 2; ++j){
            int t = t0 + j;
            if (t >= TT) break;
            LOADX(t);
            if (qform) UPDQ; else UPD(t == 0);
            float trc = d0 + d1 + d2 + d3;
            float lam = trc * 0.25f;
            float e0 = d0 + lam, e1 = d1 + lam, e2 = d2 + lam, e3 = d3 + lam;
            float detP = e0*e1 - (r10.x*r10.x + r10.y*r10.y);
            float2 w00 = csub(cscale(r20, e1), cmulf(r10, r21));
            float2 w01 = csub(cscale(r30, e1), cmulf(r10, r31));
            float2 w10 = csub(cscale(r21, e0), cjmul(r10, r20));
            float2 w11 = csub(cscale(r31, e0), cjmul(r10, r30));
            float2 va = cjmul(r30, w00), vb = cjmul(r31, w10);
            float2 V10 = make_float2(va.x + vb.x, -(va.y + vb.y));
            float reV00 = r20.x*w00.x + r20.y*w00.y + r21.x*w10.x + r21.y*w10.y;
            float reV11 = r30.x*w01.x + r30.y*w01.y + r31.x*w11.x + r31.y*w11.y;
            float t00 = detP*e2 - reV00;
            float t11 = detP*e3 - reV11;
            float2 t10 = csub(cscale(r32, detP), V10);
            float detT = t00*t11 - (t10.x*t10.x + t10.y*t10.y);
            #pragma unroll
            for (int m = 0; m < 2; ++m){
                float2 h0 = m ? hb0 : ha0;
                float2 h1 = m ? hb1 : ha1;
                float2 h2 = m ? hb2 : ha2;
                float2 h3 = m ? hb3 : ha3;
                float2 g0 = csub(cscale(h0, e1), cjmul(r10, h1));
                float2 g1 = csub(cscale(h1, e0), cmulf(r10, h0));
                float2 ta = cmulf(r20, g0), tb = cmulf(r21, g1);
                float2 hh0 = make_float2(detP*h2.x - ta.x - tb.x, detP*h2.y - ta.y - tb.y);
                ta = cmulf(r30, g0); tb = cmulf(r31, g1);
                float2 hh1 = make_float2(detP*h3.x - ta.x - tb.x, detP*h3.y - ta.y - tb.y);
                float2 y20 = csub(cscale(hh0, t11), cjmul(t10, hh1));
                float2 y21 = csub(cscale(hh1, t00), cmulf(t10, hh0));
                float2 u20 = cscale(y20, detP), u21 = cscale(y21, detP);
                ta = cmulcj(y20, r20); tb = cmulcj(y21, r30);
                float2 q0 = make_float2(detT*h0.x - ta.x - tb.x, detT*h0.y - ta.y - tb.y);
                ta = cmulcj(y20, r21); tb = cmulcj(y21, r31);
                float2 q1 = make_float2(detT*h1.x - ta.x - tb.x, detT*h1.y - ta.y - tb.y);
                float2 u10 = csub(cscale(q0, e1), cjmul(r10, q1));
                float2 u11 = csub(cscale(q1, e0), cmulf(r10, q0));
                float2 den = cjmul(h0, u10), tmp;
                tmp = cjmul(h1, u11); den.x += tmp.x; den.y += tmp.y;
                tmp = cjmul(h2, u20); den.x += tmp.x; den.y += tmp.y;
                tmp = cjmul(h3, u21); den.x += tmp.x; den.y += tmp.y;
                float2 num = cjmul(u10, x0);
                tmp = cjmul(u11, x1); num.x += tmp.x; num.y += tmp.y;
                tmp = cjmul(u20, x2); num.x += tmp.x; num.y += tmp.y;
                tmp = cjmul(u21, x3); num.x += tmp.x; num.y += tmp.y;
                float2 s = cdivf(num, make_float2(den.x, -den.y));
                if (m) S2g[t] = s; else S1g[t] = s;
            }
        }
        #undef LOADX
    }
}

// ---------- pack v2 (R8-verified): coalesced LDS transpose. block = (rb, 32-t tile) ----------
__global__ __launch_bounds__(256) void k_pack(const float* __restrict__ S1, const float* __restrict__ S2,
                                              short* __restrict__ A){
    __shared__ short tile[32*708];        // 45,312 B; row = t-in-tile, col = kk (hi 0..351 | lo 352..703)
    int bid = blockIdx.x;                 // rb*32 + tb
    int tb = bid & 31, rb = bid >> 5;
    int t0 = tb*32;
    int beam = rb >> 3, b = rb & 7;
    const float2* Sp = (const float2*)(beam ? S2 : S1) + (size_t)b*FB*TT;
    int tid = threadIdx.x;
    for (int idx = tid; idx < 32*176; idx += 256){
        int bin = idx >> 5, tq = idx & 31;
        int t = t0 + tq;
        float2 s = make_float2(0.f, 0.f);
        if (bin < FB && t < TT) s = Sp[(size_t)bin*TT + t];
        int c0 = 2*bin;
        tile[tq*708 + c0]            = bf_hi(s.x);
        tile[tq*708 + c0 + 1]        = bf_hi(s.y);
        tile[tq*708 + KSEC + c0]     = bf_lo(s.x);
        tile[tq*708 + KSEC + c0 + 1] = bf_lo(s.y);
    }
    __syncthreads();
    for (int idx = tid; idx < 32*176; idx += 256){
        int tq = idx / 176, k4 = idx % 176;
        int t = t0 + tq;
        if (t < TT)
            *(short4*)&A[(size_t)(rb*TT + t)*LDK + k4*4] = *(short4*)&tile[tq*708 + k4*4];
    }
}

// ---------- irfft MFMA GEMM (R20): 3-buffer ring, ONE barrier per step ----------
// The data-ready barrier at step s proves all waves completed s-1's ds_reads (their
// own lgkmcnt(0) precedes their s-1 MFMAs), so STG(s+2) into buf[(s-1)%3] is safe.
// 33 steps, vmcnt(2) steady-state. wn=1 waves of y=2 block fully dead (skip work).
__global__ __launch_bounds__(512, 4) void k_gemm(const short* __restrict__ A, const short* __restrict__ Bt,
                                                 float* __restrict__ C){
    __shared__ short sb2[24576];           // 48 KB: 3 buffers x (A|B) x 4096 shorts
    int tid = threadIdx.x;
    int row0 = blockIdx.x * 128;
    int col0 = blockIdx.y * 128;
    int wave = tid >> 6, lane = tid & 63;
    int wm = wave >> 1, wn = wave & 1;     // 4x2 wave grid: 32 rows x 64 cols each
    int l15 = lane & 15, quad = lane >> 4;
    bool wlive = (col0 + wn*64) < NFFT;    // y=2,wn=1 waves are fully past NFFT
    // staging (per lane)
    int rowS  = wave*16 + (lane >> 2);
    int chunk = (lane & 3) ^ ((lane >> 3) & 3);
    int grS = row0 + rowS; if (grS >= GM) grS = GM - 1;       // clamp; stores guarded
    int grB = col0 + rowS; if (grB >= NFFT) grB = NFFT - 1;   // clamp; cols >=320 unused
    const short* gA = A  + (size_t)grS*LDK + chunk*8;
    const short* gB = Bt + (size_t)grB*LDK + chunk*8;
    short* lA = sb2 + wave*512;
    // reads
    int sw  = (l15 >> 1) & 3;
    int c0r = (quad ^ sw) * 8;
    int ra0 = (wm*32 + l15)*32 + c0r;      // frag 1 at +512
    int rb0 = (wn*64 + l15)*32 + c0r;      // frag j at +j*512
    f32x4 c00 = {0.f,0.f,0.f,0.f}, c01 = c00, c02 = c00, c03 = c00;
    f32x4 c10 = c00, c11 = c00, c12 = c00, c13 = c00;

    #define KOF(s_, ka_, kb_) { int sg_ = ((s_) >= 22) ? 2 : ((s_) >= 11) ? 1 : 0; \
        int kt_ = (s_) - sg_*11; \
        ka_ = ((sg_ == 1) ? KSEC : 0) + kt_*32; \
        kb_ = ((sg_ == 2) ? KSEC : 0) + kt_*32; }
    #define STG2(s_, off_) do{ int ka_, kb_; KOF(s_, ka_, kb_); \
        ldsdma16(gA + ka_, lA + (off_));        \
        ldsdma16(gB + kb_, lA + (off_) + 4096); \
    }while(0)

    STG2(0, 0);                            // 2-deep prologue into ring slots 0,1
    STG2(1, 8192);
    #pragma unroll
    for (int s = 0; s < 33; ++s){
        int offc = (s % 3) * 8192;
        if (s < 32) asm volatile("s_waitcnt vmcnt(2)" ::: "memory");
        else        asm volatile("s_waitcnt vmcnt(0)" ::: "memory");
        __builtin_amdgcn_s_barrier();      // buf[s%3] ready; also: all s-1 reads done
        if (s < 31) STG2(s+2, ((s+2) % 3) * 8192);   // writes buf[(s-1)%3] — freed above
        bf16x8 a0{}, a1{}, b0{}, b1{}, b2{}, b3{};
        if (wlive){
            a0 = *(bf16x8*)&sb2[offc + ra0];
            a1 = *(bf16x8*)&sb2[offc + ra0 + 512];
            b0 = *(bf16x8*)&sb2[offc + 4096 + rb0];
            b1 = *(bf16x8*)&sb2[offc + 4096 + rb0 + 512];
            b2 = *(bf16x8*)&sb2[offc + 4096 + rb0 + 1024];
            b3 = *(bf16x8*)&sb2[offc + 4096 + rb0 + 1536];
            asm volatile("s_waitcnt lgkmcnt(0)" ::: "memory");
            __builtin_amdgcn_sched_barrier(0);
            c00 = __builtin_amdgcn_mfma_f32_16x16x32_bf16(a0, b0, c00, 0, 0, 0);
            c01 = __builtin_amdgcn_mfma_f32_16x16x32_bf16(a0, b1, c01, 0, 0, 0);
            c02 = __builtin_amdgcn_mfma_f32_16x16x32_bf16(a0, b2, c02, 0, 0, 0);
            c03 = __builtin_amdgcn_mfma_f32_16x16x32_bf16(a0, b3, c03, 0, 0, 0);
            c10 = __builtin_amdgcn_mfma_f32_16x16x32_bf16(a1, b0, c10, 0, 0, 0);
            c11 = __builtin_amdgcn_mfma_f32_16x16x32_bf16(a1, b1, c11, 0, 0, 0);
            c12 = __builtin_amdgcn_mfma_f32_16x16x32_bf16(a1, b2, c12, 0, 0, 0);
            c13 = __builtin_amdgcn_mfma_f32_16x16x32_bf16(a1, b3, c13, 0, 0, 0);
        }
    }
    #undef STG2
    #undef KOF
    if (wlive){
        #pragma unroll
        for (int r = 0; r < 4; ++r){
            int orow0 = row0 + wm*32 + quad*4 + r;
            int oc = col0 + wn*64 + l15;
            if (orow0 < GM){
                if (oc      < NFFT) C[(size_t)orow0*NFFT + oc]      = c00[r];
                if (oc + 16 < NFFT) C[(size_t)orow0*NFFT + oc + 16] = c01[r];
                if (oc + 32 < NFFT) C[(size_t)orow0*NFFT + oc + 32] = c02[r];
                if (oc + 48 < NFFT) C[(size_t)orow0*NFFT + oc + 48] = c03[r];
            }
            if (orow0 + 16 < GM){
                if (oc      < NFFT) C[(size_t)(orow0+16)*NFFT + oc]      = c10[r];
                if (oc + 16 < NFFT) C[(size_t)(orow0+16)*NFFT + oc + 16] = c11[r];
                if (oc + 32 < NFFT) C[(size_t)(orow0+16)*NFFT + oc + 32] = c12[r];
                if (oc + 48 < NFFT) C[(size_t)(orow0+16)*NFFT + oc + 48] = c13[r];
            }
        }
    }
}

// ---------- overlap-add, float4: 4 outputs/thread (wsum==2 in cropped interior) ----------
__global__ __launch_bounds__(256) void k_ola(const float* __restrict__ frames, float* __restrict__ out){
    int gid = blockIdx.x*256 + threadIdx.x;
    if (gid >= 2*BB*(LL/4)) return;
    int o4 = (gid % (LL/4))*4;
    int rb = gid / (LL/4);                 // beam*BB + b
    int i  = o4 + HOP;                     // mult of 4; r in {0,4,...,156}
    int t1 = i / HOP;
    int r  = i - t1*HOP;
    const float4* fb = (const float4*)(frames + (size_t)rb*TT*NFFT);
    float4 a = fb[(t1*NFFT + r) >> 2];
    float4 b = fb[((t1-1)*NFFT + r + HOP) >> 2];
    ((float4*)out)[gid] = make_float4(0.5f*(a.x+b.x), 0.5f*(a.y+b.y), 0.5f*(a.z+b.z), 0.5f*(a.w+b.w));
}

extern "C" void kernel_launch(void* const* d_in, const int* in_sizes, int n_in,
                              void* d_out, int out_size, void* d_ws, size_t ws_size,
                              hipStream_t stream){
    const float* in  = (const float*)d_in[0];   // [B, L, C] fp32
    const float* win = (const float*)d_in[1];   // [320] fp32
    float* ws = (float*)d_ws;
    // ws (floats): mean 32 | invmax 8 | htab 2576 | pad -> header 3072
    //              | S1 (2,578,576) | S2 (2,578,576) | S (10,314,304)   total ~62 MB
    // aliases: part -> S1 head (dead before k_anorm); Ahi/Alo -> S1+S2 (dead after k_gstft);
    //          Bts + Bt -> head of d_out (dead until k_ola fully overwrites; NOT in S — R13 bug);
    //          A_ir -> S (post-scan); frames -> S1/S2 (post-pack)
    float* mean   = ws;
    float* invmax = ws + 32;
    float* htab   = ws + 48;
    float* S1     = ws + 3072;
    size_t nS1 = (size_t)2*BB*FB*TT;            // 2,578,576 floats
    float* S2 = S1 + nS1;
    float* S  = S2 + nS1;                       // 10,314,304 floats
    float* part = S1;
    short* Ahi = (short*)S1;                    // 8*4*160320 = 5,130,240 shorts
    short* Alo = Ahi + (size_t)BB*CC*NPAD;      // total 10,260,480 shorts <= S1+S2 (10,314,304 short-equiv)
    short* Bts = (short*)d_out;                 // 245,760 shorts (= 122,880 floats)
    short* Bt  = (short*)((float*)d_out + 131072); // 225,280 shorts at float-offset 131072 (16B aligned)
    short* A  = (short*)S;                      // irfft A: 16016*704 bf16
    float* frames = S1;                         // 16016*320 floats over dead S1+S2

    int ngen = 2*FB*CC + 384*640 + NFFT*LDK;    // fused table generation
    k_gen<<<dim3((ngen + 255)/256), dim3(256), 0, stream>>>(win, htab, Bts, Bt);
    k_stats1<<<dim3(BB*RBLK), dim3(256), 0, stream>>>(in, part);
    k_stats2<<<dim3(BB), dim3(128), 0, stream>>>(part, mean, invmax);
    k_anorm<<<dim3((BB*(NPAD/8) + 255)/256), dim3(256), 0, stream>>>(in, mean, invmax, Ahi, Alo);
    k_gstft<<<dim3(BB*TP*CC/128, 3), dim3(512), 0, stream>>>(Ahi, Alo, Bts, S);
    k_scan<<<dim3(BB*FB), dim3(512), 0, stream>>>(S, htab, S1, S2);
    k_pack<<<dim3(512), dim3(256), 0, stream>>>(S1, S2, A);
    k_gemm<<<dim3((GM + 127)/128, (NFFT + 127)/128), dim3(512), 0, stream>>>(A, Bt, frames);
    k_ola<<<dim3((2*BB*(LL/4) + 255)/256), dim3(256), 0, stream>>>(frames, (float*)d_out);
}